// Round 8
// baseline (837.976 us; speedup 1.0000x reference)
//
#include <hip/hip_runtime.h>
#include <math.h>

#define TT 256
#define WARM 16        // Riccati restart washout: rho~0.56 => 0.56^16 ~ 1e-4
// ws float offsets
#define OFF_A    0      // A           (256)
#define OFF_NX   256    // Nx diag     (16)
#define OFF_W    512    // W = C^T Na^-1        (16x32 = 512)
#define OFF_E    1024   // E = Nxi A            (256)
#define OFF_H    1280   // H = A^T Nxi A        (256)
#define OFF_F    1536   // F = G + diag(Nxi)    (256)
#define OFF_CA   1792   // CA = C A             (32x16 = 512)
#define OFF_CB   2304   // CB = C B             (32x8  = 256)
#define OFF_K    2560   // K_t chain    (17 x 512)  -> ends 11264
#define OFF_MC   11264  // Mc_t chain   (17 x 256)  -> ends 15616
#define OFF_NB   15616  // Nb_t chain   (17 x 128)  -> ends 17792
#define OFF_GV   17792  // gv chain     (256 x 256 x 16 = 1048576)
#define NEED_WS_BYTES ((size_t)(OFF_GV + TT * 256 * 16) * 4)

__device__ __forceinline__ float softplus(float v) {
    return fmaxf(v, 0.0f) + log1pf(expf(-fabsf(v)));
}

// ---------------------------------------------------------------------------
// Kernel 1 (verified R6): QR(M),QR(N), assemble A; constants into ws.
// ---------------------------------------------------------------------------
__global__ __launch_bounds__(64) void setup_k(
    const float* __restrict__ Mm, const float* __restrict__ Nm,
    const float* __restrict__ dvec, const float* __restrict__ Bm,
    const float* __restrict__ Cm, const float* __restrict__ nx,
    const float* __restrict__ na, float* __restrict__ ws)
{
    __shared__ float qm[16][16], qn[16][16], T0[16][16];
    __shared__ float sC[32][16], sW[16][32], sAm[16][17], sBm[16][9];
    __shared__ float spv[16], d2[16], sNai[32], sNxi[16];
    const int lane = threadIdx.x;

    for (int e = lane; e < 256; e += 64) { qm[e >> 4][e & 15] = Mm[e]; qn[e >> 4][e & 15] = Nm[e]; }
    for (int e = lane; e < 512; e += 64) sC[e >> 4][e & 15] = Cm[e];
    for (int e = lane; e < 128; e += 64) sBm[e >> 3][e & 7] = Bm[e];
    if (lane < 16) {
        float s = softplus(dvec[lane]);
        spv[lane] = sqrtf(s);
        d2[lane] = 1.0f / sqrtf(1.0f + s);
        float nxv = softplus(nx[lane]) + 1e-4f;
        ws[OFF_NX + lane] = nxv;
        sNxi[lane] = 1.0f / nxv;
    }
    if (lane < 32) sNai[lane] = 1.0f / (softplus(na[lane]) + 1e-4f);
    __syncthreads();

    for (int m = 0; m < 2; ++m) {
        float (*Q)[16] = (m == 0) ? qm : qn;
        for (int j = 0; j < 16; ++j) {
            float nrm = 0.f;
#pragma unroll
            for (int r = 0; r < 16; ++r) nrm += Q[r][j] * Q[r][j];
            const float scal = 1.0f / sqrtf(nrm);
            __syncthreads();
            if (lane < 16) Q[lane][j] *= scal;
            __syncthreads();
            if (lane < 16 && lane > j) {
                float pr = 0.f;
#pragma unroll
                for (int r = 0; r < 16; ++r) pr += Q[r][j] * Q[r][lane];
#pragma unroll
                for (int r = 0; r < 16; ++r) Q[r][lane] -= pr * Q[r][j];
            }
            __syncthreads();
        }
    }
    for (int e = lane; e < 256; e += 64) {
        int i = e >> 4, j = e & 15;
        float s = 0.f;
#pragma unroll
        for (int q = 0; q < 16; ++q) s += qm[i][q] * d2[q] * qn[j][q];
        T0[i][j] = spv[i] * s;
    }
    __syncthreads();
    for (int e = lane; e < 256; e += 64) {
        int i = e >> 4, j = e & 15;
        float s = 0.f;
#pragma unroll
        for (int q = 0; q < 16; ++q) s += qn[i][q] * T0[q][j];
        ws[OFF_A + e] = s;
        sAm[i][j] = s;
    }
    for (int e = lane; e < 512; e += 64) {
        int q = e >> 5, r = e & 31;
        float w = sC[r][q] * sNai[r];
        sW[q][r] = w;
        ws[OFF_W + e] = w;
    }
    __syncthreads();
    for (int e = lane; e < 256; e += 64) {
        int i = e >> 4, j = e & 15;
        float g = 0.f;
#pragma unroll
        for (int r = 0; r < 32; ++r) g += sC[r][i] * sW[j][r];
        ws[OFF_F + e] = g + ((i == j) ? sNxi[i] : 0.f);
        ws[OFF_E + e] = sNxi[i] * sAm[i][j];
        float hsum = 0.f;
#pragma unroll
        for (int q = 0; q < 16; ++q) hsum += sAm[q][i] * sNxi[q] * sAm[q][j];
        ws[OFF_H + e] = hsum;
    }
    for (int e = lane; e < 512; e += 64) {
        int r = e >> 4, j = e & 15;
        float s = 0.f;
#pragma unroll
        for (int q = 0; q < 16; ++q) s += sC[r][q] * sAm[q][j];
        ws[OFF_CA + e] = s;
    }
    for (int e = lane; e < 256; e += 64) {
        int r = e >> 3, j = e & 7;
        float s = 0.f;
#pragma unroll
        for (int q = 0; q < 16; ++q) s += sC[r][q] * sBm[q][j];
        ws[OFF_CB + e] = s;
    }
}

// Shuffle-based Gauss-Jordan (verified R5/R6).
__device__ __forceinline__ void gj16(float (&aug)[8], const int i, const int gq) {
#pragma unroll
    for (int j = 0; j < 16; ++j) {
        float prow[8];
#pragma unroll
        for (int k = 0; k < 8; ++k) prow[k] = __shfl(aug[k], j + 16 * gq);
        const float pjj = __shfl(aug[j & 7], j + 16 * (j >> 3));
        const float cij = __shfl(aug[j & 7], i + 16 * (j >> 3));
        const float pivinv = 1.0f / pjj;
        const float f = cij * pivinv;
#pragma unroll
        for (int k = 0; k < 8; ++k)
            aug[k] = (i == j) ? prow[k] * pivinv : aug[k] - f * prow[k];
    }
}

// ---------------------------------------------------------------------------
// Kernel 2 (verified R6, WARM=16, grid=17): info-form gain chain.
// ---------------------------------------------------------------------------
__global__ __launch_bounds__(64) void chain_k(
    const float* __restrict__ cov0, const float* __restrict__ Bm,
    const float* __restrict__ ws, float* __restrict__ wsK,
    float* __restrict__ wsM, float* __restrict__ wsN)
{
    __shared__ float sW[16][33], sP[16][17], sK[16][33];
    __shared__ float sCA[32][17], sCB[32][9];
    const int lane = threadIdx.x;
    const int t = blockIdx.x;            // 0..WARM
    const int nsteps = t + 1;
    const int i = lane & 15, gq = lane >> 4, h = gq & 1;

    float Erow[16], Hr[8], Fr[8];
#pragma unroll
    for (int q = 0; q < 16; ++q) Erow[q] = ws[OFF_E + i * 16 + q];
#pragma unroll
    for (int k = 0; k < 8; ++k) Hr[k] = ws[OFF_H + i * 16 + 8 * h + k];
#pragma unroll
    for (int k = 0; k < 8; ++k) Fr[k] = ws[OFF_F + i * 16 + 8 * h + k];
    for (int e = lane; e < 512; e += 64) sW[e >> 5][e & 31] = ws[OFF_W + e];
    for (int e = lane; e < 512; e += 64) sCA[e >> 4][e & 15] = ws[OFF_CA + e];
    for (int e = lane; e < 256; e += 64) sCB[e >> 3][e & 7] = ws[OFF_CB + e];

    float aug[8];
#pragma unroll
    for (int k = 0; k < 8; ++k)
        aug[k] = (gq < 2) ? cov0[i * 16 + 8 * gq + k]
                          : ((8 * (gq - 2) + k == i) ? 1.f : 0.f);
    gj16(aug, i, gq);
    float L_r[8];
#pragma unroll
    for (int k = 0; k < 8; ++k) L_r[k] = __shfl(aug[k], i + 16 * (2 + h));

    for (int s = 0; s < nsteps; ++s) {
#pragma unroll
        for (int k = 0; k < 8; ++k)
            aug[k] = (gq < 2) ? (L_r[k] + Hr[k])
                              : ((8 * (gq - 2) + k == i) ? 1.f : 0.f);
        gj16(aug, i, gq);
        float T_r[8];
#pragma unroll
        for (int k = 0; k < 8; ++k) T_r[k] = 0.f;
#pragma unroll
        for (int q = 0; q < 16; ++q) {
            const float eq = Erow[q];
#pragma unroll
            for (int k = 0; k < 8; ++k)
                T_r[k] += eq * __shfl(aug[k], q + 16 * (2 + h));
        }
        float Trow[16];
#pragma unroll
        for (int q = 0; q < 16; ++q) Trow[q] = __shfl(T_r[q & 7], i + 16 * (q >> 3));
#pragma unroll
        for (int k = 0; k < 8; ++k) L_r[k] = Fr[k];
#pragma unroll
        for (int q = 0; q < 16; ++q) {
            const float tq = Trow[q];
#pragma unroll
            for (int k = 0; k < 8; ++k) L_r[k] -= tq * __shfl(Erow[q], 8 * h + k);
        }
    }
#pragma unroll
    for (int k = 0; k < 8; ++k)
        aug[k] = (gq < 2) ? L_r[k] : ((8 * (gq - 2) + k == i) ? 1.f : 0.f);
    gj16(aug, i, gq);
    float P_r[8];
#pragma unroll
    for (int k = 0; k < 8; ++k) P_r[k] = __shfl(aug[k], i + 16 * (2 + h));
    if (lane < 32) {
#pragma unroll
        for (int k = 0; k < 8; ++k) sP[i][8 * h + k] = P_r[k];
    }
    __syncthreads();
#pragma unroll
    for (int m = 0; m < 8; ++m) {
        const int e = lane + 64 * m, ii = e >> 5, rr = e & 31;
        float s = 0.f;
#pragma unroll
        for (int q = 0; q < 16; ++q) s += sP[ii][q] * sW[q][rr];
        sK[ii][rr] = s;
        wsK[(size_t)t * 512 + e] = s;
    }
    __syncthreads();
#pragma unroll
    for (int m = 0; m < 4; ++m) {
        const int e = lane + 64 * m, ii = e >> 4, jj = e & 15;
        float s = ws[OFF_A + e];
#pragma unroll
        for (int r = 0; r < 32; ++r) s -= sK[ii][r] * sCA[r][jj];
        wsM[(size_t)t * 256 + e] = s;
    }
#pragma unroll
    for (int m = 0; m < 2; ++m) {
        const int e = lane + 64 * m, ii = e >> 3, jj = e & 7;
        float s = Bm[e];
#pragma unroll
        for (int r = 0; r < 32; ++r) s -= sK[ii][r] * sCB[r][jj];
        wsN[(size_t)t * 128 + e] = s;
    }
}

// ---------------------------------------------------------------------------
// Kernel 3a (primary): gv_t(b) = Nb_t u_bt + K_t a_bt — fully parallel.
// Grid: TT blocks (t), 256 threads (b). gv layout: t*4096 + b*16 + i.
// ---------------------------------------------------------------------------
__global__ __launch_bounds__(256) void gv_k(
    const float* __restrict__ u, const float* __restrict__ a,
    const float* __restrict__ wsK, const float* __restrict__ wsN,
    float* __restrict__ gvb)
{
    const int t = blockIdx.x;
    const int tc = (t < WARM) ? t : WARM;
    const int b = threadIdx.x;
    const float* __restrict__ Kt = wsK + (size_t)tc * 512;
    const float* __restrict__ Nt = wsN + (size_t)tc * 128;

    float uu[8], aa[32];
#pragma unroll
    for (int j = 0; j < 8; ++j) uu[j] = u[(size_t)b * (TT * 8) + t * 8 + j];
#pragma unroll
    for (int r = 0; r < 32; ++r) aa[r] = a[(size_t)b * (TT * 32) + t * 32 + r];

    float* __restrict__ og = gvb + (size_t)t * 4096 + b * 16;
#pragma unroll
    for (int i = 0; i < 16; ++i) {
        float s = 0.f;
#pragma unroll
        for (int j = 0; j < 8; ++j) s += Nt[i * 8 + j] * uu[j];
#pragma unroll
        for (int r = 0; r < 32; ++r) s += Kt[i * 32 + r] * aa[r];
        og[i] = s;
    }
}

// ---------------------------------------------------------------------------
// Kernel 3b (primary): mean scan, batch-per-lane. Lane holds one batch's
// full 16-vector in registers: per step 256 in-lane FMAs, ZERO shuffles,
// ZERO LDS. Mc_t wave-uniform via float4 loads (L1-resident: constant for
// t>=WARM). gv prefetched one step ahead.
// ---------------------------------------------------------------------------
__global__ __launch_bounds__(64) void scan_k(
    const float* __restrict__ mean0, const float* __restrict__ wsM,
    const float* __restrict__ gvb, float* __restrict__ out)
{
    const int lane = threadIdx.x;
    const int B = blockIdx.x * 64 + lane;

    float mn[16];
    {
        const float4* mp = (const float4*)(mean0 + B * 16);
        float4 a0 = mp[0], a1 = mp[1], a2 = mp[2], a3 = mp[3];
        mn[0]=a0.x; mn[1]=a0.y; mn[2]=a0.z; mn[3]=a0.w;
        mn[4]=a1.x; mn[5]=a1.y; mn[6]=a1.z; mn[7]=a1.w;
        mn[8]=a2.x; mn[9]=a2.y; mn[10]=a2.z; mn[11]=a2.w;
        mn[12]=a3.x; mn[13]=a3.y; mn[14]=a3.z; mn[15]=a3.w;
    }
    float4 g0, g1, g2, g3;
    {
        const float4* gp = (const float4*)(gvb + B * 16);
        g0 = gp[0]; g1 = gp[1]; g2 = gp[2]; g3 = gp[3];
    }
    float* ob = out + (size_t)B * (TT * 16);

    for (int t = 0; t < TT; ++t) {
        const int tn = (t + 1 < TT) ? t + 1 : t;
        const float4* gp = (const float4*)(gvb + (size_t)tn * 4096 + B * 16);
        float4 n0 = gp[0], n1 = gp[1], n2 = gp[2], n3 = gp[3];

        const float* __restrict__ mc = wsM + (size_t)((t < WARM) ? t : WARM) * 256;
        float gc[16] = {g0.x,g0.y,g0.z,g0.w, g1.x,g1.y,g1.z,g1.w,
                        g2.x,g2.y,g2.z,g2.w, g3.x,g3.y,g3.z,g3.w};
        float nm[16];
#pragma unroll
        for (int i = 0; i < 16; ++i) {
            const float4 m0 = *(const float4*)(mc + i * 16);
            const float4 m1 = *(const float4*)(mc + i * 16 + 4);
            const float4 m2 = *(const float4*)(mc + i * 16 + 8);
            const float4 m3 = *(const float4*)(mc + i * 16 + 12);
            float s = gc[i];
            s += m0.x * mn[0] + m0.y * mn[1] + m0.z * mn[2] + m0.w * mn[3];
            s += m1.x * mn[4] + m1.y * mn[5] + m1.z * mn[6] + m1.w * mn[7];
            s += m2.x * mn[8] + m2.y * mn[9] + m2.z * mn[10] + m2.w * mn[11];
            s += m3.x * mn[12] + m3.y * mn[13] + m3.z * mn[14] + m3.w * mn[15];
            nm[i] = s;
        }
        float4* op = (float4*)(ob + t * 16);
        op[0] = make_float4(nm[0], nm[1], nm[2], nm[3]);
        op[1] = make_float4(nm[4], nm[5], nm[6], nm[7]);
        op[2] = make_float4(nm[8], nm[9], nm[10], nm[11]);
        op[3] = make_float4(nm[12], nm[13], nm[14], nm[15]);
#pragma unroll
        for (int i = 0; i < 16; ++i) mn[i] = nm[i];
        g0 = n0; g1 = n1; g2 = n2; g3 = n3;
    }
}

// ---------------------------------------------------------------------------
// Kernel 3-fallback (verified R6 mean_k, adapted to 17-slot chain via
// min(t,WARM) indexing) — used only if ws_size can't hold the gv chain.
// ---------------------------------------------------------------------------
__global__ __launch_bounds__(64) void meanf_k(
    const float* __restrict__ mean0, const float* __restrict__ u,
    const float* __restrict__ a, const float* __restrict__ wsK,
    const float* __restrict__ wsM, const float* __restrict__ wsN,
    float* __restrict__ out)
{
    const int lane = threadIdx.x;
    const int b = blockIdx.x;
    const int i = lane & 15;
    const int g = lane >> 4;

    const float* ub = u + (size_t)b * TT * 8;
    const float* ab = a + (size_t)b * TT * 32;
    float* ob = out + (size_t)b * TT * 16;

    float mn = mean0[b * 16 + i];

    float Mc[16];
    {
        const float4* p = (const float4*)(wsM + i * 16);
        float4 x0 = p[0], x1 = p[1], x2 = p[2], x3 = p[3];
        Mc[0]=x0.x; Mc[1]=x0.y; Mc[2]=x0.z; Mc[3]=x0.w;
        Mc[4]=x1.x; Mc[5]=x1.y; Mc[6]=x1.z; Mc[7]=x1.w;
        Mc[8]=x2.x; Mc[9]=x2.y; Mc[10]=x2.z; Mc[11]=x2.w;
        Mc[12]=x3.x; Mc[13]=x3.y; Mc[14]=x3.z; Mc[15]=x3.w;
    }
    float gv;
    {
        float4 k0 = *(const float4*)(wsK + i * 32 + 8 * g);
        float4 k1 = *(const float4*)(wsK + i * 32 + 8 * g + 4);
        float4 n0 = *(const float4*)(wsN + i * 8);
        float4 n1 = *(const float4*)(wsN + i * 8 + 4);
        float u0 = ub[lane & 7];
        float a0 = ab[lane & 31];
        float part = k0.x * __shfl(a0, 8*g+0) + k0.y * __shfl(a0, 8*g+1)
                   + k0.z * __shfl(a0, 8*g+2) + k0.w * __shfl(a0, 8*g+3)
                   + k1.x * __shfl(a0, 8*g+4) + k1.y * __shfl(a0, 8*g+5)
                   + k1.z * __shfl(a0, 8*g+6) + k1.w * __shfl(a0, 8*g+7);
        float nbs = n0.x * __shfl(u0,0) + n0.y * __shfl(u0,1)
                  + n0.z * __shfl(u0,2) + n0.w * __shfl(u0,3)
                  + n1.x * __shfl(u0,4) + n1.y * __shfl(u0,5)
                  + n1.z * __shfl(u0,6) + n1.w * __shfl(u0,7);
        part += (g == 3) ? nbs : 0.f;
        part += __shfl_xor(part, 16);
        part += __shfl_xor(part, 32);
        gv = part;
    }
    float4 mA, mB, mC, mD, kp0, kp1, np0, np1;
    float upn, apn;
    {
        const int s1 = (1 < WARM) ? 1 : WARM;
        const float4* p = (const float4*)(wsM + (size_t)s1 * 256 + i * 16);
        mA = p[0]; mB = p[1]; mC = p[2]; mD = p[3];
        kp0 = *(const float4*)(wsK + (size_t)s1 * 512 + i * 32 + 8 * g);
        kp1 = *(const float4*)(wsK + (size_t)s1 * 512 + i * 32 + 8 * g + 4);
        np0 = *(const float4*)(wsN + (size_t)s1 * 128 + i * 8);
        np1 = *(const float4*)(wsN + (size_t)s1 * 128 + i * 8 + 4);
        upn = ub[8 + (lane & 7)];
        apn = ab[32 + (lane & 31)];
    }

    for (int t = 0; t < TT; ++t) {
        const int t2 = (t + 2 < TT) ? t + 2 : TT - 1;
        const int s2 = (t2 < WARM) ? t2 : WARM;
        const float4* mp = (const float4*)(wsM + (size_t)s2 * 256 + i * 16);
        float4 l0 = mp[0], l1 = mp[1], l2 = mp[2], l3 = mp[3];
        float4 kl0 = *(const float4*)(wsK + (size_t)s2 * 512 + i * 32 + 8 * g);
        float4 kl1 = *(const float4*)(wsK + (size_t)s2 * 512 + i * 32 + 8 * g + 4);
        float4 nl0 = *(const float4*)(wsN + (size_t)s2 * 128 + i * 8);
        float4 nl1 = *(const float4*)(wsN + (size_t)s2 * 128 + i * 8 + 4);
        float ul = ub[t2 * 8 + (lane & 7)];
        float al = ab[t2 * 32 + (lane & 31)];

        float s0 = gv, s1 = 0.f, s2f = 0.f, s3 = 0.f;
#pragma unroll
        for (int q = 0; q < 16; q += 4) {
            s0  += Mc[q]     * __shfl(mn, q);
            s1  += Mc[q + 1] * __shfl(mn, q + 1);
            s2f += Mc[q + 2] * __shfl(mn, q + 2);
            s3  += Mc[q + 3] * __shfl(mn, q + 3);
        }
        mn = (s0 + s1) + (s2f + s3);
        if (lane < 16) ob[t * 16 + lane] = mn;

        float part = kp0.x * __shfl(apn, 8*g+0) + kp0.y * __shfl(apn, 8*g+1)
                   + kp0.z * __shfl(apn, 8*g+2) + kp0.w * __shfl(apn, 8*g+3)
                   + kp1.x * __shfl(apn, 8*g+4) + kp1.y * __shfl(apn, 8*g+5)
                   + kp1.z * __shfl(apn, 8*g+6) + kp1.w * __shfl(apn, 8*g+7);
        float nbs = np0.x * __shfl(upn,0) + np0.y * __shfl(upn,1)
                  + np0.z * __shfl(upn,2) + np0.w * __shfl(upn,3)
                  + np1.x * __shfl(upn,4) + np1.y * __shfl(upn,5)
                  + np1.z * __shfl(upn,6) + np1.w * __shfl(upn,7);
        part += (g == 3) ? nbs : 0.f;
        part += __shfl_xor(part, 16);
        part += __shfl_xor(part, 32);
        gv = part;

        Mc[0]=mA.x; Mc[1]=mA.y; Mc[2]=mA.z; Mc[3]=mA.w;
        Mc[4]=mB.x; Mc[5]=mB.y; Mc[6]=mB.z; Mc[7]=mB.w;
        Mc[8]=mC.x; Mc[9]=mC.y; Mc[10]=mC.z; Mc[11]=mC.w;
        Mc[12]=mD.x; Mc[13]=mD.y; Mc[14]=mD.z; Mc[15]=mD.w;
        mA = l0; mB = l1; mC = l2; mD = l3;
        kp0 = kl0; kp1 = kl1; np0 = nl0; np1 = nl1;
        upn = ul; apn = al;
    }
}

extern "C" void kernel_launch(void* const* d_in, const int* in_sizes, int n_in,
                              void* d_out, int out_size, void* d_ws, size_t ws_size,
                              hipStream_t stream) {
    const float* mean0 = nullptr; const float* cov0 = nullptr;
    const float* u = nullptr;     const float* a = nullptr;
    const float* Mm = nullptr;    const float* Nm = nullptr;
    const float* dv = nullptr;    const float* Bm = nullptr;
    const float* Cm = nullptr;    const float* nxp = nullptr;
    const float* nap = nullptr;
    for (int i = 0; i < n_in; ++i) {
        const float* p = (const float*)d_in[i];
        switch (in_sizes[i]) {
            case 256 * 16:        mean0 = p; break;
            case 256 * 256:       cov0 = p; break;
            case 256 * 256 * 8:   u = p; break;
            case 256 * 256 * 32:  a = p; break;
            case 256:             if (!Mm) Mm = p; else Nm = p; break;
            case 16:              if (!dv) dv = p; else nxp = p; break;
            case 128:             Bm = p; break;
            case 512:             Cm = p; break;
            case 32:              nap = p; break;
            default: break;
        }
    }
    float* ws  = (float*)d_ws;
    float* wsK = ws + OFF_K;
    float* wsM = ws + OFF_MC;
    float* wsN = ws + OFF_NB;
    float* gvb = ws + OFF_GV;

    setup_k<<<1, 64, 0, stream>>>(Mm, Nm, dv, Bm, Cm, nxp, nap, ws);
    chain_k<<<WARM + 1, 64, 0, stream>>>(cov0, Bm, ws, wsK, wsM, wsN);
    if (ws_size >= NEED_WS_BYTES) {
        gv_k<<<TT, 256, 0, stream>>>(u, a, wsK, wsN, gvb);
        scan_k<<<4, 64, 0, stream>>>(mean0, wsM, gvb, (float*)d_out);
    } else {
        meanf_k<<<256, 64, 0, stream>>>(mean0, u, a, wsK, wsM, wsN, (float*)d_out);
    }
}

// Round 9
// 249.425 us; speedup vs baseline: 3.3596x; 3.3596x over previous
//
#include <hip/hip_runtime.h>
#include <math.h>

#define TT 256
#define WARM 16        // Riccati restart washout: rho~0.56 => 0.56^16 ~ 1e-4
// ws float offsets
#define OFF_A    0      // A           (256)
#define OFF_NX   256    // Nx diag     (16)
#define OFF_W    512    // W = C^T Na^-1        (16x32 = 512)
#define OFF_E    1024   // E = Nxi A            (256)
#define OFF_H    1280   // H = A^T Nxi A        (256)
#define OFF_F    1536   // F = G + diag(Nxi)    (256)
#define OFF_CA   1792   // CA = C A             (32x16 = 512)
#define OFF_CB   2304   // CB = C B             (32x8  = 256)
#define OFF_K    2560   // K_t chain    (17 x 512)  -> 11264
#define OFF_MC   11264  // Mc_t chain   (17 x 256)  -> 15616
#define OFF_NB   15616  // Nb_t chain   (17 x 128)  -> 17792
#define OFF_P0   17792  // Mseg0 = Mc_15...Mc_0 (256) -> 18048
#define OFF_PP   18048  // Mp = Mc_16^16        (256) -> 18304
#define OFF_WSEG 18304  // w_s per (s,b): 16 x 256 x 16 -> 83840
#define OFF_BND  83840  // boundary mn_{16s}: 16 x 256 x 16 -> 149376
#define OFF_GV   149376 // gv chain: 256 x 256 x 16 = 1048576
#define NEED_WS_BYTES ((size_t)(OFF_GV + TT * 256 * 16) * 4)

__device__ __forceinline__ float softplus(float v) {
    return fmaxf(v, 0.0f) + log1pf(expf(-fabsf(v)));
}

// ---------------------------------------------------------------------------
// Kernel 1 (verified R6/R8): QR(M),QR(N), assemble A; constants into ws.
// ---------------------------------------------------------------------------
__global__ __launch_bounds__(64) void setup_k(
    const float* __restrict__ Mm, const float* __restrict__ Nm,
    const float* __restrict__ dvec, const float* __restrict__ Bm,
    const float* __restrict__ Cm, const float* __restrict__ nx,
    const float* __restrict__ na, float* __restrict__ ws)
{
    __shared__ float qm[16][16], qn[16][16], T0[16][16];
    __shared__ float sC[32][16], sW[16][32], sAm[16][17], sBm[16][9];
    __shared__ float spv[16], d2[16], sNai[32], sNxi[16];
    const int lane = threadIdx.x;

    for (int e = lane; e < 256; e += 64) { qm[e >> 4][e & 15] = Mm[e]; qn[e >> 4][e & 15] = Nm[e]; }
    for (int e = lane; e < 512; e += 64) sC[e >> 4][e & 15] = Cm[e];
    for (int e = lane; e < 128; e += 64) sBm[e >> 3][e & 7] = Bm[e];
    if (lane < 16) {
        float s = softplus(dvec[lane]);
        spv[lane] = sqrtf(s);
        d2[lane] = 1.0f / sqrtf(1.0f + s);
        float nxv = softplus(nx[lane]) + 1e-4f;
        ws[OFF_NX + lane] = nxv;
        sNxi[lane] = 1.0f / nxv;
    }
    if (lane < 32) sNai[lane] = 1.0f / (softplus(na[lane]) + 1e-4f);
    __syncthreads();

    for (int m = 0; m < 2; ++m) {
        float (*Q)[16] = (m == 0) ? qm : qn;
        for (int j = 0; j < 16; ++j) {
            float nrm = 0.f;
#pragma unroll
            for (int r = 0; r < 16; ++r) nrm += Q[r][j] * Q[r][j];
            const float scal = 1.0f / sqrtf(nrm);
            __syncthreads();
            if (lane < 16) Q[lane][j] *= scal;
            __syncthreads();
            if (lane < 16 && lane > j) {
                float pr = 0.f;
#pragma unroll
                for (int r = 0; r < 16; ++r) pr += Q[r][j] * Q[r][lane];
#pragma unroll
                for (int r = 0; r < 16; ++r) Q[r][lane] -= pr * Q[r][j];
            }
            __syncthreads();
        }
    }
    for (int e = lane; e < 256; e += 64) {
        int i = e >> 4, j = e & 15;
        float s = 0.f;
#pragma unroll
        for (int q = 0; q < 16; ++q) s += qm[i][q] * d2[q] * qn[j][q];
        T0[i][j] = spv[i] * s;
    }
    __syncthreads();
    for (int e = lane; e < 256; e += 64) {
        int i = e >> 4, j = e & 15;
        float s = 0.f;
#pragma unroll
        for (int q = 0; q < 16; ++q) s += qn[i][q] * T0[q][j];
        ws[OFF_A + e] = s;
        sAm[i][j] = s;
    }
    for (int e = lane; e < 512; e += 64) {
        int q = e >> 5, r = e & 31;
        float w = sC[r][q] * sNai[r];
        sW[q][r] = w;
        ws[OFF_W + e] = w;
    }
    __syncthreads();
    for (int e = lane; e < 256; e += 64) {
        int i = e >> 4, j = e & 15;
        float g = 0.f;
#pragma unroll
        for (int r = 0; r < 32; ++r) g += sC[r][i] * sW[j][r];
        ws[OFF_F + e] = g + ((i == j) ? sNxi[i] : 0.f);
        ws[OFF_E + e] = sNxi[i] * sAm[i][j];
        float hsum = 0.f;
#pragma unroll
        for (int q = 0; q < 16; ++q) hsum += sAm[q][i] * sNxi[q] * sAm[q][j];
        ws[OFF_H + e] = hsum;
    }
    for (int e = lane; e < 512; e += 64) {
        int r = e >> 4, j = e & 15;
        float s = 0.f;
#pragma unroll
        for (int q = 0; q < 16; ++q) s += sC[r][q] * sAm[q][j];
        ws[OFF_CA + e] = s;
    }
    for (int e = lane; e < 256; e += 64) {
        int r = e >> 3, j = e & 7;
        float s = 0.f;
#pragma unroll
        for (int q = 0; q < 16; ++q) s += sC[r][q] * sBm[q][j];
        ws[OFF_CB + e] = s;
    }
}

// Shuffle-based Gauss-Jordan (verified R5/R6/R8).
__device__ __forceinline__ void gj16(float (&aug)[8], const int i, const int gq) {
#pragma unroll
    for (int j = 0; j < 16; ++j) {
        float prow[8];
#pragma unroll
        for (int k = 0; k < 8; ++k) prow[k] = __shfl(aug[k], j + 16 * gq);
        const float pjj = __shfl(aug[j & 7], j + 16 * (j >> 3));
        const float cij = __shfl(aug[j & 7], i + 16 * (j >> 3));
        const float pivinv = 1.0f / pjj;
        const float f = cij * pivinv;
#pragma unroll
        for (int k = 0; k < 8; ++k)
            aug[k] = (i == j) ? prow[k] * pivinv : aug[k] - f * prow[k];
    }
}

// ---------------------------------------------------------------------------
// Kernel 2 (verified R6/R8): info-form gain chain, WARM=16, grid=17.
// ---------------------------------------------------------------------------
__global__ __launch_bounds__(64) void chain_k(
    const float* __restrict__ cov0, const float* __restrict__ Bm,
    const float* __restrict__ ws, float* __restrict__ wsK,
    float* __restrict__ wsM, float* __restrict__ wsN)
{
    __shared__ float sW[16][33], sP[16][17], sK[16][33];
    __shared__ float sCA[32][17], sCB[32][9];
    const int lane = threadIdx.x;
    const int t = blockIdx.x;            // 0..WARM
    const int nsteps = t + 1;
    const int i = lane & 15, gq = lane >> 4, h = gq & 1;

    float Erow[16], Hr[8], Fr[8];
#pragma unroll
    for (int q = 0; q < 16; ++q) Erow[q] = ws[OFF_E + i * 16 + q];
#pragma unroll
    for (int k = 0; k < 8; ++k) Hr[k] = ws[OFF_H + i * 16 + 8 * h + k];
#pragma unroll
    for (int k = 0; k < 8; ++k) Fr[k] = ws[OFF_F + i * 16 + 8 * h + k];
    for (int e = lane; e < 512; e += 64) sW[e >> 5][e & 31] = ws[OFF_W + e];
    for (int e = lane; e < 512; e += 64) sCA[e >> 4][e & 15] = ws[OFF_CA + e];
    for (int e = lane; e < 256; e += 64) sCB[e >> 3][e & 7] = ws[OFF_CB + e];

    float aug[8];
#pragma unroll
    for (int k = 0; k < 8; ++k)
        aug[k] = (gq < 2) ? cov0[i * 16 + 8 * gq + k]
                          : ((8 * (gq - 2) + k == i) ? 1.f : 0.f);
    gj16(aug, i, gq);
    float L_r[8];
#pragma unroll
    for (int k = 0; k < 8; ++k) L_r[k] = __shfl(aug[k], i + 16 * (2 + h));

    for (int s = 0; s < nsteps; ++s) {
#pragma unroll
        for (int k = 0; k < 8; ++k)
            aug[k] = (gq < 2) ? (L_r[k] + Hr[k])
                              : ((8 * (gq - 2) + k == i) ? 1.f : 0.f);
        gj16(aug, i, gq);
        float T_r[8];
#pragma unroll
        for (int k = 0; k < 8; ++k) T_r[k] = 0.f;
#pragma unroll
        for (int q = 0; q < 16; ++q) {
            const float eq = Erow[q];
#pragma unroll
            for (int k = 0; k < 8; ++k)
                T_r[k] += eq * __shfl(aug[k], q + 16 * (2 + h));
        }
        float Trow[16];
#pragma unroll
        for (int q = 0; q < 16; ++q) Trow[q] = __shfl(T_r[q & 7], i + 16 * (q >> 3));
#pragma unroll
        for (int k = 0; k < 8; ++k) L_r[k] = Fr[k];
#pragma unroll
        for (int q = 0; q < 16; ++q) {
            const float tq = Trow[q];
#pragma unroll
            for (int k = 0; k < 8; ++k) L_r[k] -= tq * __shfl(Erow[q], 8 * h + k);
        }
    }
#pragma unroll
    for (int k = 0; k < 8; ++k)
        aug[k] = (gq < 2) ? L_r[k] : ((8 * (gq - 2) + k == i) ? 1.f : 0.f);
    gj16(aug, i, gq);
    float P_r[8];
#pragma unroll
    for (int k = 0; k < 8; ++k) P_r[k] = __shfl(aug[k], i + 16 * (2 + h));
    if (lane < 32) {
#pragma unroll
        for (int k = 0; k < 8; ++k) sP[i][8 * h + k] = P_r[k];
    }
    __syncthreads();
#pragma unroll
    for (int m = 0; m < 8; ++m) {
        const int e = lane + 64 * m, ii = e >> 5, rr = e & 31;
        float s = 0.f;
#pragma unroll
        for (int q = 0; q < 16; ++q) s += sP[ii][q] * sW[q][rr];
        sK[ii][rr] = s;
        wsK[(size_t)t * 512 + e] = s;
    }
    __syncthreads();
#pragma unroll
    for (int m = 0; m < 4; ++m) {
        const int e = lane + 64 * m, ii = e >> 4, jj = e & 15;
        float s = ws[OFF_A + e];
#pragma unroll
        for (int r = 0; r < 32; ++r) s -= sK[ii][r] * sCA[r][jj];
        wsM[(size_t)t * 256 + e] = s;
    }
#pragma unroll
    for (int m = 0; m < 2; ++m) {
        const int e = lane + 64 * m, ii = e >> 3, jj = e & 7;
        float s = Bm[e];
#pragma unroll
        for (int r = 0; r < 32; ++r) s -= sK[ii][r] * sCB[r][jj];
        wsN[(size_t)t * 128 + e] = s;
    }
}

// ---------------------------------------------------------------------------
// Kernel 3 (verified R8): gv_t(b) = Nb_t u_bt + K_t a_bt, fully parallel.
// ---------------------------------------------------------------------------
__global__ __launch_bounds__(256) void gv_k(
    const float* __restrict__ u, const float* __restrict__ a,
    const float* __restrict__ wsK, const float* __restrict__ wsN,
    float* __restrict__ gvb)
{
    const int t = blockIdx.x;
    const int tc = (t < WARM) ? t : WARM;
    const int b = threadIdx.x;
    const float* __restrict__ Kt = wsK + (size_t)tc * 512;
    const float* __restrict__ Nt = wsN + (size_t)tc * 128;

    float uu[8], aa[32];
#pragma unroll
    for (int j = 0; j < 8; ++j) uu[j] = u[(size_t)b * (TT * 8) + t * 8 + j];
#pragma unroll
    for (int r = 0; r < 32; ++r) aa[r] = a[(size_t)b * (TT * 32) + t * 32 + r];

    float* __restrict__ og = gvb + (size_t)t * 4096 + b * 16;
#pragma unroll
    for (int i = 0; i < 16; ++i) {
        float s = 0.f;
#pragma unroll
        for (int j = 0; j < 8; ++j) s += Nt[i * 8 + j] * uu[j];
#pragma unroll
        for (int r = 0; r < 32; ++r) s += Kt[i * 32 + r] * aa[r];
        og[i] = s;
    }
}

// ---------------------------------------------------------------------------
// Kernel 4: segment-composite matrices. Mseg0 = Mc_15...Mc_1 Mc_0,
// Mp = Mc_16^16 (4 squarings). One block, 256 threads, LDS matmuls.
// ---------------------------------------------------------------------------
__global__ __launch_bounds__(256) void pow_k(
    const float* __restrict__ wsM, float* __restrict__ ws)
{
    __shared__ float Mcur[16][17], Mt[16][17], Mnx[16][17];
    const int tid = threadIdx.x;
    const int i = tid >> 4, j = tid & 15;

    Mcur[i][j] = wsM[tid];                 // Mc_0
    __syncthreads();
    for (int t = 1; t < 16; ++t) {
        Mt[i][j] = wsM[(size_t)t * 256 + tid];
        __syncthreads();
        float s = 0.f;
#pragma unroll
        for (int q = 0; q < 16; ++q) s += Mt[i][q] * Mcur[q][j];
        Mnx[i][j] = s;
        __syncthreads();
        Mcur[i][j] = Mnx[i][j];
        __syncthreads();
    }
    ws[OFF_P0 + tid] = Mcur[i][j];

    Mcur[i][j] = wsM[(size_t)16 * 256 + tid];   // Mc_16
    __syncthreads();
    for (int r = 0; r < 4; ++r) {
        float s = 0.f;
#pragma unroll
        for (int q = 0; q < 16; ++q) s += Mcur[i][q] * Mcur[q][j];
        Mnx[i][j] = s;
        __syncthreads();
        Mcur[i][j] = Mnx[i][j];
        __syncthreads();
    }
    ws[OFF_PP + tid] = Mcur[i][j];
}

// ---------------------------------------------------------------------------
// Kernel 5: phase A — per (segment, batch) wave computes the segment's
// accumulated offset w = sum_j (Mc products) gv, 16 register steps.
// Lanes (g = lane>>4, i = lane&15): state replicated across g; matvec split
// over 4 j-groups + xor-reduce.
// ---------------------------------------------------------------------------
__global__ __launch_bounds__(64) void phA_k(
    const float* __restrict__ wsM, const float* __restrict__ gvb,
    float* __restrict__ wseg)
{
    const int lane = threadIdx.x;
    const int i = lane & 15, g = lane >> 4;
    const int seg = blockIdx.x >> 8;
    const int b = blockIdx.x & 255;

    float mcs[16][4];
#pragma unroll
    for (int j = 0; j < 16; ++j) {
        const int tc = (seg == 0) ? j : 16;
        const float4 v = *(const float4*)(wsM + (size_t)tc * 256 + i * 16 + 4 * g);
        mcs[j][0] = v.x; mcs[j][1] = v.y; mcs[j][2] = v.z; mcs[j][3] = v.w;
    }
    float gvs[16];
#pragma unroll
    for (int j = 0; j < 16; ++j)
        gvs[j] = gvb[(size_t)(16 * seg + j) * 4096 + b * 16 + i];

    float w = 0.f;
#pragma unroll
    for (int j = 0; j < 16; ++j) {
        float part = mcs[j][0] * __shfl(w, 4 * g + 0)
                   + mcs[j][1] * __shfl(w, 4 * g + 1)
                   + mcs[j][2] * __shfl(w, 4 * g + 2)
                   + mcs[j][3] * __shfl(w, 4 * g + 3);
        part += __shfl_xor(part, 16);
        part += __shfl_xor(part, 32);
        w = part + gvs[j];
    }
    if (lane < 16) wseg[(size_t)seg * 4096 + b * 16 + i] = w;
}

// ---------------------------------------------------------------------------
// Kernel 6: phase B — boundary recursion over 16 segments (serial), batches
// fully parallel (one wave per batch). mn_{s+1} = M_seg(s) mn_s + w_s.
// ---------------------------------------------------------------------------
__global__ __launch_bounds__(64) void phB_k(
    const float* __restrict__ mean0, const float* __restrict__ ws,
    const float* __restrict__ wseg, float* __restrict__ bnd)
{
    const int lane = threadIdx.x;
    const int i = lane & 15, g = lane >> 4;
    const int b = blockIdx.x;

    const float4 v0 = *(const float4*)(ws + OFF_P0 + i * 16 + 4 * g);
    const float4 vp = *(const float4*)(ws + OFF_PP + i * 16 + 4 * g);
    const float m0s[4] = {v0.x, v0.y, v0.z, v0.w};
    const float mps[4] = {vp.x, vp.y, vp.z, vp.w};
    float wv[16];
#pragma unroll
    for (int s = 0; s < 16; ++s) wv[s] = wseg[(size_t)s * 4096 + b * 16 + i];

    float mn = mean0[b * 16 + i];
#pragma unroll
    for (int s = 0; s < 16; ++s) {
        if (lane < 16) bnd[(size_t)s * 4096 + b * 16 + i] = mn;
        const float c0 = (s == 0) ? m0s[0] : mps[0];
        const float c1 = (s == 0) ? m0s[1] : mps[1];
        const float c2 = (s == 0) ? m0s[2] : mps[2];
        const float c3 = (s == 0) ? m0s[3] : mps[3];
        float part = c0 * __shfl(mn, 4 * g + 0)
                   + c1 * __shfl(mn, 4 * g + 1)
                   + c2 * __shfl(mn, 4 * g + 2)
                   + c3 * __shfl(mn, 4 * g + 3);
        part += __shfl_xor(part, 16);
        part += __shfl_xor(part, 32);
        mn = part + wv[s];
    }
}

// ---------------------------------------------------------------------------
// Kernel 7: phase C — regenerate interior means from the segment boundary,
// emit outputs. Same wave layout as phase A.
// ---------------------------------------------------------------------------
__global__ __launch_bounds__(64) void phC_k(
    const float* __restrict__ wsM, const float* __restrict__ gvb,
    const float* __restrict__ bnd, float* __restrict__ out)
{
    const int lane = threadIdx.x;
    const int i = lane & 15, g = lane >> 4;
    const int seg = blockIdx.x >> 8;
    const int b = blockIdx.x & 255;

    float mcs[16][4];
#pragma unroll
    for (int j = 0; j < 16; ++j) {
        const int tc = (seg == 0) ? j : 16;
        const float4 v = *(const float4*)(wsM + (size_t)tc * 256 + i * 16 + 4 * g);
        mcs[j][0] = v.x; mcs[j][1] = v.y; mcs[j][2] = v.z; mcs[j][3] = v.w;
    }
    float gvs[16];
#pragma unroll
    for (int j = 0; j < 16; ++j)
        gvs[j] = gvb[(size_t)(16 * seg + j) * 4096 + b * 16 + i];

    float mn = bnd[(size_t)seg * 4096 + b * 16 + i];
    float* ob = out + (size_t)b * 4096 + (size_t)(16 * seg) * 16;
#pragma unroll
    for (int j = 0; j < 16; ++j) {
        float part = mcs[j][0] * __shfl(mn, 4 * g + 0)
                   + mcs[j][1] * __shfl(mn, 4 * g + 1)
                   + mcs[j][2] * __shfl(mn, 4 * g + 2)
                   + mcs[j][3] * __shfl(mn, 4 * g + 3);
        part += __shfl_xor(part, 16);
        part += __shfl_xor(part, 32);
        mn = part + gvs[j];
        if (lane < 16) ob[j * 16 + i] = mn;
    }
}

// ---------------------------------------------------------------------------
// Fallback (verified R6/R8): serial mean pass, used only if ws too small.
// ---------------------------------------------------------------------------
__global__ __launch_bounds__(64) void meanf_k(
    const float* __restrict__ mean0, const float* __restrict__ u,
    const float* __restrict__ a, const float* __restrict__ wsK,
    const float* __restrict__ wsM, const float* __restrict__ wsN,
    float* __restrict__ out)
{
    const int lane = threadIdx.x;
    const int b = blockIdx.x;
    const int i = lane & 15;
    const int g = lane >> 4;

    const float* ub = u + (size_t)b * TT * 8;
    const float* ab = a + (size_t)b * TT * 32;
    float* ob = out + (size_t)b * TT * 16;

    float mn = mean0[b * 16 + i];

    float Mc[16];
    {
        const float4* p = (const float4*)(wsM + i * 16);
        float4 x0 = p[0], x1 = p[1], x2 = p[2], x3 = p[3];
        Mc[0]=x0.x; Mc[1]=x0.y; Mc[2]=x0.z; Mc[3]=x0.w;
        Mc[4]=x1.x; Mc[5]=x1.y; Mc[6]=x1.z; Mc[7]=x1.w;
        Mc[8]=x2.x; Mc[9]=x2.y; Mc[10]=x2.z; Mc[11]=x2.w;
        Mc[12]=x3.x; Mc[13]=x3.y; Mc[14]=x3.z; Mc[15]=x3.w;
    }
    float gv;
    {
        float4 k0 = *(const float4*)(wsK + i * 32 + 8 * g);
        float4 k1 = *(const float4*)(wsK + i * 32 + 8 * g + 4);
        float4 n0 = *(const float4*)(wsN + i * 8);
        float4 n1 = *(const float4*)(wsN + i * 8 + 4);
        float u0 = ub[lane & 7];
        float a0 = ab[lane & 31];
        float part = k0.x * __shfl(a0, 8*g+0) + k0.y * __shfl(a0, 8*g+1)
                   + k0.z * __shfl(a0, 8*g+2) + k0.w * __shfl(a0, 8*g+3)
                   + k1.x * __shfl(a0, 8*g+4) + k1.y * __shfl(a0, 8*g+5)
                   + k1.z * __shfl(a0, 8*g+6) + k1.w * __shfl(a0, 8*g+7);
        float nbs = n0.x * __shfl(u0,0) + n0.y * __shfl(u0,1)
                  + n0.z * __shfl(u0,2) + n0.w * __shfl(u0,3)
                  + n1.x * __shfl(u0,4) + n1.y * __shfl(u0,5)
                  + n1.z * __shfl(u0,6) + n1.w * __shfl(u0,7);
        part += (g == 3) ? nbs : 0.f;
        part += __shfl_xor(part, 16);
        part += __shfl_xor(part, 32);
        gv = part;
    }
    float4 mA, mB, mC, mD, kp0, kp1, np0, np1;
    float upn, apn;
    {
        const float4* p = (const float4*)(wsM + (size_t)1 * 256 + i * 16);
        mA = p[0]; mB = p[1]; mC = p[2]; mD = p[3];
        kp0 = *(const float4*)(wsK + (size_t)1 * 512 + i * 32 + 8 * g);
        kp1 = *(const float4*)(wsK + (size_t)1 * 512 + i * 32 + 8 * g + 4);
        np0 = *(const float4*)(wsN + (size_t)1 * 128 + i * 8);
        np1 = *(const float4*)(wsN + (size_t)1 * 128 + i * 8 + 4);
        upn = ub[8 + (lane & 7)];
        apn = ab[32 + (lane & 31)];
    }

    for (int t = 0; t < TT; ++t) {
        const int t2 = (t + 2 < TT) ? t + 2 : TT - 1;
        const int s2 = (t2 < WARM) ? t2 : WARM;
        const float4* mp = (const float4*)(wsM + (size_t)s2 * 256 + i * 16);
        float4 l0 = mp[0], l1 = mp[1], l2 = mp[2], l3 = mp[3];
        float4 kl0 = *(const float4*)(wsK + (size_t)s2 * 512 + i * 32 + 8 * g);
        float4 kl1 = *(const float4*)(wsK + (size_t)s2 * 512 + i * 32 + 8 * g + 4);
        float4 nl0 = *(const float4*)(wsN + (size_t)s2 * 128 + i * 8);
        float4 nl1 = *(const float4*)(wsN + (size_t)s2 * 128 + i * 8 + 4);
        float ul = ub[t2 * 8 + (lane & 7)];
        float al = ab[t2 * 32 + (lane & 31)];

        float s0 = gv, s1 = 0.f, s2f = 0.f, s3 = 0.f;
#pragma unroll
        for (int q = 0; q < 16; q += 4) {
            s0  += Mc[q]     * __shfl(mn, q);
            s1  += Mc[q + 1] * __shfl(mn, q + 1);
            s2f += Mc[q + 2] * __shfl(mn, q + 2);
            s3  += Mc[q + 3] * __shfl(mn, q + 3);
        }
        mn = (s0 + s1) + (s2f + s3);
        if (lane < 16) ob[t * 16 + lane] = mn;

        float part = kp0.x * __shfl(apn, 8*g+0) + kp0.y * __shfl(apn, 8*g+1)
                   + kp0.z * __shfl(apn, 8*g+2) + kp0.w * __shfl(apn, 8*g+3)
                   + kp1.x * __shfl(apn, 8*g+4) + kp1.y * __shfl(apn, 8*g+5)
                   + kp1.z * __shfl(apn, 8*g+6) + kp1.w * __shfl(apn, 8*g+7);
        float nbs = np0.x * __shfl(upn,0) + np0.y * __shfl(upn,1)
                  + np0.z * __shfl(upn,2) + np0.w * __shfl(upn,3)
                  + np1.x * __shfl(upn,4) + np1.y * __shfl(upn,5)
                  + np1.z * __shfl(upn,6) + np1.w * __shfl(upn,7);
        part += (g == 3) ? nbs : 0.f;
        part += __shfl_xor(part, 16);
        part += __shfl_xor(part, 32);
        gv = part;

        Mc[0]=mA.x; Mc[1]=mA.y; Mc[2]=mA.z; Mc[3]=mA.w;
        Mc[4]=mB.x; Mc[5]=mB.y; Mc[6]=mB.z; Mc[7]=mB.w;
        Mc[8]=mC.x; Mc[9]=mC.y; Mc[10]=mC.z; Mc[11]=mC.w;
        Mc[12]=mD.x; Mc[13]=mD.y; Mc[14]=mD.z; Mc[15]=mD.w;
        mA = l0; mB = l1; mC = l2; mD = l3;
        kp0 = kl0; kp1 = kl1; np0 = nl0; np1 = nl1;
        upn = ul; apn = al;
    }
}

extern "C" void kernel_launch(void* const* d_in, const int* in_sizes, int n_in,
                              void* d_out, int out_size, void* d_ws, size_t ws_size,
                              hipStream_t stream) {
    const float* mean0 = nullptr; const float* cov0 = nullptr;
    const float* u = nullptr;     const float* a = nullptr;
    const float* Mm = nullptr;    const float* Nm = nullptr;
    const float* dv = nullptr;    const float* Bm = nullptr;
    const float* Cm = nullptr;    const float* nxp = nullptr;
    const float* nap = nullptr;
    for (int i = 0; i < n_in; ++i) {
        const float* p = (const float*)d_in[i];
        switch (in_sizes[i]) {
            case 256 * 16:        mean0 = p; break;
            case 256 * 256:       cov0 = p; break;
            case 256 * 256 * 8:   u = p; break;
            case 256 * 256 * 32:  a = p; break;
            case 256:             if (!Mm) Mm = p; else Nm = p; break;
            case 16:              if (!dv) dv = p; else nxp = p; break;
            case 128:             Bm = p; break;
            case 512:             Cm = p; break;
            case 32:              nap = p; break;
            default: break;
        }
    }
    float* ws   = (float*)d_ws;
    float* wsK  = ws + OFF_K;
    float* wsM  = ws + OFF_MC;
    float* wsN  = ws + OFF_NB;
    float* wseg = ws + OFF_WSEG;
    float* bnd  = ws + OFF_BND;
    float* gvb  = ws + OFF_GV;

    setup_k<<<1, 64, 0, stream>>>(Mm, Nm, dv, Bm, Cm, nxp, nap, ws);
    chain_k<<<WARM + 1, 64, 0, stream>>>(cov0, Bm, ws, wsK, wsM, wsN);
    if (ws_size >= NEED_WS_BYTES) {
        pow_k<<<1, 256, 0, stream>>>(wsM, ws);
        gv_k<<<TT, 256, 0, stream>>>(u, a, wsK, wsN, gvb);
        phA_k<<<16 * 256, 64, 0, stream>>>(wsM, gvb, wseg);
        phB_k<<<256, 64, 0, stream>>>(mean0, ws, wseg, bnd);
        phC_k<<<16 * 256, 64, 0, stream>>>(wsM, gvb, bnd, (float*)d_out);
    } else {
        meanf_k<<<256, 64, 0, stream>>>(mean0, u, a, wsK, wsM, wsN, (float*)d_out);
    }
}

// Round 10
// 235.415 us; speedup vs baseline: 3.5596x; 1.0595x over previous
//
#include <hip/hip_runtime.h>
#include <math.h>

#define TT 256
#define WARM 16
// ws float offsets
#define OFF_A    0      // A (256)
#define OFF_W    512    // W = C^T Na^-1 (16x32 = 512)
#define OFF_CA   1024   // CA = C A (512)
#define OFF_CB   1536   // CB = C B (256)
#define OFF_MAPS 1792   // 5 maps x {E(256),F(256),H(256)} = 3840 -> 5632
#define OFF_K    5632   // 17 x 512 -> 14336
#define OFF_MC   14336  // 17 x 256 -> 18688
#define OFF_NB   18688  // 17 x 128 -> 20864
#define OFF_P0   20864  // Mseg0 (256) -> 21120
#define OFF_PP   21120  // Mc16^16 (256) -> 21376
#define OFF_WSEG 21376  // 16 x 256 x 16 -> 86912
#define OFF_BND  86912  // 16 x 256 x 16 -> 152448
#define NEED_WS_BYTES ((size_t)152448 * 4)

__device__ __forceinline__ float softplus(float v) {
    return fmaxf(v, 0.0f) + log1pf(expf(-fabsf(v)));
}

// Shuffle-based Gauss-Jordan, [X|I] -> [I|X^-1] (verified R5-R9).
// Layout: lane (i=l&15, gq=l>>4) holds aug[i][8*gq+k], k=0..7.
__device__ __forceinline__ void gj16(float (&aug)[8], const int i, const int gq) {
#pragma unroll
    for (int j = 0; j < 16; ++j) {
        float prow[8];
#pragma unroll
        for (int k = 0; k < 8; ++k) prow[k] = __shfl(aug[k], j + 16 * gq);
        const float pjj = __shfl(aug[j & 7], j + 16 * (j >> 3));
        const float cij = __shfl(aug[j & 7], i + 16 * (j >> 3));
        const float pivinv = 1.0f / pjj;
        const float f = cij * pivinv;
#pragma unroll
        for (int k = 0; k < 8; ++k)
            aug[k] = (i == j) ? prow[k] * pivinv : aug[k] - f * prow[k];
    }
}

// ---------------------------------------------------------------------------
// Kernel 1: QR(M),QR(N) (verified MGS), assemble A; constants; then build
// the 1/2/4/8/16-step Riccati maps by Woodbury doubling:
//   V=F+H, Z=V^-1:  F'=F-EZE^T,  E'=EZE,  H'=H-E^T Z E.
// ---------------------------------------------------------------------------
__global__ __launch_bounds__(64) void setup_k(
    const float* __restrict__ Mm, const float* __restrict__ Nm,
    const float* __restrict__ dvec, const float* __restrict__ Bm,
    const float* __restrict__ Cm, const float* __restrict__ nx,
    const float* __restrict__ na, float* __restrict__ ws)
{
    __shared__ float qm[16][16], qn[16][16], T0[16][16];
    __shared__ float sC[32][16], sW[16][32], sAm[16][17], sBm[16][9];
    __shared__ float sE[16][17], sF[16][17], sH[16][17], sScr[16][17];
    __shared__ float spv[16], d2[16], sNai[32], sNxi[16];
    const int lane = threadIdx.x;
    const int i = lane & 15, gq = lane >> 4, h = gq & 1;

    for (int e = lane; e < 256; e += 64) { qm[e >> 4][e & 15] = Mm[e]; qn[e >> 4][e & 15] = Nm[e]; }
    for (int e = lane; e < 512; e += 64) sC[e >> 4][e & 15] = Cm[e];
    for (int e = lane; e < 128; e += 64) sBm[e >> 3][e & 7] = Bm[e];
    if (lane < 16) {
        float s = softplus(dvec[lane]);
        spv[lane] = sqrtf(s);
        d2[lane] = 1.0f / sqrtf(1.0f + s);
        sNxi[lane] = 1.0f / (softplus(nx[lane]) + 1e-4f);
    }
    if (lane < 32) sNai[lane] = 1.0f / (softplus(na[lane]) + 1e-4f);
    __syncthreads();

    // MGS QR (verified): positive col norms => sign-fixed factors
    for (int m = 0; m < 2; ++m) {
        float (*Q)[16] = (m == 0) ? qm : qn;
        for (int j = 0; j < 16; ++j) {
            float nrm = 0.f;
#pragma unroll
            for (int r = 0; r < 16; ++r) nrm += Q[r][j] * Q[r][j];
            const float scal = 1.0f / sqrtf(nrm);
            __syncthreads();
            if (lane < 16) Q[lane][j] *= scal;
            __syncthreads();
            if (lane < 16 && lane > j) {
                float pr = 0.f;
#pragma unroll
                for (int r = 0; r < 16; ++r) pr += Q[r][j] * Q[r][lane];
#pragma unroll
                for (int r = 0; r < 16; ++r) Q[r][lane] -= pr * Q[r][j];
            }
            __syncthreads();
        }
    }
    // A = Uq * (D1 Q D2 Uq^T)
    for (int e = lane; e < 256; e += 64) {
        int ii = e >> 4, j = e & 15;
        float s = 0.f;
#pragma unroll
        for (int q = 0; q < 16; ++q) s += qm[ii][q] * d2[q] * qn[j][q];
        T0[ii][j] = spv[ii] * s;
    }
    __syncthreads();
    for (int e = lane; e < 256; e += 64) {
        int ii = e >> 4, j = e & 15;
        float s = 0.f;
#pragma unroll
        for (int q = 0; q < 16; ++q) s += qn[ii][q] * T0[q][j];
        ws[OFF_A + e] = s;
        sAm[ii][j] = s;
    }
    for (int e = lane; e < 512; e += 64) {
        int q = e >> 5, r = e & 31;
        float w = sC[r][q] * sNai[r];
        sW[q][r] = w;
        ws[OFF_W + e] = w;
    }
    __syncthreads();
    // base map: E = Nxi A, H = A^T Nxi A, F = G + diag(Nxi)
    for (int e = lane; e < 256; e += 64) {
        int ii = e >> 4, j = e & 15;
        float g = 0.f;
#pragma unroll
        for (int r = 0; r < 32; ++r) g += sC[r][ii] * sW[j][r];
        sF[ii][j] = g + ((ii == j) ? sNxi[ii] : 0.f);
        sE[ii][j] = sNxi[ii] * sAm[ii][j];
        float hsum = 0.f;
#pragma unroll
        for (int q = 0; q < 16; ++q) hsum += sAm[q][ii] * sNxi[q] * sAm[q][j];
        sH[ii][j] = hsum;
    }
    for (int e = lane; e < 512; e += 64) {
        int r = e >> 4, j = e & 15;
        float s = 0.f;
#pragma unroll
        for (int q = 0; q < 16; ++q) s += sC[r][q] * sAm[q][j];
        ws[OFF_CA + e] = s;
    }
    for (int e = lane; e < 256; e += 64) {
        int r = e >> 3, j = e & 7;
        float s = 0.f;
#pragma unroll
        for (int q = 0; q < 16; ++q) s += sC[r][q] * sBm[q][j];
        ws[OFF_CB + e] = s;
    }
    __syncthreads();

    // registers for doubling: Erow = E[i][:], ETrow = E[:][i], Fr/Hr mirrored
    float Erow[16], ETrow[16], Fr[8], Hr[8];
#pragma unroll
    for (int q = 0; q < 16; ++q) { Erow[q] = sE[i][q]; ETrow[q] = sE[q][i]; }
#pragma unroll
    for (int k = 0; k < 8; ++k) { Fr[k] = sF[i][8 * h + k]; Hr[k] = sH[i][8 * h + k]; }

    // write map 0
    if (gq == 0) {
#pragma unroll
        for (int q = 0; q < 16; ++q) ws[OFF_MAPS + i * 16 + q] = Erow[q];
    }
    if (gq < 2) {
#pragma unroll
        for (int k = 0; k < 8; ++k) {
            ws[OFF_MAPS + 256 + i * 16 + 8 * h + k] = Fr[k];
            ws[OFF_MAPS + 512 + i * 16 + 8 * h + k] = Hr[k];
        }
    }

    // 4 doublings -> maps for 2,4,8,16 steps
    for (int m = 1; m <= 4; ++m) {
        // Z = (F+H)^-1
        float aug[8];
#pragma unroll
        for (int k = 0; k < 8; ++k)
            aug[k] = (gq < 2) ? (Fr[k] + Hr[k]) : ((8 * (gq - 2) + k == i) ? 1.f : 0.f);
        gj16(aug, i, gq);
        float Z_r[8];
#pragma unroll
        for (int k = 0; k < 8; ++k) Z_r[k] = __shfl(aug[k], i + 16 * (2 + h));
        // T = E Z (mirrored), Trow
        float T_r[8];
#pragma unroll
        for (int k = 0; k < 8; ++k) T_r[k] = 0.f;
#pragma unroll
        for (int q = 0; q < 16; ++q) {
            const float eq = Erow[q];
#pragma unroll
            for (int k = 0; k < 8; ++k) T_r[k] += eq * __shfl(Z_r[k], q + 16 * h);
        }
        float Trow[16];
#pragma unroll
        for (int q = 0; q < 16; ++q) Trow[q] = __shfl(T_r[q & 7], i + 16 * (q >> 3));
        // T2 = E^T Z (mirrored), T2row
        float T2_r[8];
#pragma unroll
        for (int k = 0; k < 8; ++k) T2_r[k] = 0.f;
#pragma unroll
        for (int q = 0; q < 16; ++q) {
            const float eq = ETrow[q];
#pragma unroll
            for (int k = 0; k < 8; ++k) T2_r[k] += eq * __shfl(Z_r[k], q + 16 * h);
        }
        float T2row[16];
#pragma unroll
        for (int q = 0; q < 16; ++q) T2row[q] = __shfl(T2_r[q & 7], i + 16 * (q >> 3));
        // F' = F - T E^T ; H' = H - T2 E ; E' = T E   (mirrored)
        float F2r[8], H2r[8], E2r[8];
#pragma unroll
        for (int k = 0; k < 8; ++k) { F2r[k] = Fr[k]; H2r[k] = Hr[k]; E2r[k] = 0.f; }
#pragma unroll
        for (int q = 0; q < 16; ++q) {
            const float tq = Trow[q], t2q = T2row[q];
#pragma unroll
            for (int k = 0; k < 8; ++k) {
                const float ecol = __shfl(Erow[q], 8 * h + k);    // E[8h+k][q]
                const float etcol = __shfl(ETrow[q], 8 * h + k);  // E[q][8h+k]
                F2r[k] -= tq * ecol;
                H2r[k] -= t2q * etcol;
                E2r[k] += tq * etcol;
            }
        }
        // round-trip E' through LDS to rebuild Erow/ETrow
        __syncthreads();
        if (gq < 2) {
#pragma unroll
            for (int k = 0; k < 8; ++k) sScr[i][8 * h + k] = E2r[k];
        }
        __syncthreads();
#pragma unroll
        for (int q = 0; q < 16; ++q) { Erow[q] = sScr[i][q]; ETrow[q] = sScr[q][i]; }
#pragma unroll
        for (int k = 0; k < 8; ++k) { Fr[k] = F2r[k]; Hr[k] = H2r[k]; }
        // store map m
        const int base = OFF_MAPS + m * 768;
        if (gq == 0) {
#pragma unroll
            for (int q = 0; q < 16; ++q) ws[base + i * 16 + q] = Erow[q];
        }
        if (gq < 2) {
#pragma unroll
            for (int k = 0; k < 8; ++k) {
                ws[base + 256 + i * 16 + 8 * h + k] = Fr[k];
                ws[base + 512 + i * 16 + 8 * h + k] = Hr[k];
            }
        }
    }
}

// ---------------------------------------------------------------------------
// Kernel 2: gain chain via binary map decomposition. Block t applies maps
// {16,8,4,2,1} per bits of n=t+1 (powers of the same map commute), then
// P = L^-1, K = P W, Mc = A - K CA, Nb = B - K CB (verified epilogue).
// ---------------------------------------------------------------------------
__global__ __launch_bounds__(64) void chain_k(
    const float* __restrict__ cov0, const float* __restrict__ Bm,
    const float* __restrict__ ws, float* __restrict__ wsK,
    float* __restrict__ wsM, float* __restrict__ wsN)
{
    __shared__ float sW[16][33], sP[16][17], sK[16][33];
    __shared__ float sCA[32][17], sCB[32][9];
    const int lane = threadIdx.x;
    const int t = blockIdx.x;            // 0..16
    const int n = t + 1;                 // 1..17 applications of the base map
    const int i = lane & 15, gq = lane >> 4, h = gq & 1;

    for (int e = lane; e < 512; e += 64) sW[e >> 5][e & 31] = ws[OFF_W + e];
    for (int e = lane; e < 512; e += 64) sCA[e >> 4][e & 15] = ws[OFF_CA + e];
    for (int e = lane; e < 256; e += 64) sCB[e >> 3][e & 7] = ws[OFF_CB + e];

    // L0 = inv(cov0)
    float aug[8];
#pragma unroll
    for (int k = 0; k < 8; ++k)
        aug[k] = (gq < 2) ? cov0[i * 16 + 8 * gq + k]
                          : ((8 * (gq - 2) + k == i) ? 1.f : 0.f);
    gj16(aug, i, gq);
    float L_r[8];
#pragma unroll
    for (int k = 0; k < 8; ++k) L_r[k] = __shfl(aug[k], i + 16 * (2 + h));

    for (int m = 4; m >= 0; --m) {
        if (!(n & (1 << m))) continue;
        const int base = OFF_MAPS + m * 768;
        float Er[16], Fr[8], Hr[8];
#pragma unroll
        for (int q = 0; q < 16; ++q) Er[q] = ws[base + i * 16 + q];
#pragma unroll
        for (int k = 0; k < 8; ++k) {
            Fr[k] = ws[base + 256 + i * 16 + 8 * h + k];
            Hr[k] = ws[base + 512 + i * 16 + 8 * h + k];
        }
        // L' = F - E (L+H)^-1 E^T
#pragma unroll
        for (int k = 0; k < 8; ++k)
            aug[k] = (gq < 2) ? (L_r[k] + Hr[k]) : ((8 * (gq - 2) + k == i) ? 1.f : 0.f);
        gj16(aug, i, gq);
        float T_r[8];
#pragma unroll
        for (int k = 0; k < 8; ++k) T_r[k] = 0.f;
#pragma unroll
        for (int q = 0; q < 16; ++q) {
            const float eq = Er[q];
#pragma unroll
            for (int k = 0; k < 8; ++k) T_r[k] += eq * __shfl(aug[k], q + 16 * (2 + h));
        }
        float Trow[16];
#pragma unroll
        for (int q = 0; q < 16; ++q) Trow[q] = __shfl(T_r[q & 7], i + 16 * (q >> 3));
#pragma unroll
        for (int k = 0; k < 8; ++k) L_r[k] = Fr[k];
#pragma unroll
        for (int q = 0; q < 16; ++q) {
            const float tq = Trow[q];
#pragma unroll
            for (int k = 0; k < 8; ++k) L_r[k] -= tq * __shfl(Er[q], 8 * h + k);
        }
    }
    // P = L^-1
#pragma unroll
    for (int k = 0; k < 8; ++k)
        aug[k] = (gq < 2) ? L_r[k] : ((8 * (gq - 2) + k == i) ? 1.f : 0.f);
    gj16(aug, i, gq);
    float P_r[8];
#pragma unroll
    for (int k = 0; k < 8; ++k) P_r[k] = __shfl(aug[k], i + 16 * (2 + h));
    if (lane < 32) {
#pragma unroll
        for (int k = 0; k < 8; ++k) sP[i][8 * h + k] = P_r[k];
    }
    __syncthreads();
#pragma unroll
    for (int m = 0; m < 8; ++m) {
        const int e = lane + 64 * m, ii = e >> 5, rr = e & 31;
        float s = 0.f;
#pragma unroll
        for (int q = 0; q < 16; ++q) s += sP[ii][q] * sW[q][rr];
        sK[ii][rr] = s;
        wsK[(size_t)t * 512 + e] = s;
    }
    __syncthreads();
#pragma unroll
    for (int m = 0; m < 4; ++m) {
        const int e = lane + 64 * m, ii = e >> 4, jj = e & 15;
        float s = ws[OFF_A + e];
#pragma unroll
        for (int r = 0; r < 32; ++r) s -= sK[ii][r] * sCA[r][jj];
        wsM[(size_t)t * 256 + e] = s;
    }
#pragma unroll
    for (int m = 0; m < 2; ++m) {
        const int e = lane + 64 * m, ii = e >> 3, jj = e & 7;
        float s = Bm[e];
#pragma unroll
        for (int r = 0; r < 32; ++r) s -= sK[ii][r] * sCB[r][jj];
        wsN[(size_t)t * 128 + e] = s;
    }
}

// ---------------------------------------------------------------------------
// Kernel 3: phase A — per (segment, batch) wave: w = sum_j prod(Mc) gv,
// gv computed INLINE (gv = Nb u + K a). Blocks 0 and 256 also emit the
// segment-product matrices P0 = Mc15..Mc0 and PP = Mc16^16 for phase B.
// ---------------------------------------------------------------------------
__global__ __launch_bounds__(64) void phA_k(
    const float* __restrict__ u, const float* __restrict__ a,
    const float* __restrict__ ws, const float* __restrict__ wsK,
    const float* __restrict__ wsM, const float* __restrict__ wsN,
    float* __restrict__ wseg, float* __restrict__ wsp)
{
    const int lane = threadIdx.x;
    const int i = lane & 15, g = lane >> 4;
    const int seg = blockIdx.x >> 8;
    const int b = blockIdx.x & 255;

    float mcs[16][4];
#pragma unroll
    for (int j = 0; j < 16; ++j) {
        const int tc = (seg == 0) ? j : 16;
        const float4 v = *(const float4*)(wsM + (size_t)tc * 256 + i * 16 + 4 * g);
        mcs[j][0] = v.x; mcs[j][1] = v.y; mcs[j][2] = v.z; mcs[j][3] = v.w;
    }
    float kc[8], nbc[8];
    if (seg != 0) {
        const float4 k0 = *(const float4*)(wsK + (size_t)16 * 512 + i * 32 + 8 * g);
        const float4 k1 = *(const float4*)(wsK + (size_t)16 * 512 + i * 32 + 8 * g + 4);
        const float4 n0 = *(const float4*)(wsN + (size_t)16 * 128 + i * 8);
        const float4 n1 = *(const float4*)(wsN + (size_t)16 * 128 + i * 8 + 4);
        kc[0]=k0.x; kc[1]=k0.y; kc[2]=k0.z; kc[3]=k0.w;
        kc[4]=k1.x; kc[5]=k1.y; kc[6]=k1.z; kc[7]=k1.w;
        nbc[0]=n0.x; nbc[1]=n0.y; nbc[2]=n0.z; nbc[3]=n0.w;
        nbc[4]=n1.x; nbc[5]=n1.y; nbc[6]=n1.z; nbc[7]=n1.w;
    }

    float w = 0.f;
#pragma unroll
    for (int j = 0; j < 16; ++j) {
        const int t = 16 * seg + j;
        float kr[8], nbr[8];
        if (seg == 0) {
            const float4 k0 = *(const float4*)(wsK + (size_t)j * 512 + i * 32 + 8 * g);
            const float4 k1 = *(const float4*)(wsK + (size_t)j * 512 + i * 32 + 8 * g + 4);
            const float4 n0 = *(const float4*)(wsN + (size_t)j * 128 + i * 8);
            const float4 n1 = *(const float4*)(wsN + (size_t)j * 128 + i * 8 + 4);
            kr[0]=k0.x; kr[1]=k0.y; kr[2]=k0.z; kr[3]=k0.w;
            kr[4]=k1.x; kr[5]=k1.y; kr[6]=k1.z; kr[7]=k1.w;
            nbr[0]=n0.x; nbr[1]=n0.y; nbr[2]=n0.z; nbr[3]=n0.w;
            nbr[4]=n1.x; nbr[5]=n1.y; nbr[6]=n1.z; nbr[7]=n1.w;
        } else {
#pragma unroll
            for (int k = 0; k < 8; ++k) { kr[k] = kc[k]; nbr[k] = nbc[k]; }
        }
        const float a0 = a[(size_t)b * (TT * 32) + t * 32 + (lane & 31)];
        const float u0 = u[(size_t)b * (TT * 8) + t * 8 + (lane & 7)];
        // gv[i] = Nb[i][:] u + K[i][:] a   (partial over r in [8g,8g+8))
        float gvp = kr[0] * __shfl(a0, 8*g+0) + kr[1] * __shfl(a0, 8*g+1)
                  + kr[2] * __shfl(a0, 8*g+2) + kr[3] * __shfl(a0, 8*g+3)
                  + kr[4] * __shfl(a0, 8*g+4) + kr[5] * __shfl(a0, 8*g+5)
                  + kr[6] * __shfl(a0, 8*g+6) + kr[7] * __shfl(a0, 8*g+7);
        float nbs = nbr[0] * __shfl(u0,0) + nbr[1] * __shfl(u0,1)
                  + nbr[2] * __shfl(u0,2) + nbr[3] * __shfl(u0,3)
                  + nbr[4] * __shfl(u0,4) + nbr[5] * __shfl(u0,5)
                  + nbr[6] * __shfl(u0,6) + nbr[7] * __shfl(u0,7);
        gvp += (g == 3) ? nbs : 0.f;
        gvp += __shfl_xor(gvp, 16);
        gvp += __shfl_xor(gvp, 32);
        // w = Mc_j w + gv
        float part = mcs[j][0] * __shfl(w, 4*g+0) + mcs[j][1] * __shfl(w, 4*g+1)
                   + mcs[j][2] * __shfl(w, 4*g+2) + mcs[j][3] * __shfl(w, 4*g+3);
        part += __shfl_xor(part, 16);
        part += __shfl_xor(part, 32);
        w = part + gvp;
    }
    if (lane < 16) wseg[(size_t)seg * 4096 + b * 16 + i] = w;

    // segment-product emitters (block-uniform branches)
    if (blockIdx.x == 0) {          // P0 = Mc15 ... Mc0
        float pr[4];
#pragma unroll
        for (int k = 0; k < 4; ++k) pr[k] = (4 * g + k == i) ? 1.f : 0.f;
#pragma unroll
        for (int j = 0; j < 16; ++j) {
            float np[4] = {0.f, 0.f, 0.f, 0.f};
#pragma unroll
            for (int q = 0; q < 16; ++q) {
                const float mq = __shfl(mcs[j][q & 3], i + 16 * (q >> 2));
#pragma unroll
                for (int k = 0; k < 4; ++k) np[k] += mq * __shfl(pr[k], q + 16 * g);
            }
#pragma unroll
            for (int k = 0; k < 4; ++k) pr[k] = np[k];
        }
#pragma unroll
        for (int k = 0; k < 4; ++k) wsp[i * 16 + 4 * g + k] = pr[k];      // OFF_P0
    }
    if (blockIdx.x == 256) {        // PP = Mc16^16 (4 squarings)
        float pr[4];
#pragma unroll
        for (int k = 0; k < 4; ++k) pr[k] = mcs[0][k];
#pragma unroll
        for (int r = 0; r < 4; ++r) {
            float np[4] = {0.f, 0.f, 0.f, 0.f};
#pragma unroll
            for (int q = 0; q < 16; ++q) {
                const float sq = __shfl(pr[q & 3], i + 16 * (q >> 2));
#pragma unroll
                for (int k = 0; k < 4; ++k) np[k] += sq * __shfl(pr[k], q + 16 * g);
            }
#pragma unroll
            for (int k = 0; k < 4; ++k) pr[k] = np[k];
        }
#pragma unroll
        for (int k = 0; k < 4; ++k) wsp[256 + i * 16 + 4 * g + k] = pr[k]; // OFF_PP
    }
}

// ---------------------------------------------------------------------------
// Kernel 4: phase B (verified R9) — boundary recursion over 16 segments.
// ---------------------------------------------------------------------------
__global__ __launch_bounds__(64) void phB_k(
    const float* __restrict__ mean0, const float* __restrict__ wsp,
    const float* __restrict__ wseg, float* __restrict__ bnd)
{
    const int lane = threadIdx.x;
    const int i = lane & 15, g = lane >> 4;
    const int b = blockIdx.x;

    const float4 v0 = *(const float4*)(wsp + i * 16 + 4 * g);
    const float4 vp = *(const float4*)(wsp + 256 + i * 16 + 4 * g);
    const float m0s[4] = {v0.x, v0.y, v0.z, v0.w};
    const float mps[4] = {vp.x, vp.y, vp.z, vp.w};
    float wv[16];
#pragma unroll
    for (int s = 0; s < 16; ++s) wv[s] = wseg[(size_t)s * 4096 + b * 16 + i];

    float mn = mean0[b * 16 + i];
#pragma unroll
    for (int s = 0; s < 16; ++s) {
        if (lane < 16) bnd[(size_t)s * 4096 + b * 16 + i] = mn;
        const float c0 = (s == 0) ? m0s[0] : mps[0];
        const float c1 = (s == 0) ? m0s[1] : mps[1];
        const float c2 = (s == 0) ? m0s[2] : mps[2];
        const float c3 = (s == 0) ? m0s[3] : mps[3];
        float part = c0 * __shfl(mn, 4 * g + 0) + c1 * __shfl(mn, 4 * g + 1)
                   + c2 * __shfl(mn, 4 * g + 2) + c3 * __shfl(mn, 4 * g + 3);
        part += __shfl_xor(part, 16);
        part += __shfl_xor(part, 32);
        mn = part + wv[s];
    }
}

// ---------------------------------------------------------------------------
// Kernel 5: phase C — regenerate interiors (gv inline), emit outputs.
// ---------------------------------------------------------------------------
__global__ __launch_bounds__(64) void phC_k(
    const float* __restrict__ u, const float* __restrict__ a,
    const float* __restrict__ wsK, const float* __restrict__ wsM,
    const float* __restrict__ wsN, const float* __restrict__ bnd,
    float* __restrict__ out)
{
    const int lane = threadIdx.x;
    const int i = lane & 15, g = lane >> 4;
    const int seg = blockIdx.x >> 8;
    const int b = blockIdx.x & 255;

    float mcs[16][4];
#pragma unroll
    for (int j = 0; j < 16; ++j) {
        const int tc = (seg == 0) ? j : 16;
        const float4 v = *(const float4*)(wsM + (size_t)tc * 256 + i * 16 + 4 * g);
        mcs[j][0] = v.x; mcs[j][1] = v.y; mcs[j][2] = v.z; mcs[j][3] = v.w;
    }
    float kc[8], nbc[8];
    if (seg != 0) {
        const float4 k0 = *(const float4*)(wsK + (size_t)16 * 512 + i * 32 + 8 * g);
        const float4 k1 = *(const float4*)(wsK + (size_t)16 * 512 + i * 32 + 8 * g + 4);
        const float4 n0 = *(const float4*)(wsN + (size_t)16 * 128 + i * 8);
        const float4 n1 = *(const float4*)(wsN + (size_t)16 * 128 + i * 8 + 4);
        kc[0]=k0.x; kc[1]=k0.y; kc[2]=k0.z; kc[3]=k0.w;
        kc[4]=k1.x; kc[5]=k1.y; kc[6]=k1.z; kc[7]=k1.w;
        nbc[0]=n0.x; nbc[1]=n0.y; nbc[2]=n0.z; nbc[3]=n0.w;
        nbc[4]=n1.x; nbc[5]=n1.y; nbc[6]=n1.z; nbc[7]=n1.w;
    }

    float mn = bnd[(size_t)seg * 4096 + b * 16 + i];
    float* ob = out + (size_t)b * 4096 + (size_t)(16 * seg) * 16;
#pragma unroll
    for (int j = 0; j < 16; ++j) {
        const int t = 16 * seg + j;
        float kr[8], nbr[8];
        if (seg == 0) {
            const float4 k0 = *(const float4*)(wsK + (size_t)j * 512 + i * 32 + 8 * g);
            const float4 k1 = *(const float4*)(wsK + (size_t)j * 512 + i * 32 + 8 * g + 4);
            const float4 n0 = *(const float4*)(wsN + (size_t)j * 128 + i * 8);
            const float4 n1 = *(const float4*)(wsN + (size_t)j * 128 + i * 8 + 4);
            kr[0]=k0.x; kr[1]=k0.y; kr[2]=k0.z; kr[3]=k0.w;
            kr[4]=k1.x; kr[5]=k1.y; kr[6]=k1.z; kr[7]=k1.w;
            nbr[0]=n0.x; nbr[1]=n0.y; nbr[2]=n0.z; nbr[3]=n0.w;
            nbr[4]=n1.x; nbr[5]=n1.y; nbr[6]=n1.z; nbr[7]=n1.w;
        } else {
#pragma unroll
            for (int k = 0; k < 8; ++k) { kr[k] = kc[k]; nbr[k] = nbc[k]; }
        }
        const float a0 = a[(size_t)b * (TT * 32) + t * 32 + (lane & 31)];
        const float u0 = u[(size_t)b * (TT * 8) + t * 8 + (lane & 7)];
        float gvp = kr[0] * __shfl(a0, 8*g+0) + kr[1] * __shfl(a0, 8*g+1)
                  + kr[2] * __shfl(a0, 8*g+2) + kr[3] * __shfl(a0, 8*g+3)
                  + kr[4] * __shfl(a0, 8*g+4) + kr[5] * __shfl(a0, 8*g+5)
                  + kr[6] * __shfl(a0, 8*g+6) + kr[7] * __shfl(a0, 8*g+7);
        float nbs = nbr[0] * __shfl(u0,0) + nbr[1] * __shfl(u0,1)
                  + nbr[2] * __shfl(u0,2) + nbr[3] * __shfl(u0,3)
                  + nbr[4] * __shfl(u0,4) + nbr[5] * __shfl(u0,5)
                  + nbr[6] * __shfl(u0,6) + nbr[7] * __shfl(u0,7);
        gvp += (g == 3) ? nbs : 0.f;
        gvp += __shfl_xor(gvp, 16);
        gvp += __shfl_xor(gvp, 32);
        float part = mcs[j][0] * __shfl(mn, 4*g+0) + mcs[j][1] * __shfl(mn, 4*g+1)
                   + mcs[j][2] * __shfl(mn, 4*g+2) + mcs[j][3] * __shfl(mn, 4*g+3);
        part += __shfl_xor(part, 16);
        part += __shfl_xor(part, 32);
        mn = part + gvp;
        if (lane < 16) ob[j * 16 + i] = mn;
    }
}

// ---------------------------------------------------------------------------
// Fallback (verified R6/R8/R9): serial mean pass if ws too small.
// ---------------------------------------------------------------------------
__global__ __launch_bounds__(64) void meanf_k(
    const float* __restrict__ mean0, const float* __restrict__ u,
    const float* __restrict__ a, const float* __restrict__ wsK,
    const float* __restrict__ wsM, const float* __restrict__ wsN,
    float* __restrict__ out)
{
    const int lane = threadIdx.x;
    const int b = blockIdx.x;
    const int i = lane & 15;
    const int g = lane >> 4;

    const float* ub = u + (size_t)b * TT * 8;
    const float* ab = a + (size_t)b * TT * 32;
    float* ob = out + (size_t)b * TT * 16;

    float mn = mean0[b * 16 + i];
    float Mc[16];
    {
        const float4* p = (const float4*)(wsM + i * 16);
        float4 x0 = p[0], x1 = p[1], x2 = p[2], x3 = p[3];
        Mc[0]=x0.x; Mc[1]=x0.y; Mc[2]=x0.z; Mc[3]=x0.w;
        Mc[4]=x1.x; Mc[5]=x1.y; Mc[6]=x1.z; Mc[7]=x1.w;
        Mc[8]=x2.x; Mc[9]=x2.y; Mc[10]=x2.z; Mc[11]=x2.w;
        Mc[12]=x3.x; Mc[13]=x3.y; Mc[14]=x3.z; Mc[15]=x3.w;
    }
    float gv;
    {
        float4 k0 = *(const float4*)(wsK + i * 32 + 8 * g);
        float4 k1 = *(const float4*)(wsK + i * 32 + 8 * g + 4);
        float4 n0 = *(const float4*)(wsN + i * 8);
        float4 n1 = *(const float4*)(wsN + i * 8 + 4);
        float u0 = ub[lane & 7];
        float a0 = ab[lane & 31];
        float part = k0.x * __shfl(a0, 8*g+0) + k0.y * __shfl(a0, 8*g+1)
                   + k0.z * __shfl(a0, 8*g+2) + k0.w * __shfl(a0, 8*g+3)
                   + k1.x * __shfl(a0, 8*g+4) + k1.y * __shfl(a0, 8*g+5)
                   + k1.z * __shfl(a0, 8*g+6) + k1.w * __shfl(a0, 8*g+7);
        float nbs = n0.x * __shfl(u0,0) + n0.y * __shfl(u0,1)
                  + n0.z * __shfl(u0,2) + n0.w * __shfl(u0,3)
                  + n1.x * __shfl(u0,4) + n1.y * __shfl(u0,5)
                  + n1.z * __shfl(u0,6) + n1.w * __shfl(u0,7);
        part += (g == 3) ? nbs : 0.f;
        part += __shfl_xor(part, 16);
        part += __shfl_xor(part, 32);
        gv = part;
    }
    float4 mA, mB, mC, mD, kp0, kp1, np0, np1;
    float upn, apn;
    {
        const float4* p = (const float4*)(wsM + 256 + i * 16);
        mA = p[0]; mB = p[1]; mC = p[2]; mD = p[3];
        kp0 = *(const float4*)(wsK + 512 + i * 32 + 8 * g);
        kp1 = *(const float4*)(wsK + 512 + i * 32 + 8 * g + 4);
        np0 = *(const float4*)(wsN + 128 + i * 8);
        np1 = *(const float4*)(wsN + 128 + i * 8 + 4);
        upn = ub[8 + (lane & 7)];
        apn = ab[32 + (lane & 31)];
    }

    for (int t = 0; t < TT; ++t) {
        const int t2 = (t + 2 < TT) ? t + 2 : TT - 1;
        const int s2 = (t2 < WARM) ? t2 : WARM;
        const float4* mp = (const float4*)(wsM + (size_t)s2 * 256 + i * 16);
        float4 l0 = mp[0], l1 = mp[1], l2 = mp[2], l3 = mp[3];
        float4 kl0 = *(const float4*)(wsK + (size_t)s2 * 512 + i * 32 + 8 * g);
        float4 kl1 = *(const float4*)(wsK + (size_t)s2 * 512 + i * 32 + 8 * g + 4);
        float4 nl0 = *(const float4*)(wsN + (size_t)s2 * 128 + i * 8);
        float4 nl1 = *(const float4*)(wsN + (size_t)s2 * 128 + i * 8 + 4);
        float ul = ub[t2 * 8 + (lane & 7)];
        float al = ab[t2 * 32 + (lane & 31)];

        float s0 = gv, s1 = 0.f, s2f = 0.f, s3 = 0.f;
#pragma unroll
        for (int q = 0; q < 16; q += 4) {
            s0  += Mc[q]     * __shfl(mn, q);
            s1  += Mc[q + 1] * __shfl(mn, q + 1);
            s2f += Mc[q + 2] * __shfl(mn, q + 2);
            s3  += Mc[q + 3] * __shfl(mn, q + 3);
        }
        mn = (s0 + s1) + (s2f + s3);
        if (lane < 16) ob[t * 16 + lane] = mn;

        float part = kp0.x * __shfl(apn, 8*g+0) + kp0.y * __shfl(apn, 8*g+1)
                   + kp0.z * __shfl(apn, 8*g+2) + kp0.w * __shfl(apn, 8*g+3)
                   + kp1.x * __shfl(apn, 8*g+4) + kp1.y * __shfl(apn, 8*g+5)
                   + kp1.z * __shfl(apn, 8*g+6) + kp1.w * __shfl(apn, 8*g+7);
        float nbs = np0.x * __shfl(upn,0) + np0.y * __shfl(upn,1)
                  + np0.z * __shfl(upn,2) + np0.w * __shfl(upn,3)
                  + np1.x * __shfl(upn,4) + np1.y * __shfl(upn,5)
                  + np1.z * __shfl(upn,6) + np1.w * __shfl(upn,7);
        part += (g == 3) ? nbs : 0.f;
        part += __shfl_xor(part, 16);
        part += __shfl_xor(part, 32);
        gv = part;

        Mc[0]=mA.x; Mc[1]=mA.y; Mc[2]=mA.z; Mc[3]=mA.w;
        Mc[4]=mB.x; Mc[5]=mB.y; Mc[6]=mB.z; Mc[7]=mB.w;
        Mc[8]=mC.x; Mc[9]=mC.y; Mc[10]=mC.z; Mc[11]=mC.w;
        Mc[12]=mD.x; Mc[13]=mD.y; Mc[14]=mD.z; Mc[15]=mD.w;
        mA = l0; mB = l1; mC = l2; mD = l3;
        kp0 = kl0; kp1 = kl1; np0 = nl0; np1 = nl1;
        upn = ul; apn = al;
    }
}

extern "C" void kernel_launch(void* const* d_in, const int* in_sizes, int n_in,
                              void* d_out, int out_size, void* d_ws, size_t ws_size,
                              hipStream_t stream) {
    const float* mean0 = nullptr; const float* cov0 = nullptr;
    const float* u = nullptr;     const float* a = nullptr;
    const float* Mm = nullptr;    const float* Nm = nullptr;
    const float* dv = nullptr;    const float* Bm = nullptr;
    const float* Cm = nullptr;    const float* nxp = nullptr;
    const float* nap = nullptr;
    for (int i = 0; i < n_in; ++i) {
        const float* p = (const float*)d_in[i];
        switch (in_sizes[i]) {
            case 256 * 16:        mean0 = p; break;
            case 256 * 256:       cov0 = p; break;
            case 256 * 256 * 8:   u = p; break;
            case 256 * 256 * 32:  a = p; break;
            case 256:             if (!Mm) Mm = p; else Nm = p; break;
            case 16:              if (!dv) dv = p; else nxp = p; break;
            case 128:             Bm = p; break;
            case 512:             Cm = p; break;
            case 32:              nap = p; break;
            default: break;
        }
    }
    float* ws   = (float*)d_ws;
    float* wsK  = ws + OFF_K;
    float* wsM  = ws + OFF_MC;
    float* wsN  = ws + OFF_NB;
    float* wsp  = ws + OFF_P0;   // P0 at +0, PP at +256
    float* wseg = ws + OFF_WSEG;
    float* bnd  = ws + OFF_BND;

    setup_k<<<1, 64, 0, stream>>>(Mm, Nm, dv, Bm, Cm, nxp, nap, ws);
    chain_k<<<WARM + 1, 64, 0, stream>>>(cov0, Bm, ws, wsK, wsM, wsN);
    if (ws_size >= NEED_WS_BYTES) {
        phA_k<<<16 * 256, 64, 0, stream>>>(u, a, ws, wsK, wsM, wsN, wseg, wsp);
        phB_k<<<256, 64, 0, stream>>>(mean0, wsp, wseg, bnd);
        phC_k<<<16 * 256, 64, 0, stream>>>(u, a, wsK, wsM, wsN, bnd, (float*)d_out);
    } else {
        meanf_k<<<256, 64, 0, stream>>>(mean0, u, a, wsK, wsM, wsN, (float*)d_out);
    }
}

// Round 11
// 227.629 us; speedup vs baseline: 3.6813x; 1.0342x over previous
//
#include <hip/hip_runtime.h>
#include <math.h>

#define TT 256
#define WARM 16
// ws float offsets
#define OFF_A    0      // A (256)
#define OFF_W    512    // W = C^T Na^-1 (16x32 = 512)
#define OFF_CA   1024   // CA = C A (512)
#define OFF_CB   1536   // CB = C B (256)
#define OFF_MAPS 1792   // 5 maps x {E(256),F(256),H(256)} = 3840 -> 5632
#define OFF_K    5632   // 17 x 512 -> 14336
#define OFF_MC   14336  // 17 x 256 -> 18688
#define OFF_NB   18688  // 17 x 128 -> 20864
#define OFF_P0   20864  // Mseg0 (256) -> 21120
#define OFF_PP   21120  // Mc16^16 (256) -> 21376
#define OFF_WSEG 21376  // 16 x 256 x 16 -> 86912
#define OFF_BND  86912  // 16 x 256 x 16 -> 152448
#define NEED_WS_BYTES ((size_t)152448 * 4)

__device__ __forceinline__ float softplus(float v) {
    return fmaxf(v, 0.0f) + log1pf(expf(-fabsf(v)));
}

// Shuffle-based Gauss-Jordan, [X|I] -> [I|X^-1] (verified R5-R10).
// Layout: lane (i, gq) holds aug[i][8*gq+k], k=0..7.
__device__ __forceinline__ void gj16(float (&aug)[8], const int i, const int gq) {
#pragma unroll
    for (int j = 0; j < 16; ++j) {
        float prow[8];
#pragma unroll
        for (int k = 0; k < 8; ++k) prow[k] = __shfl(aug[k], j + 16 * gq);
        const float pjj = __shfl(aug[j & 7], j + 16 * (j >> 3));
        const float cij = __shfl(aug[j & 7], i + 16 * (j >> 3));
        const float pivinv = 1.0f / pjj;
        const float f = cij * pivinv;
#pragma unroll
        for (int k = 0; k < 8; ++k)
            aug[k] = (i == j) ? prow[k] * pivinv : aug[k] - f * prow[k];
    }
}

// ---------------------------------------------------------------------------
// Kernel 1: 256 threads. Register-resident MGS QR of M and N (both at once,
// column-per-lane, wave 0), assemble A + constants (all 256 threads), then
// Woodbury doubling for the 1/2/4/8/16-step Riccati maps (all 4 waves
// redundantly, lane-relative indices => identical values, uniform barriers).
// ---------------------------------------------------------------------------
__global__ __launch_bounds__(256) void setup_k(
    const float* __restrict__ Mm, const float* __restrict__ Nm,
    const float* __restrict__ dvec, const float* __restrict__ Bm,
    const float* __restrict__ Cm, const float* __restrict__ nx,
    const float* __restrict__ na, float* __restrict__ ws)
{
    __shared__ float qm[16][17], qn[16][17], T0s[16][17];
    __shared__ float sC[32][17], sW[16][33], sAm[16][17], sBm[16][9];
    __shared__ float sE[16][17], sF[16][17], sH[16][17], sScr[16][17];
    __shared__ float spv[16], d2[16], sNai[32], sNxi[16];
    const int tid = threadIdx.x;
    const int lane = tid & 63;
    const int i = lane & 15, gq = lane >> 4, h = gq & 1;

    qm[tid >> 4][tid & 15] = Mm[tid];
    qn[tid >> 4][tid & 15] = Nm[tid];
    for (int e = tid; e < 512; e += 256) sC[e >> 4][e & 15] = Cm[e];
    if (tid < 128) sBm[tid >> 3][tid & 7] = Bm[tid];
    if (tid < 16) {
        float s = softplus(dvec[tid]);
        spv[tid] = sqrtf(s);
        d2[tid] = 1.0f / sqrtf(1.0f + s);
        sNxi[tid] = 1.0f / (softplus(nx[tid]) + 1e-4f);
    }
    if (tid < 32) sNai[tid] = 1.0f / (softplus(na[tid]) + 1e-4f);
    __syncthreads();

    // ---- wave 0: register MGS on both matrices simultaneously ----
    // lanes 0-15: columns of M; lanes 16-31: columns of N; 32-63 idle.
    // Identical arithmetic order to the verified LDS MGS (norm before scale,
    // project k>j against scaled q_j) => same sign-fixed factors.
    if (tid < 64) {
        const int j0 = lane & 15;
        const int mi = lane >> 4;
        float (*Qs)[17] = (mi == 1) ? qn : qm;
        float col[16];
#pragma unroll
        for (int r = 0; r < 16; ++r) col[r] = Qs[r][j0];
        const int base = lane & 48;
#pragma unroll
        for (int j = 0; j < 16; ++j) {
            float qj[16];
#pragma unroll
            for (int r = 0; r < 16; ++r) qj[r] = __shfl(col[r], base + j);
            float nrm = 0.f;
#pragma unroll
            for (int r = 0; r < 16; ++r) nrm += qj[r] * qj[r];
            const float scal = 1.0f / sqrtf(nrm);
#pragma unroll
            for (int r = 0; r < 16; ++r) qj[r] *= scal;
            if (j0 == j) {
#pragma unroll
                for (int r = 0; r < 16; ++r) col[r] = qj[r];
            } else if (j0 > j) {
                float pr = 0.f;
#pragma unroll
                for (int r = 0; r < 16; ++r) pr += qj[r] * col[r];
#pragma unroll
                for (int r = 0; r < 16; ++r) col[r] -= pr * qj[r];
            }
        }
        if (mi < 2) {
#pragma unroll
            for (int r = 0; r < 16; ++r) Qs[r][j0] = col[r];
        }
    }
    __syncthreads();

    // ---- assembly with all 256 threads (1 element each) ----
    {
        const int ii = tid >> 4, j = tid & 15;
        float s = 0.f;
#pragma unroll
        for (int q = 0; q < 16; ++q) s += qm[ii][q] * d2[q] * qn[j][q];
        T0s[ii][j] = spv[ii] * s;
    }
    __syncthreads();
    {
        const int ii = tid >> 4, j = tid & 15;
        float s = 0.f;
#pragma unroll
        for (int q = 0; q < 16; ++q) s += qn[ii][q] * T0s[q][j];
        ws[OFF_A + tid] = s;
        sAm[ii][j] = s;
    }
    for (int e = tid; e < 512; e += 256) {
        int q = e >> 5, r = e & 31;
        float w = sC[r][q] * sNai[r];
        sW[q][r] = w;
        ws[OFF_W + e] = w;
    }
    __syncthreads();
    // base map: E = Nxi A, H = A^T Nxi A, F = G + diag(Nxi)
    {
        const int ii = tid >> 4, j = tid & 15;
        float g = 0.f;
#pragma unroll
        for (int r = 0; r < 32; ++r) g += sC[r][ii] * sW[j][r];
        sF[ii][j] = g + ((ii == j) ? sNxi[ii] : 0.f);
        sE[ii][j] = sNxi[ii] * sAm[ii][j];
        float hsum = 0.f;
#pragma unroll
        for (int q = 0; q < 16; ++q) hsum += sAm[q][ii] * sNxi[q] * sAm[q][j];
        sH[ii][j] = hsum;
    }
    for (int e = tid; e < 512; e += 256) {
        int r = e >> 4, j = e & 15;
        float s = 0.f;
#pragma unroll
        for (int q = 0; q < 16; ++q) s += sC[r][q] * sAm[q][j];
        ws[OFF_CA + e] = s;
    }
    {
        int r = tid >> 3, j = tid & 7;
        if (tid < 256) {
            float s = 0.f;
#pragma unroll
            for (int q = 0; q < 16; ++q) s += sC[r][q] * sBm[q][j];
            ws[OFF_CB + tid] = s;
        }
    }
    __syncthreads();

    // ---- Woodbury doubling (all waves redundantly; lane-relative) ----
    float Erow[16], ETrow[16], Fr[8], Hr[8];
#pragma unroll
    for (int q = 0; q < 16; ++q) { Erow[q] = sE[i][q]; ETrow[q] = sE[q][i]; }
#pragma unroll
    for (int k = 0; k < 8; ++k) { Fr[k] = sF[i][8 * h + k]; Hr[k] = sH[i][8 * h + k]; }

    if (tid < 16) {
#pragma unroll
        for (int q = 0; q < 16; ++q) ws[OFF_MAPS + i * 16 + q] = Erow[q];
    }
    if (tid < 32) {
#pragma unroll
        for (int k = 0; k < 8; ++k) {
            ws[OFF_MAPS + 256 + i * 16 + 8 * h + k] = Fr[k];
            ws[OFF_MAPS + 512 + i * 16 + 8 * h + k] = Hr[k];
        }
    }

    for (int m = 1; m <= 4; ++m) {
        // Z = (F+H)^-1
        float aug[8];
#pragma unroll
        for (int k = 0; k < 8; ++k)
            aug[k] = (gq < 2) ? (Fr[k] + Hr[k]) : ((8 * (gq - 2) + k == i) ? 1.f : 0.f);
        gj16(aug, i, gq);
        float Z_r[8];
#pragma unroll
        for (int k = 0; k < 8; ++k) Z_r[k] = __shfl(aug[k], i + 16 * (2 + h));
        // T = E Z (mirrored), Trow
        float T_r[8];
#pragma unroll
        for (int k = 0; k < 8; ++k) T_r[k] = 0.f;
#pragma unroll
        for (int q = 0; q < 16; ++q) {
            const float eq = Erow[q];
#pragma unroll
            for (int k = 0; k < 8; ++k) T_r[k] += eq * __shfl(Z_r[k], q + 16 * h);
        }
        float Trow[16];
#pragma unroll
        for (int q = 0; q < 16; ++q) Trow[q] = __shfl(T_r[q & 7], i + 16 * (q >> 3));
        // T2 = E^T Z (mirrored), T2row
        float T2_r[8];
#pragma unroll
        for (int k = 0; k < 8; ++k) T2_r[k] = 0.f;
#pragma unroll
        for (int q = 0; q < 16; ++q) {
            const float eq = ETrow[q];
#pragma unroll
            for (int k = 0; k < 8; ++k) T2_r[k] += eq * __shfl(Z_r[k], q + 16 * h);
        }
        float T2row[16];
#pragma unroll
        for (int q = 0; q < 16; ++q) T2row[q] = __shfl(T2_r[q & 7], i + 16 * (q >> 3));
        // F' = F - T E^T ; H' = H - T2 E ; E' = T E
        float F2r[8], H2r[8], E2r[8];
#pragma unroll
        for (int k = 0; k < 8; ++k) { F2r[k] = Fr[k]; H2r[k] = Hr[k]; E2r[k] = 0.f; }
#pragma unroll
        for (int q = 0; q < 16; ++q) {
            const float tq = Trow[q], t2q = T2row[q];
#pragma unroll
            for (int k = 0; k < 8; ++k) {
                const float ecol = __shfl(Erow[q], 8 * h + k);    // E[8h+k][q]
                const float etcol = __shfl(ETrow[q], 8 * h + k);  // E[q][8h+k]
                F2r[k] -= tq * ecol;
                H2r[k] -= t2q * etcol;
                E2r[k] += tq * etcol;
            }
        }
        // E' roundtrip through LDS (uniform barriers: all 256 threads)
        __syncthreads();
        if (tid < 32) {
#pragma unroll
            for (int k = 0; k < 8; ++k) sScr[i][8 * h + k] = E2r[k];
        }
        __syncthreads();
#pragma unroll
        for (int q = 0; q < 16; ++q) { Erow[q] = sScr[i][q]; ETrow[q] = sScr[q][i]; }
#pragma unroll
        for (int k = 0; k < 8; ++k) { Fr[k] = F2r[k]; Hr[k] = H2r[k]; }
        // store map m
        const int base = OFF_MAPS + m * 768;
        if (tid < 16) {
#pragma unroll
            for (int q = 0; q < 16; ++q) ws[base + i * 16 + q] = Erow[q];
        }
        if (tid < 32) {
#pragma unroll
            for (int k = 0; k < 8; ++k) {
                ws[base + 256 + i * 16 + 8 * h + k] = Fr[k];
                ws[base + 512 + i * 16 + 8 * h + k] = Hr[k];
            }
        }
    }
}

// ---------------------------------------------------------------------------
// Kernel 2 (verified R10): gain chain via binary map decomposition.
// ---------------------------------------------------------------------------
__global__ __launch_bounds__(64) void chain_k(
    const float* __restrict__ cov0, const float* __restrict__ Bm,
    const float* __restrict__ ws, float* __restrict__ wsK,
    float* __restrict__ wsM, float* __restrict__ wsN)
{
    __shared__ float sW[16][33], sP[16][17], sK[16][33];
    __shared__ float sCA[32][17], sCB[32][9];
    const int lane = threadIdx.x;
    const int t = blockIdx.x;            // 0..16
    const int n = t + 1;
    const int i = lane & 15, gq = lane >> 4, h = gq & 1;

    for (int e = lane; e < 512; e += 64) sW[e >> 5][e & 31] = ws[OFF_W + e];
    for (int e = lane; e < 512; e += 64) sCA[e >> 4][e & 15] = ws[OFF_CA + e];
    for (int e = lane; e < 256; e += 64) sCB[e >> 3][e & 7] = ws[OFF_CB + e];

    float aug[8];
#pragma unroll
    for (int k = 0; k < 8; ++k)
        aug[k] = (gq < 2) ? cov0[i * 16 + 8 * gq + k]
                          : ((8 * (gq - 2) + k == i) ? 1.f : 0.f);
    gj16(aug, i, gq);
    float L_r[8];
#pragma unroll
    for (int k = 0; k < 8; ++k) L_r[k] = __shfl(aug[k], i + 16 * (2 + h));

    for (int m = 4; m >= 0; --m) {
        if (!(n & (1 << m))) continue;
        const int base = OFF_MAPS + m * 768;
        float Er[16], Fr[8], Hr[8];
#pragma unroll
        for (int q = 0; q < 16; ++q) Er[q] = ws[base + i * 16 + q];
#pragma unroll
        for (int k = 0; k < 8; ++k) {
            Fr[k] = ws[base + 256 + i * 16 + 8 * h + k];
            Hr[k] = ws[base + 512 + i * 16 + 8 * h + k];
        }
#pragma unroll
        for (int k = 0; k < 8; ++k)
            aug[k] = (gq < 2) ? (L_r[k] + Hr[k]) : ((8 * (gq - 2) + k == i) ? 1.f : 0.f);
        gj16(aug, i, gq);
        float T_r[8];
#pragma unroll
        for (int k = 0; k < 8; ++k) T_r[k] = 0.f;
#pragma unroll
        for (int q = 0; q < 16; ++q) {
            const float eq = Er[q];
#pragma unroll
            for (int k = 0; k < 8; ++k) T_r[k] += eq * __shfl(aug[k], q + 16 * (2 + h));
        }
        float Trow[16];
#pragma unroll
        for (int q = 0; q < 16; ++q) Trow[q] = __shfl(T_r[q & 7], i + 16 * (q >> 3));
#pragma unroll
        for (int k = 0; k < 8; ++k) L_r[k] = Fr[k];
#pragma unroll
        for (int q = 0; q < 16; ++q) {
            const float tq = Trow[q];
#pragma unroll
            for (int k = 0; k < 8; ++k) L_r[k] -= tq * __shfl(Er[q], 8 * h + k);
        }
    }
    // P = L^-1
#pragma unroll
    for (int k = 0; k < 8; ++k)
        aug[k] = (gq < 2) ? L_r[k] : ((8 * (gq - 2) + k == i) ? 1.f : 0.f);
    gj16(aug, i, gq);
    float P_r[8];
#pragma unroll
    for (int k = 0; k < 8; ++k) P_r[k] = __shfl(aug[k], i + 16 * (2 + h));
    if (lane < 32) {
#pragma unroll
        for (int k = 0; k < 8; ++k) sP[i][8 * h + k] = P_r[k];
    }
    __syncthreads();
#pragma unroll
    for (int m = 0; m < 8; ++m) {
        const int e = lane + 64 * m, ii = e >> 5, rr = e & 31;
        float s = 0.f;
#pragma unroll
        for (int q = 0; q < 16; ++q) s += sP[ii][q] * sW[q][rr];
        sK[ii][rr] = s;
        wsK[(size_t)t * 512 + e] = s;
    }
    __syncthreads();
#pragma unroll
    for (int m = 0; m < 4; ++m) {
        const int e = lane + 64 * m, ii = e >> 4, jj = e & 15;
        float s = ws[OFF_A + e];
#pragma unroll
        for (int r = 0; r < 32; ++r) s -= sK[ii][r] * sCA[r][jj];
        wsM[(size_t)t * 256 + e] = s;
    }
#pragma unroll
    for (int m = 0; m < 2; ++m) {
        const int e = lane + 64 * m, ii = e >> 3, jj = e & 7;
        float s = Bm[e];
#pragma unroll
        for (int r = 0; r < 32; ++r) s -= sK[ii][r] * sCB[r][jj];
        wsN[(size_t)t * 128 + e] = s;
    }
}

// ---------------------------------------------------------------------------
// Kernel 3 (verified R10): phase A — segment offsets, gv inline; blocks 0 and
// 256 also emit P0 = Mc15..Mc0 and PP = Mc16^16.
// ---------------------------------------------------------------------------
__global__ __launch_bounds__(64) void phA_k(
    const float* __restrict__ u, const float* __restrict__ a,
    const float* __restrict__ ws, const float* __restrict__ wsK,
    const float* __restrict__ wsM, const float* __restrict__ wsN,
    float* __restrict__ wseg, float* __restrict__ wsp)
{
    const int lane = threadIdx.x;
    const int i = lane & 15, g = lane >> 4;
    const int seg = blockIdx.x >> 8;
    const int b = blockIdx.x & 255;

    float mcs[16][4];
#pragma unroll
    for (int j = 0; j < 16; ++j) {
        const int tc = (seg == 0) ? j : 16;
        const float4 v = *(const float4*)(wsM + (size_t)tc * 256 + i * 16 + 4 * g);
        mcs[j][0] = v.x; mcs[j][1] = v.y; mcs[j][2] = v.z; mcs[j][3] = v.w;
    }
    float kc[8], nbc[8];
    if (seg != 0) {
        const float4 k0 = *(const float4*)(wsK + (size_t)16 * 512 + i * 32 + 8 * g);
        const float4 k1 = *(const float4*)(wsK + (size_t)16 * 512 + i * 32 + 8 * g + 4);
        const float4 n0 = *(const float4*)(wsN + (size_t)16 * 128 + i * 8);
        const float4 n1 = *(const float4*)(wsN + (size_t)16 * 128 + i * 8 + 4);
        kc[0]=k0.x; kc[1]=k0.y; kc[2]=k0.z; kc[3]=k0.w;
        kc[4]=k1.x; kc[5]=k1.y; kc[6]=k1.z; kc[7]=k1.w;
        nbc[0]=n0.x; nbc[1]=n0.y; nbc[2]=n0.z; nbc[3]=n0.w;
        nbc[4]=n1.x; nbc[5]=n1.y; nbc[6]=n1.z; nbc[7]=n1.w;
    }

    float w = 0.f;
#pragma unroll
    for (int j = 0; j < 16; ++j) {
        const int t = 16 * seg + j;
        float kr[8], nbr[8];
        if (seg == 0) {
            const float4 k0 = *(const float4*)(wsK + (size_t)j * 512 + i * 32 + 8 * g);
            const float4 k1 = *(const float4*)(wsK + (size_t)j * 512 + i * 32 + 8 * g + 4);
            const float4 n0 = *(const float4*)(wsN + (size_t)j * 128 + i * 8);
            const float4 n1 = *(const float4*)(wsN + (size_t)j * 128 + i * 8 + 4);
            kr[0]=k0.x; kr[1]=k0.y; kr[2]=k0.z; kr[3]=k0.w;
            kr[4]=k1.x; kr[5]=k1.y; kr[6]=k1.z; kr[7]=k1.w;
            nbr[0]=n0.x; nbr[1]=n0.y; nbr[2]=n0.z; nbr[3]=n0.w;
            nbr[4]=n1.x; nbr[5]=n1.y; nbr[6]=n1.z; nbr[7]=n1.w;
        } else {
#pragma unroll
            for (int k = 0; k < 8; ++k) { kr[k] = kc[k]; nbr[k] = nbc[k]; }
        }
        const float a0 = a[(size_t)b * (TT * 32) + t * 32 + (lane & 31)];
        const float u0 = u[(size_t)b * (TT * 8) + t * 8 + (lane & 7)];
        float gvp = kr[0] * __shfl(a0, 8*g+0) + kr[1] * __shfl(a0, 8*g+1)
                  + kr[2] * __shfl(a0, 8*g+2) + kr[3] * __shfl(a0, 8*g+3)
                  + kr[4] * __shfl(a0, 8*g+4) + kr[5] * __shfl(a0, 8*g+5)
                  + kr[6] * __shfl(a0, 8*g+6) + kr[7] * __shfl(a0, 8*g+7);
        float nbs = nbr[0] * __shfl(u0,0) + nbr[1] * __shfl(u0,1)
                  + nbr[2] * __shfl(u0,2) + nbr[3] * __shfl(u0,3)
                  + nbr[4] * __shfl(u0,4) + nbr[5] * __shfl(u0,5)
                  + nbr[6] * __shfl(u0,6) + nbr[7] * __shfl(u0,7);
        gvp += (g == 3) ? nbs : 0.f;
        gvp += __shfl_xor(gvp, 16);
        gvp += __shfl_xor(gvp, 32);
        float part = mcs[j][0] * __shfl(w, 4*g+0) + mcs[j][1] * __shfl(w, 4*g+1)
                   + mcs[j][2] * __shfl(w, 4*g+2) + mcs[j][3] * __shfl(w, 4*g+3);
        part += __shfl_xor(part, 16);
        part += __shfl_xor(part, 32);
        w = part + gvp;
    }
    if (lane < 16) wseg[(size_t)seg * 4096 + b * 16 + i] = w;

    if (blockIdx.x == 0) {          // P0 = Mc15 ... Mc0
        float pr[4];
#pragma unroll
        for (int k = 0; k < 4; ++k) pr[k] = (4 * g + k == i) ? 1.f : 0.f;
#pragma unroll
        for (int j = 0; j < 16; ++j) {
            float np[4] = {0.f, 0.f, 0.f, 0.f};
#pragma unroll
            for (int q = 0; q < 16; ++q) {
                const float mq = __shfl(mcs[j][q & 3], i + 16 * (q >> 2));
#pragma unroll
                for (int k = 0; k < 4; ++k) np[k] += mq * __shfl(pr[k], q + 16 * g);
            }
#pragma unroll
            for (int k = 0; k < 4; ++k) pr[k] = np[k];
        }
#pragma unroll
        for (int k = 0; k < 4; ++k) wsp[i * 16 + 4 * g + k] = pr[k];
    }
    if (blockIdx.x == 256) {        // PP = Mc16^16
        float pr[4];
#pragma unroll
        for (int k = 0; k < 4; ++k) pr[k] = mcs[0][k];
#pragma unroll
        for (int r = 0; r < 4; ++r) {
            float np[4] = {0.f, 0.f, 0.f, 0.f};
#pragma unroll
            for (int q = 0; q < 16; ++q) {
                const float sq = __shfl(pr[q & 3], i + 16 * (q >> 2));
#pragma unroll
                for (int k = 0; k < 4; ++k) np[k] += sq * __shfl(pr[k], q + 16 * g);
            }
#pragma unroll
            for (int k = 0; k < 4; ++k) pr[k] = np[k];
        }
#pragma unroll
        for (int k = 0; k < 4; ++k) wsp[256 + i * 16 + 4 * g + k] = pr[k];
    }
}

// ---------------------------------------------------------------------------
// Kernel 4 (verified R9/R10): phase B — boundary recursion.
// ---------------------------------------------------------------------------
__global__ __launch_bounds__(64) void phB_k(
    const float* __restrict__ mean0, const float* __restrict__ wsp,
    const float* __restrict__ wseg, float* __restrict__ bnd)
{
    const int lane = threadIdx.x;
    const int i = lane & 15, g = lane >> 4;
    const int b = blockIdx.x;

    const float4 v0 = *(const float4*)(wsp + i * 16 + 4 * g);
    const float4 vp = *(const float4*)(wsp + 256 + i * 16 + 4 * g);
    const float m0s[4] = {v0.x, v0.y, v0.z, v0.w};
    const float mps[4] = {vp.x, vp.y, vp.z, vp.w};
    float wv[16];
#pragma unroll
    for (int s = 0; s < 16; ++s) wv[s] = wseg[(size_t)s * 4096 + b * 16 + i];

    float mn = mean0[b * 16 + i];
#pragma unroll
    for (int s = 0; s < 16; ++s) {
        if (lane < 16) bnd[(size_t)s * 4096 + b * 16 + i] = mn;
        const float c0 = (s == 0) ? m0s[0] : mps[0];
        const float c1 = (s == 0) ? m0s[1] : mps[1];
        const float c2 = (s == 0) ? m0s[2] : mps[2];
        const float c3 = (s == 0) ? m0s[3] : mps[3];
        float part = c0 * __shfl(mn, 4 * g + 0) + c1 * __shfl(mn, 4 * g + 1)
                   + c2 * __shfl(mn, 4 * g + 2) + c3 * __shfl(mn, 4 * g + 3);
        part += __shfl_xor(part, 16);
        part += __shfl_xor(part, 32);
        mn = part + wv[s];
    }
}

// ---------------------------------------------------------------------------
// Kernel 5 (verified R10): phase C — regenerate interiors, emit outputs.
// ---------------------------------------------------------------------------
__global__ __launch_bounds__(64) void phC_k(
    const float* __restrict__ u, const float* __restrict__ a,
    const float* __restrict__ wsK, const float* __restrict__ wsM,
    const float* __restrict__ wsN, const float* __restrict__ bnd,
    float* __restrict__ out)
{
    const int lane = threadIdx.x;
    const int i = lane & 15, g = lane >> 4;
    const int seg = blockIdx.x >> 8;
    const int b = blockIdx.x & 255;

    float mcs[16][4];
#pragma unroll
    for (int j = 0; j < 16; ++j) {
        const int tc = (seg == 0) ? j : 16;
        const float4 v = *(const float4*)(wsM + (size_t)tc * 256 + i * 16 + 4 * g);
        mcs[j][0] = v.x; mcs[j][1] = v.y; mcs[j][2] = v.z; mcs[j][3] = v.w;
    }
    float kc[8], nbc[8];
    if (seg != 0) {
        const float4 k0 = *(const float4*)(wsK + (size_t)16 * 512 + i * 32 + 8 * g);
        const float4 k1 = *(const float4*)(wsK + (size_t)16 * 512 + i * 32 + 8 * g + 4);
        const float4 n0 = *(const float4*)(wsN + (size_t)16 * 128 + i * 8);
        const float4 n1 = *(const float4*)(wsN + (size_t)16 * 128 + i * 8 + 4);
        kc[0]=k0.x; kc[1]=k0.y; kc[2]=k0.z; kc[3]=k0.w;
        kc[4]=k1.x; kc[5]=k1.y; kc[6]=k1.z; kc[7]=k1.w;
        nbc[0]=n0.x; nbc[1]=n0.y; nbc[2]=n0.z; nbc[3]=n0.w;
        nbc[4]=n1.x; nbc[5]=n1.y; nbc[6]=n1.z; nbc[7]=n1.w;
    }

    float mn = bnd[(size_t)seg * 4096 + b * 16 + i];
    float* ob = out + (size_t)b * 4096 + (size_t)(16 * seg) * 16;
#pragma unroll
    for (int j = 0; j < 16; ++j) {
        const int t = 16 * seg + j;
        float kr[8], nbr[8];
        if (seg == 0) {
            const float4 k0 = *(const float4*)(wsK + (size_t)j * 512 + i * 32 + 8 * g);
            const float4 k1 = *(const float4*)(wsK + (size_t)j * 512 + i * 32 + 8 * g + 4);
            const float4 n0 = *(const float4*)(wsN + (size_t)j * 128 + i * 8);
            const float4 n1 = *(const float4*)(wsN + (size_t)j * 128 + i * 8 + 4);
            kr[0]=k0.x; kr[1]=k0.y; kr[2]=k0.z; kr[3]=k0.w;
            kr[4]=k1.x; kr[5]=k1.y; kr[6]=k1.z; kr[7]=k1.w;
            nbr[0]=n0.x; nbr[1]=n0.y; nbr[2]=n0.z; nbr[3]=n0.w;
            nbr[4]=n1.x; nbr[5]=n1.y; nbr[6]=n1.z; nbr[7]=n1.w;
        } else {
#pragma unroll
            for (int k = 0; k < 8; ++k) { kr[k] = kc[k]; nbr[k] = nbc[k]; }
        }
        const float a0 = a[(size_t)b * (TT * 32) + t * 32 + (lane & 31)];
        const float u0 = u[(size_t)b * (TT * 8) + t * 8 + (lane & 7)];
        float gvp = kr[0] * __shfl(a0, 8*g+0) + kr[1] * __shfl(a0, 8*g+1)
                  + kr[2] * __shfl(a0, 8*g+2) + kr[3] * __shfl(a0, 8*g+3)
                  + kr[4] * __shfl(a0, 8*g+4) + kr[5] * __shfl(a0, 8*g+5)
                  + kr[6] * __shfl(a0, 8*g+6) + kr[7] * __shfl(a0, 8*g+7);
        float nbs = nbr[0] * __shfl(u0,0) + nbr[1] * __shfl(u0,1)
                  + nbr[2] * __shfl(u0,2) + nbr[3] * __shfl(u0,3)
                  + nbr[4] * __shfl(u0,4) + nbr[5] * __shfl(u0,5)
                  + nbr[6] * __shfl(u0,6) + nbr[7] * __shfl(u0,7);
        gvp += (g == 3) ? nbs : 0.f;
        gvp += __shfl_xor(gvp, 16);
        gvp += __shfl_xor(gvp, 32);
        float part = mcs[j][0] * __shfl(mn, 4*g+0) + mcs[j][1] * __shfl(mn, 4*g+1)
                   + mcs[j][2] * __shfl(mn, 4*g+2) + mcs[j][3] * __shfl(mn, 4*g+3);
        part += __shfl_xor(part, 16);
        part += __shfl_xor(part, 32);
        mn = part + gvp;
        if (lane < 16) ob[j * 16 + i] = mn;
    }
}

// ---------------------------------------------------------------------------
// Fallback (verified R6/R8/R9): serial mean pass if ws too small.
// ---------------------------------------------------------------------------
__global__ __launch_bounds__(64) void meanf_k(
    const float* __restrict__ mean0, const float* __restrict__ u,
    const float* __restrict__ a, const float* __restrict__ wsK,
    const float* __restrict__ wsM, const float* __restrict__ wsN,
    float* __restrict__ out)
{
    const int lane = threadIdx.x;
    const int b = blockIdx.x;
    const int i = lane & 15;
    const int g = lane >> 4;

    const float* ub = u + (size_t)b * TT * 8;
    const float* ab = a + (size_t)b * TT * 32;
    float* ob = out + (size_t)b * TT * 16;

    float mn = mean0[b * 16 + i];
    float Mc[16];
    {
        const float4* p = (const float4*)(wsM + i * 16);
        float4 x0 = p[0], x1 = p[1], x2 = p[2], x3 = p[3];
        Mc[0]=x0.x; Mc[1]=x0.y; Mc[2]=x0.z; Mc[3]=x0.w;
        Mc[4]=x1.x; Mc[5]=x1.y; Mc[6]=x1.z; Mc[7]=x1.w;
        Mc[8]=x2.x; Mc[9]=x2.y; Mc[10]=x2.z; Mc[11]=x2.w;
        Mc[12]=x3.x; Mc[13]=x3.y; Mc[14]=x3.z; Mc[15]=x3.w;
    }
    float gv;
    {
        float4 k0 = *(const float4*)(wsK + i * 32 + 8 * g);
        float4 k1 = *(const float4*)(wsK + i * 32 + 8 * g + 4);
        float4 n0 = *(const float4*)(wsN + i * 8);
        float4 n1 = *(const float4*)(wsN + i * 8 + 4);
        float u0 = ub[lane & 7];
        float a0 = ab[lane & 31];
        float part = k0.x * __shfl(a0, 8*g+0) + k0.y * __shfl(a0, 8*g+1)
                   + k0.z * __shfl(a0, 8*g+2) + k0.w * __shfl(a0, 8*g+3)
                   + k1.x * __shfl(a0, 8*g+4) + k1.y * __shfl(a0, 8*g+5)
                   + k1.z * __shfl(a0, 8*g+6) + k1.w * __shfl(a0, 8*g+7);
        float nbs = n0.x * __shfl(u0,0) + n0.y * __shfl(u0,1)
                  + n0.z * __shfl(u0,2) + n0.w * __shfl(u0,3)
                  + n1.x * __shfl(u0,4) + n1.y * __shfl(u0,5)
                  + n1.z * __shfl(u0,6) + n1.w * __shfl(u0,7);
        part += (g == 3) ? nbs : 0.f;
        part += __shfl_xor(part, 16);
        part += __shfl_xor(part, 32);
        gv = part;
    }
    float4 mA, mB, mC, mD, kp0, kp1, np0, np1;
    float upn, apn;
    {
        const float4* p = (const float4*)(wsM + 256 + i * 16);
        mA = p[0]; mB = p[1]; mC = p[2]; mD = p[3];
        kp0 = *(const float4*)(wsK + 512 + i * 32 + 8 * g);
        kp1 = *(const float4*)(wsK + 512 + i * 32 + 8 * g + 4);
        np0 = *(const float4*)(wsN + 128 + i * 8);
        np1 = *(const float4*)(wsN + 128 + i * 8 + 4);
        upn = ub[8 + (lane & 7)];
        apn = ab[32 + (lane & 31)];
    }

    for (int t = 0; t < TT; ++t) {
        const int t2 = (t + 2 < TT) ? t + 2 : TT - 1;
        const int s2 = (t2 < WARM) ? t2 : WARM;
        const float4* mp = (const float4*)(wsM + (size_t)s2 * 256 + i * 16);
        float4 l0 = mp[0], l1 = mp[1], l2 = mp[2], l3 = mp[3];
        float4 kl0 = *(const float4*)(wsK + (size_t)s2 * 512 + i * 32 + 8 * g);
        float4 kl1 = *(const float4*)(wsK + (size_t)s2 * 512 + i * 32 + 8 * g + 4);
        float4 nl0 = *(const float4*)(wsN + (size_t)s2 * 128 + i * 8);
        float4 nl1 = *(const float4*)(wsN + (size_t)s2 * 128 + i * 8 + 4);
        float ul = ub[t2 * 8 + (lane & 7)];
        float al = ab[t2 * 32 + (lane & 31)];

        float s0 = gv, s1 = 0.f, s2f = 0.f, s3 = 0.f;
#pragma unroll
        for (int q = 0; q < 16; q += 4) {
            s0  += Mc[q]     * __shfl(mn, q);
            s1  += Mc[q + 1] * __shfl(mn, q + 1);
            s2f += Mc[q + 2] * __shfl(mn, q + 2);
            s3  += Mc[q + 3] * __shfl(mn, q + 3);
        }
        mn = (s0 + s1) + (s2f + s3);
        if (lane < 16) ob[t * 16 + lane] = mn;

        float part = kp0.x * __shfl(apn, 8*g+0) + kp0.y * __shfl(apn, 8*g+1)
                   + kp0.z * __shfl(apn, 8*g+2) + kp0.w * __shfl(apn, 8*g+3)
                   + kp1.x * __shfl(apn, 8*g+4) + kp1.y * __shfl(apn, 8*g+5)
                   + kp1.z * __shfl(apn, 8*g+6) + kp1.w * __shfl(apn, 8*g+7);
        float nbs = np0.x * __shfl(upn,0) + np0.y * __shfl(upn,1)
                  + np0.z * __shfl(upn,2) + np0.w * __shfl(upn,3)
                  + np1.x * __shfl(upn,4) + np1.y * __shfl(upn,5)
                  + np1.z * __shfl(upn,6) + np1.w * __shfl(upn,7);
        part += (g == 3) ? nbs : 0.f;
        part += __shfl_xor(part, 16);
        part += __shfl_xor(part, 32);
        gv = part;

        Mc[0]=mA.x; Mc[1]=mA.y; Mc[2]=mA.z; Mc[3]=mA.w;
        Mc[4]=mB.x; Mc[5]=mB.y; Mc[6]=mB.z; Mc[7]=mB.w;
        Mc[8]=mC.x; Mc[9]=mC.y; Mc[10]=mC.z; Mc[11]=mC.w;
        Mc[12]=mD.x; Mc[13]=mD.y; Mc[14]=mD.z; Mc[15]=mD.w;
        mA = l0; mB = l1; mC = l2; mD = l3;
        kp0 = kl0; kp1 = kl1; np0 = nl0; np1 = nl1;
        upn = ul; apn = al;
    }
}

extern "C" void kernel_launch(void* const* d_in, const int* in_sizes, int n_in,
                              void* d_out, int out_size, void* d_ws, size_t ws_size,
                              hipStream_t stream) {
    const float* mean0 = nullptr; const float* cov0 = nullptr;
    const float* u = nullptr;     const float* a = nullptr;
    const float* Mm = nullptr;    const float* Nm = nullptr;
    const float* dv = nullptr;    const float* Bm = nullptr;
    const float* Cm = nullptr;    const float* nxp = nullptr;
    const float* nap = nullptr;
    for (int i = 0; i < n_in; ++i) {
        const float* p = (const float*)d_in[i];
        switch (in_sizes[i]) {
            case 256 * 16:        mean0 = p; break;
            case 256 * 256:       cov0 = p; break;
            case 256 * 256 * 8:   u = p; break;
            case 256 * 256 * 32:  a = p; break;
            case 256:             if (!Mm) Mm = p; else Nm = p; break;
            case 16:              if (!dv) dv = p; else nxp = p; break;
            case 128:             Bm = p; break;
            case 512:             Cm = p; break;
            case 32:              nap = p; break;
            default: break;
        }
    }
    float* ws   = (float*)d_ws;
    float* wsK  = ws + OFF_K;
    float* wsM  = ws + OFF_MC;
    float* wsN  = ws + OFF_NB;
    float* wsp  = ws + OFF_P0;
    float* wseg = ws + OFF_WSEG;
    float* bnd  = ws + OFF_BND;

    setup_k<<<1, 256, 0, stream>>>(Mm, Nm, dv, Bm, Cm, nxp, nap, ws);
    chain_k<<<WARM + 1, 64, 0, stream>>>(cov0, Bm, ws, wsK, wsM, wsN);
    if (ws_size >= NEED_WS_BYTES) {
        phA_k<<<16 * 256, 64, 0, stream>>>(u, a, ws, wsK, wsM, wsN, wseg, wsp);
        phB_k<<<256, 64, 0, stream>>>(mean0, wsp, wseg, bnd);
        phC_k<<<16 * 256, 64, 0, stream>>>(u, a, wsK, wsM, wsN, bnd, (float*)d_out);
    } else {
        meanf_k<<<256, 64, 0, stream>>>(mean0, u, a, wsK, wsM, wsN, (float*)d_out);
    }
}

// Round 12
// 204.898 us; speedup vs baseline: 4.0897x; 1.1109x over previous
//
#include <hip/hip_runtime.h>
#include <math.h>

#define TT 256
#define WARM 16
// ws float offsets
#define OFF_A    0      // A (256)
#define OFF_W    512    // W = C^T Na^-1 (16x32 = 512)
#define OFF_CA   1024   // CA = C A (512)
#define OFF_CB   1536   // CB = C B (256)
#define OFF_MAPS 1792   // 5 maps x {E(256),F(256),H(256)} = 3840 -> 5632
#define OFF_K    5632   // 17 x 512 -> 14336
#define OFF_MC   14336  // 17 x 256 -> 18688
#define OFF_NB   18688  // 17 x 128 -> 20864
#define OFF_P0   20864  // Mseg0 (256) -> 21120
#define OFF_PP   21120  // Mc16^16 (256) -> 21376
#define OFF_WSEG 21376  // 16 x 256 x 16 -> 86912
#define OFF_BND  86912  // 16 x 256 x 16 -> 152448
#define NEED_WS_BYTES ((size_t)152448 * 4)

__device__ __forceinline__ float softplus(float v) {
    return fmaxf(v, 0.0f) + log1pf(expf(-fabsf(v)));
}

// Shuffle-based Gauss-Jordan, [X|I] -> [I|X^-1] (verified R5-R11).
// Layout: lane (i, gq) holds aug[i][8*gq+k], k=0..7.
__device__ __forceinline__ void gj16(float (&aug)[8], const int i, const int gq) {
#pragma unroll
    for (int j = 0; j < 16; ++j) {
        float prow[8];
#pragma unroll
        for (int k = 0; k < 8; ++k) prow[k] = __shfl(aug[k], j + 16 * gq);
        const float pjj = __shfl(aug[j & 7], j + 16 * (j >> 3));
        const float cij = __shfl(aug[j & 7], i + 16 * (j >> 3));
        const float pivinv = 1.0f / pjj;
        const float f = cij * pivinv;
#pragma unroll
        for (int k = 0; k < 8; ++k)
            aug[k] = (i == j) ? prow[k] * pivinv : aug[k] - f * prow[k];
    }
}

// ---------------------------------------------------------------------------
// Kernel 1 (R12: code-size-minimized). 256 threads. Register MGS QR (rolled
// j-loop, bit-identical arithmetic to R11), assembly, then Woodbury doubling
// in LDS with runtime loops (verified R2/R4 double-buffered GJ pattern;
// same summation order as the verified R10 register doubling).
// ---------------------------------------------------------------------------
__global__ __launch_bounds__(256) void setup_k(
    const float* __restrict__ Mm, const float* __restrict__ Nm,
    const float* __restrict__ dvec, const float* __restrict__ Bm,
    const float* __restrict__ Cm, const float* __restrict__ nx,
    const float* __restrict__ na, float* __restrict__ ws)
{
    __shared__ float qm[16][17], qn[16][17], T0s[16][17];
    __shared__ float sC[32][17], sW[16][33], sAm[16][17], sBm[16][9];
    __shared__ float sE[16][17], sF[16][17], sH[16][17];
    __shared__ float sT[16][17], sT2[16][17];
    __shared__ float aug[2][16][33];
    __shared__ float spv[16], d2[16], sNai[32], sNxi[16];
    const int tid = threadIdx.x;

    qm[tid >> 4][tid & 15] = Mm[tid];
    qn[tid >> 4][tid & 15] = Nm[tid];
    for (int e = tid; e < 512; e += 256) sC[e >> 4][e & 15] = Cm[e];
    if (tid < 128) sBm[tid >> 3][tid & 7] = Bm[tid];
    if (tid < 16) {
        float s = softplus(dvec[tid]);
        spv[tid] = sqrtf(s);
        d2[tid] = 1.0f / sqrtf(1.0f + s);
        sNxi[tid] = 1.0f / (softplus(nx[tid]) + 1e-4f);
    }
    if (tid < 32) sNai[tid] = 1.0f / (softplus(na[tid]) + 1e-4f);
    __syncthreads();

    // ---- wave 0: register MGS on both matrices, ROLLED j-loop ----
    if (tid < 64) {
        const int j0 = tid & 15;
        const int mi = tid >> 4;
        float (*Qs)[17] = (mi == 1) ? qn : qm;
        float col[16];
#pragma unroll
        for (int r = 0; r < 16; ++r) col[r] = Qs[r][j0];
        const int base = tid & 48;
#pragma unroll 1
        for (int j = 0; j < 16; ++j) {
            float qj[16];
#pragma unroll
            for (int r = 0; r < 16; ++r) qj[r] = __shfl(col[r], base + j);
            float nrm = 0.f;
#pragma unroll
            for (int r = 0; r < 16; ++r) nrm += qj[r] * qj[r];
            const float scal = 1.0f / sqrtf(nrm);
#pragma unroll
            for (int r = 0; r < 16; ++r) qj[r] *= scal;
            if (j0 == j) {
#pragma unroll
                for (int r = 0; r < 16; ++r) col[r] = qj[r];
            } else if (j0 > j) {
                float pr = 0.f;
#pragma unroll
                for (int r = 0; r < 16; ++r) pr += qj[r] * col[r];
#pragma unroll
                for (int r = 0; r < 16; ++r) col[r] -= pr * qj[r];
            }
        }
        if (mi < 2) {
#pragma unroll
            for (int r = 0; r < 16; ++r) Qs[r][j0] = col[r];
        }
    }
    __syncthreads();

    // ---- assembly (1 element per thread) ----
    {
        const int ii = tid >> 4, j = tid & 15;
        float s = 0.f;
        for (int q = 0; q < 16; ++q) s += qm[ii][q] * d2[q] * qn[j][q];
        T0s[ii][j] = spv[ii] * s;
    }
    __syncthreads();
    {
        const int ii = tid >> 4, j = tid & 15;
        float s = 0.f;
        for (int q = 0; q < 16; ++q) s += qn[ii][q] * T0s[q][j];
        ws[OFF_A + tid] = s;
        sAm[ii][j] = s;
    }
    for (int e = tid; e < 512; e += 256) {
        int q = e >> 5, r = e & 31;
        float w = sC[r][q] * sNai[r];
        sW[q][r] = w;
        ws[OFF_W + e] = w;
    }
    __syncthreads();
    // base map: E = Nxi A, H = A^T Nxi A, F = G + diag(Nxi)
    {
        const int ii = tid >> 4, j = tid & 15;
        float g = 0.f;
        for (int r = 0; r < 32; ++r) g += sC[r][ii] * sW[j][r];
        sF[ii][j] = g + ((ii == j) ? sNxi[ii] : 0.f);
        sE[ii][j] = sNxi[ii] * sAm[ii][j];
        float hsum = 0.f;
        for (int q = 0; q < 16; ++q) hsum += sAm[q][ii] * sNxi[q] * sAm[q][j];
        sH[ii][j] = hsum;
    }
    for (int e = tid; e < 512; e += 256) {
        int r = e >> 4, j = e & 15;
        float s = 0.f;
        for (int q = 0; q < 16; ++q) s += sC[r][q] * sAm[q][j];
        ws[OFF_CA + e] = s;
    }
    {
        int r = tid >> 3, j = tid & 7;
        float s = 0.f;
        for (int q = 0; q < 16; ++q) s += sC[r][q] * sBm[q][j];
        ws[OFF_CB + tid] = s;
    }
    __syncthreads();
    // store map 0
    ws[OFF_MAPS + tid]       = sE[tid >> 4][tid & 15];
    ws[OFF_MAPS + 256 + tid] = sF[tid >> 4][tid & 15];
    ws[OFF_MAPS + 512 + tid] = sH[tid >> 4][tid & 15];

    // ---- Woodbury doubling, LDS + runtime loops (small code) ----
    // V=F+H, Z=V^-1: F' = F - T E^T, H' = H - T2 E, E' = T E,
    // with T = E Z, T2 = E^T Z.  (Algebra verified R10.)
#pragma unroll 1
    for (int m = 1; m <= 4; ++m) {
        // aug[0] = [F+H | I]
        for (int e = tid; e < 512; e += 256) {
            int r = e >> 5, c = e & 31;
            aug[0][r][c] = (c < 16) ? (sF[r][c] + sH[r][c])
                                    : ((c - 16 == r) ? 1.f : 0.f);
        }
        __syncthreads();
        // double-buffered GJ, no pivoting (SPD), 1 barrier/pivot
        int cur = 0;
#pragma unroll 1
        for (int j = 0; j < 16; ++j) {
            const float pivinv = 1.0f / aug[cur][j][j];
            for (int e = tid; e < 512; e += 256) {
                int r = e >> 5, c = e & 31;
                float ajc = aug[cur][j][c];
                aug[1 - cur][r][c] = (r == j)
                    ? ajc * pivinv
                    : aug[cur][r][c] - aug[cur][r][j] * pivinv * ajc;
            }
            __syncthreads();
            cur ^= 1;
        }
        // T = E Z, T2 = E^T Z   (Z[q][jj] = aug[cur][q][16+jj])
        {
            const int ii = tid >> 4, jj = tid & 15;
            float t = 0.f, t2 = 0.f;
            for (int q = 0; q < 16; ++q) {
                const float z = aug[cur][q][16 + jj];
                t  += sE[ii][q] * z;
                t2 += sE[q][ii] * z;
            }
            sT[ii][jj] = t;
            sT2[ii][jj] = t2;
        }
        __syncthreads();
        // F' = F - T E^T ; H' = H - T2 E ; E' = T E
        {
            const int ii = tid >> 4, jj = tid & 15;
            float f = sF[ii][jj], hh = sH[ii][jj], e2 = 0.f;
            for (int q = 0; q < 16; ++q) {
                f  -= sT[ii][q]  * sE[jj][q];
                hh -= sT2[ii][q] * sE[q][jj];
                e2 += sT[ii][q]  * sE[q][jj];
            }
            __syncthreads();   // all reads of sE/sF/sH done
            sF[ii][jj] = f;
            sH[ii][jj] = hh;
            sE[ii][jj] = e2;
        }
        __syncthreads();
        // store map m
        const int base = OFF_MAPS + m * 768;
        ws[base + tid]       = sE[tid >> 4][tid & 15];
        ws[base + 256 + tid] = sF[tid >> 4][tid & 15];
        ws[base + 512 + tid] = sH[tid >> 4][tid & 15];
    }
}

// ---------------------------------------------------------------------------
// Kernel 2 (verified R10/R11, unchanged): gain chain via binary maps.
// ---------------------------------------------------------------------------
__global__ __launch_bounds__(64) void chain_k(
    const float* __restrict__ cov0, const float* __restrict__ Bm,
    const float* __restrict__ ws, float* __restrict__ wsK,
    float* __restrict__ wsM, float* __restrict__ wsN)
{
    __shared__ float sW[16][33], sP[16][17], sK[16][33];
    __shared__ float sCA[32][17], sCB[32][9];
    const int lane = threadIdx.x;
    const int t = blockIdx.x;            // 0..16
    const int n = t + 1;
    const int i = lane & 15, gq = lane >> 4, h = gq & 1;

    for (int e = lane; e < 512; e += 64) sW[e >> 5][e & 31] = ws[OFF_W + e];
    for (int e = lane; e < 512; e += 64) sCA[e >> 4][e & 15] = ws[OFF_CA + e];
    for (int e = lane; e < 256; e += 64) sCB[e >> 3][e & 7] = ws[OFF_CB + e];

    float aug[8];
#pragma unroll
    for (int k = 0; k < 8; ++k)
        aug[k] = (gq < 2) ? cov0[i * 16 + 8 * gq + k]
                          : ((8 * (gq - 2) + k == i) ? 1.f : 0.f);
    gj16(aug, i, gq);
    float L_r[8];
#pragma unroll
    for (int k = 0; k < 8; ++k) L_r[k] = __shfl(aug[k], i + 16 * (2 + h));

    for (int m = 4; m >= 0; --m) {
        if (!(n & (1 << m))) continue;
        const int base = OFF_MAPS + m * 768;
        float Er[16], Fr[8], Hr[8];
#pragma unroll
        for (int q = 0; q < 16; ++q) Er[q] = ws[base + i * 16 + q];
#pragma unroll
        for (int k = 0; k < 8; ++k) {
            Fr[k] = ws[base + 256 + i * 16 + 8 * h + k];
            Hr[k] = ws[base + 512 + i * 16 + 8 * h + k];
        }
#pragma unroll
        for (int k = 0; k < 8; ++k)
            aug[k] = (gq < 2) ? (L_r[k] + Hr[k]) : ((8 * (gq - 2) + k == i) ? 1.f : 0.f);
        gj16(aug, i, gq);
        float T_r[8];
#pragma unroll
        for (int k = 0; k < 8; ++k) T_r[k] = 0.f;
#pragma unroll
        for (int q = 0; q < 16; ++q) {
            const float eq = Er[q];
#pragma unroll
            for (int k = 0; k < 8; ++k) T_r[k] += eq * __shfl(aug[k], q + 16 * (2 + h));
        }
        float Trow[16];
#pragma unroll
        for (int q = 0; q < 16; ++q) Trow[q] = __shfl(T_r[q & 7], i + 16 * (q >> 3));
#pragma unroll
        for (int k = 0; k < 8; ++k) L_r[k] = Fr[k];
#pragma unroll
        for (int q = 0; q < 16; ++q) {
            const float tq = Trow[q];
#pragma unroll
            for (int k = 0; k < 8; ++k) L_r[k] -= tq * __shfl(Er[q], 8 * h + k);
        }
    }
    // P = L^-1
#pragma unroll
    for (int k = 0; k < 8; ++k)
        aug[k] = (gq < 2) ? L_r[k] : ((8 * (gq - 2) + k == i) ? 1.f : 0.f);
    gj16(aug, i, gq);
    float P_r[8];
#pragma unroll
    for (int k = 0; k < 8; ++k) P_r[k] = __shfl(aug[k], i + 16 * (2 + h));
    if (lane < 32) {
#pragma unroll
        for (int k = 0; k < 8; ++k) sP[i][8 * h + k] = P_r[k];
    }
    __syncthreads();
#pragma unroll
    for (int m = 0; m < 8; ++m) {
        const int e = lane + 64 * m, ii = e >> 5, rr = e & 31;
        float s = 0.f;
#pragma unroll
        for (int q = 0; q < 16; ++q) s += sP[ii][q] * sW[q][rr];
        sK[ii][rr] = s;
        wsK[(size_t)t * 512 + e] = s;
    }
    __syncthreads();
#pragma unroll
    for (int m = 0; m < 4; ++m) {
        const int e = lane + 64 * m, ii = e >> 4, jj = e & 15;
        float s = ws[OFF_A + e];
#pragma unroll
        for (int r = 0; r < 32; ++r) s -= sK[ii][r] * sCA[r][jj];
        wsM[(size_t)t * 256 + e] = s;
    }
#pragma unroll
    for (int m = 0; m < 2; ++m) {
        const int e = lane + 64 * m, ii = e >> 3, jj = e & 7;
        float s = Bm[e];
#pragma unroll
        for (int r = 0; r < 32; ++r) s -= sK[ii][r] * sCB[r][jj];
        wsN[(size_t)t * 128 + e] = s;
    }
}

// ---------------------------------------------------------------------------
// Kernel 3 (verified R10/R11, unchanged): phase A.
// ---------------------------------------------------------------------------
__global__ __launch_bounds__(64) void phA_k(
    const float* __restrict__ u, const float* __restrict__ a,
    const float* __restrict__ ws, const float* __restrict__ wsK,
    const float* __restrict__ wsM, const float* __restrict__ wsN,
    float* __restrict__ wseg, float* __restrict__ wsp)
{
    const int lane = threadIdx.x;
    const int i = lane & 15, g = lane >> 4;
    const int seg = blockIdx.x >> 8;
    const int b = blockIdx.x & 255;

    float mcs[16][4];
#pragma unroll
    for (int j = 0; j < 16; ++j) {
        const int tc = (seg == 0) ? j : 16;
        const float4 v = *(const float4*)(wsM + (size_t)tc * 256 + i * 16 + 4 * g);
        mcs[j][0] = v.x; mcs[j][1] = v.y; mcs[j][2] = v.z; mcs[j][3] = v.w;
    }
    float kc[8], nbc[8];
    if (seg != 0) {
        const float4 k0 = *(const float4*)(wsK + (size_t)16 * 512 + i * 32 + 8 * g);
        const float4 k1 = *(const float4*)(wsK + (size_t)16 * 512 + i * 32 + 8 * g + 4);
        const float4 n0 = *(const float4*)(wsN + (size_t)16 * 128 + i * 8);
        const float4 n1 = *(const float4*)(wsN + (size_t)16 * 128 + i * 8 + 4);
        kc[0]=k0.x; kc[1]=k0.y; kc[2]=k0.z; kc[3]=k0.w;
        kc[4]=k1.x; kc[5]=k1.y; kc[6]=k1.z; kc[7]=k1.w;
        nbc[0]=n0.x; nbc[1]=n0.y; nbc[2]=n0.z; nbc[3]=n0.w;
        nbc[4]=n1.x; nbc[5]=n1.y; nbc[6]=n1.z; nbc[7]=n1.w;
    }

    float w = 0.f;
#pragma unroll
    for (int j = 0; j < 16; ++j) {
        const int t = 16 * seg + j;
        float kr[8], nbr[8];
        if (seg == 0) {
            const float4 k0 = *(const float4*)(wsK + (size_t)j * 512 + i * 32 + 8 * g);
            const float4 k1 = *(const float4*)(wsK + (size_t)j * 512 + i * 32 + 8 * g + 4);
            const float4 n0 = *(const float4*)(wsN + (size_t)j * 128 + i * 8);
            const float4 n1 = *(const float4*)(wsN + (size_t)j * 128 + i * 8 + 4);
            kr[0]=k0.x; kr[1]=k0.y; kr[2]=k0.z; kr[3]=k0.w;
            kr[4]=k1.x; kr[5]=k1.y; kr[6]=k1.z; kr[7]=k1.w;
            nbr[0]=n0.x; nbr[1]=n0.y; nbr[2]=n0.z; nbr[3]=n0.w;
            nbr[4]=n1.x; nbr[5]=n1.y; nbr[6]=n1.z; nbr[7]=n1.w;
        } else {
#pragma unroll
            for (int k = 0; k < 8; ++k) { kr[k] = kc[k]; nbr[k] = nbc[k]; }
        }
        const float a0 = a[(size_t)b * (TT * 32) + t * 32 + (lane & 31)];
        const float u0 = u[(size_t)b * (TT * 8) + t * 8 + (lane & 7)];
        float gvp = kr[0] * __shfl(a0, 8*g+0) + kr[1] * __shfl(a0, 8*g+1)
                  + kr[2] * __shfl(a0, 8*g+2) + kr[3] * __shfl(a0, 8*g+3)
                  + kr[4] * __shfl(a0, 8*g+4) + kr[5] * __shfl(a0, 8*g+5)
                  + kr[6] * __shfl(a0, 8*g+6) + kr[7] * __shfl(a0, 8*g+7);
        float nbs = nbr[0] * __shfl(u0,0) + nbr[1] * __shfl(u0,1)
                  + nbr[2] * __shfl(u0,2) + nbr[3] * __shfl(u0,3)
                  + nbr[4] * __shfl(u0,4) + nbr[5] * __shfl(u0,5)
                  + nbr[6] * __shfl(u0,6) + nbr[7] * __shfl(u0,7);
        gvp += (g == 3) ? nbs : 0.f;
        gvp += __shfl_xor(gvp, 16);
        gvp += __shfl_xor(gvp, 32);
        float part = mcs[j][0] * __shfl(w, 4*g+0) + mcs[j][1] * __shfl(w, 4*g+1)
                   + mcs[j][2] * __shfl(w, 4*g+2) + mcs[j][3] * __shfl(w, 4*g+3);
        part += __shfl_xor(part, 16);
        part += __shfl_xor(part, 32);
        w = part + gvp;
    }
    if (lane < 16) wseg[(size_t)seg * 4096 + b * 16 + i] = w;

    if (blockIdx.x == 0) {          // P0 = Mc15 ... Mc0
        float pr[4];
#pragma unroll
        for (int k = 0; k < 4; ++k) pr[k] = (4 * g + k == i) ? 1.f : 0.f;
#pragma unroll
        for (int j = 0; j < 16; ++j) {
            float np[4] = {0.f, 0.f, 0.f, 0.f};
#pragma unroll
            for (int q = 0; q < 16; ++q) {
                const float mq = __shfl(mcs[j][q & 3], i + 16 * (q >> 2));
#pragma unroll
                for (int k = 0; k < 4; ++k) np[k] += mq * __shfl(pr[k], q + 16 * g);
            }
#pragma unroll
            for (int k = 0; k < 4; ++k) pr[k] = np[k];
        }
#pragma unroll
        for (int k = 0; k < 4; ++k) wsp[i * 16 + 4 * g + k] = pr[k];
    }
    if (blockIdx.x == 256) {        // PP = Mc16^16
        float pr[4];
#pragma unroll
        for (int k = 0; k < 4; ++k) pr[k] = mcs[0][k];
#pragma unroll
        for (int r = 0; r < 4; ++r) {
            float np[4] = {0.f, 0.f, 0.f, 0.f};
#pragma unroll
            for (int q = 0; q < 16; ++q) {
                const float sq = __shfl(pr[q & 3], i + 16 * (q >> 2));
#pragma unroll
                for (int k = 0; k < 4; ++k) np[k] += sq * __shfl(pr[k], q + 16 * g);
            }
#pragma unroll
            for (int k = 0; k < 4; ++k) pr[k] = np[k];
        }
#pragma unroll
        for (int k = 0; k < 4; ++k) wsp[256 + i * 16 + 4 * g + k] = pr[k];
    }
}

// ---------------------------------------------------------------------------
// Kernel 4 (verified R9-R11, unchanged): phase B.
// ---------------------------------------------------------------------------
__global__ __launch_bounds__(64) void phB_k(
    const float* __restrict__ mean0, const float* __restrict__ wsp,
    const float* __restrict__ wseg, float* __restrict__ bnd)
{
    const int lane = threadIdx.x;
    const int i = lane & 15, g = lane >> 4;
    const int b = blockIdx.x;

    const float4 v0 = *(const float4*)(wsp + i * 16 + 4 * g);
    const float4 vp = *(const float4*)(wsp + 256 + i * 16 + 4 * g);
    const float m0s[4] = {v0.x, v0.y, v0.z, v0.w};
    const float mps[4] = {vp.x, vp.y, vp.z, vp.w};
    float wv[16];
#pragma unroll
    for (int s = 0; s < 16; ++s) wv[s] = wseg[(size_t)s * 4096 + b * 16 + i];

    float mn = mean0[b * 16 + i];
#pragma unroll
    for (int s = 0; s < 16; ++s) {
        if (lane < 16) bnd[(size_t)s * 4096 + b * 16 + i] = mn;
        const float c0 = (s == 0) ? m0s[0] : mps[0];
        const float c1 = (s == 0) ? m0s[1] : mps[1];
        const float c2 = (s == 0) ? m0s[2] : mps[2];
        const float c3 = (s == 0) ? m0s[3] : mps[3];
        float part = c0 * __shfl(mn, 4 * g + 0) + c1 * __shfl(mn, 4 * g + 1)
                   + c2 * __shfl(mn, 4 * g + 2) + c3 * __shfl(mn, 4 * g + 3);
        part += __shfl_xor(part, 16);
        part += __shfl_xor(part, 32);
        mn = part + wv[s];
    }
}

// ---------------------------------------------------------------------------
// Kernel 5 (verified R10/R11, unchanged): phase C.
// ---------------------------------------------------------------------------
__global__ __launch_bounds__(64) void phC_k(
    const float* __restrict__ u, const float* __restrict__ a,
    const float* __restrict__ wsK, const float* __restrict__ wsM,
    const float* __restrict__ wsN, const float* __restrict__ bnd,
    float* __restrict__ out)
{
    const int lane = threadIdx.x;
    const int i = lane & 15, g = lane >> 4;
    const int seg = blockIdx.x >> 8;
    const int b = blockIdx.x & 255;

    float mcs[16][4];
#pragma unroll
    for (int j = 0; j < 16; ++j) {
        const int tc = (seg == 0) ? j : 16;
        const float4 v = *(const float4*)(wsM + (size_t)tc * 256 + i * 16 + 4 * g);
        mcs[j][0] = v.x; mcs[j][1] = v.y; mcs[j][2] = v.z; mcs[j][3] = v.w;
    }
    float kc[8], nbc[8];
    if (seg != 0) {
        const float4 k0 = *(const float4*)(wsK + (size_t)16 * 512 + i * 32 + 8 * g);
        const float4 k1 = *(const float4*)(wsK + (size_t)16 * 512 + i * 32 + 8 * g + 4);
        const float4 n0 = *(const float4*)(wsN + (size_t)16 * 128 + i * 8);
        const float4 n1 = *(const float4*)(wsN + (size_t)16 * 128 + i * 8 + 4);
        kc[0]=k0.x; kc[1]=k0.y; kc[2]=k0.z; kc[3]=k0.w;
        kc[4]=k1.x; kc[5]=k1.y; kc[6]=k1.z; kc[7]=k1.w;
        nbc[0]=n0.x; nbc[1]=n0.y; nbc[2]=n0.z; nbc[3]=n0.w;
        nbc[4]=n1.x; nbc[5]=n1.y; nbc[6]=n1.z; nbc[7]=n1.w;
    }

    float mn = bnd[(size_t)seg * 4096 + b * 16 + i];
    float* ob = out + (size_t)b * 4096 + (size_t)(16 * seg) * 16;
#pragma unroll
    for (int j = 0; j < 16; ++j) {
        const int t = 16 * seg + j;
        float kr[8], nbr[8];
        if (seg == 0) {
            const float4 k0 = *(const float4*)(wsK + (size_t)j * 512 + i * 32 + 8 * g);
            const float4 k1 = *(const float4*)(wsK + (size_t)j * 512 + i * 32 + 8 * g + 4);
            const float4 n0 = *(const float4*)(wsN + (size_t)j * 128 + i * 8);
            const float4 n1 = *(const float4*)(wsN + (size_t)j * 128 + i * 8 + 4);
            kr[0]=k0.x; kr[1]=k0.y; kr[2]=k0.z; kr[3]=k0.w;
            kr[4]=k1.x; kr[5]=k1.y; kr[6]=k1.z; kr[7]=k1.w;
            nbr[0]=n0.x; nbr[1]=n0.y; nbr[2]=n0.z; nbr[3]=n0.w;
            nbr[4]=n1.x; nbr[5]=n1.y; nbr[6]=n1.z; nbr[7]=n1.w;
        } else {
#pragma unroll
            for (int k = 0; k < 8; ++k) { kr[k] = kc[k]; nbr[k] = nbc[k]; }
        }
        const float a0 = a[(size_t)b * (TT * 32) + t * 32 + (lane & 31)];
        const float u0 = u[(size_t)b * (TT * 8) + t * 8 + (lane & 7)];
        float gvp = kr[0] * __shfl(a0, 8*g+0) + kr[1] * __shfl(a0, 8*g+1)
                  + kr[2] * __shfl(a0, 8*g+2) + kr[3] * __shfl(a0, 8*g+3)
                  + kr[4] * __shfl(a0, 8*g+4) + kr[5] * __shfl(a0, 8*g+5)
                  + kr[6] * __shfl(a0, 8*g+6) + kr[7] * __shfl(a0, 8*g+7);
        float nbs = nbr[0] * __shfl(u0,0) + nbr[1] * __shfl(u0,1)
                  + nbr[2] * __shfl(u0,2) + nbr[3] * __shfl(u0,3)
                  + nbr[4] * __shfl(u0,4) + nbr[5] * __shfl(u0,5)
                  + nbr[6] * __shfl(u0,6) + nbr[7] * __shfl(u0,7);
        gvp += (g == 3) ? nbs : 0.f;
        gvp += __shfl_xor(gvp, 16);
        gvp += __shfl_xor(gvp, 32);
        float part = mcs[j][0] * __shfl(mn, 4*g+0) + mcs[j][1] * __shfl(mn, 4*g+1)
                   + mcs[j][2] * __shfl(mn, 4*g+2) + mcs[j][3] * __shfl(mn, 4*g+3);
        part += __shfl_xor(part, 16);
        part += __shfl_xor(part, 32);
        mn = part + gvp;
        if (lane < 16) ob[j * 16 + i] = mn;
    }
}

// ---------------------------------------------------------------------------
// Fallback (verified R6/R8/R9, unchanged): serial mean pass if ws too small.
// ---------------------------------------------------------------------------
__global__ __launch_bounds__(64) void meanf_k(
    const float* __restrict__ mean0, const float* __restrict__ u,
    const float* __restrict__ a, const float* __restrict__ wsK,
    const float* __restrict__ wsM, const float* __restrict__ wsN,
    float* __restrict__ out)
{
    const int lane = threadIdx.x;
    const int b = blockIdx.x;
    const int i = lane & 15;
    const int g = lane >> 4;

    const float* ub = u + (size_t)b * TT * 8;
    const float* ab = a + (size_t)b * TT * 32;
    float* ob = out + (size_t)b * TT * 16;

    float mn = mean0[b * 16 + i];
    float Mc[16];
    {
        const float4* p = (const float4*)(wsM + i * 16);
        float4 x0 = p[0], x1 = p[1], x2 = p[2], x3 = p[3];
        Mc[0]=x0.x; Mc[1]=x0.y; Mc[2]=x0.z; Mc[3]=x0.w;
        Mc[4]=x1.x; Mc[5]=x1.y; Mc[6]=x1.z; Mc[7]=x1.w;
        Mc[8]=x2.x; Mc[9]=x2.y; Mc[10]=x2.z; Mc[11]=x2.w;
        Mc[12]=x3.x; Mc[13]=x3.y; Mc[14]=x3.z; Mc[15]=x3.w;
    }
    float gv;
    {
        float4 k0 = *(const float4*)(wsK + i * 32 + 8 * g);
        float4 k1 = *(const float4*)(wsK + i * 32 + 8 * g + 4);
        float4 n0 = *(const float4*)(wsN + i * 8);
        float4 n1 = *(const float4*)(wsN + i * 8 + 4);
        float u0 = ub[lane & 7];
        float a0 = ab[lane & 31];
        float part = k0.x * __shfl(a0, 8*g+0) + k0.y * __shfl(a0, 8*g+1)
                   + k0.z * __shfl(a0, 8*g+2) + k0.w * __shfl(a0, 8*g+3)
                   + k1.x * __shfl(a0, 8*g+4) + k1.y * __shfl(a0, 8*g+5)
                   + k1.z * __shfl(a0, 8*g+6) + k1.w * __shfl(a0, 8*g+7);
        float nbs = n0.x * __shfl(u0,0) + n0.y * __shfl(u0,1)
                  + n0.z * __shfl(u0,2) + n0.w * __shfl(u0,3)
                  + n1.x * __shfl(u0,4) + n1.y * __shfl(u0,5)
                  + n1.z * __shfl(u0,6) + n1.w * __shfl(u0,7);
        part += (g == 3) ? nbs : 0.f;
        part += __shfl_xor(part, 16);
        part += __shfl_xor(part, 32);
        gv = part;
    }
    float4 mA, mB, mC, mD, kp0, kp1, np0, np1;
    float upn, apn;
    {
        const float4* p = (const float4*)(wsM + 256 + i * 16);
        mA = p[0]; mB = p[1]; mC = p[2]; mD = p[3];
        kp0 = *(const float4*)(wsK + 512 + i * 32 + 8 * g);
        kp1 = *(const float4*)(wsK + 512 + i * 32 + 8 * g + 4);
        np0 = *(const float4*)(wsN + 128 + i * 8);
        np1 = *(const float4*)(wsN + 128 + i * 8 + 4);
        upn = ub[8 + (lane & 7)];
        apn = ab[32 + (lane & 31)];
    }

    for (int t = 0; t < TT; ++t) {
        const int t2 = (t + 2 < TT) ? t + 2 : TT - 1;
        const int s2 = (t2 < WARM) ? t2 : WARM;
        const float4* mp = (const float4*)(wsM + (size_t)s2 * 256 + i * 16);
        float4 l0 = mp[0], l1 = mp[1], l2 = mp[2], l3 = mp[3];
        float4 kl0 = *(const float4*)(wsK + (size_t)s2 * 512 + i * 32 + 8 * g);
        float4 kl1 = *(const float4*)(wsK + (size_t)s2 * 512 + i * 32 + 8 * g + 4);
        float4 nl0 = *(const float4*)(wsN + (size_t)s2 * 128 + i * 8);
        float4 nl1 = *(const float4*)(wsN + (size_t)s2 * 128 + i * 8 + 4);
        float ul = ub[t2 * 8 + (lane & 7)];
        float al = ab[t2 * 32 + (lane & 31)];

        float s0 = gv, s1 = 0.f, s2f = 0.f, s3 = 0.f;
#pragma unroll
        for (int q = 0; q < 16; q += 4) {
            s0  += Mc[q]     * __shfl(mn, q);
            s1  += Mc[q + 1] * __shfl(mn, q + 1);
            s2f += Mc[q + 2] * __shfl(mn, q + 2);
            s3  += Mc[q + 3] * __shfl(mn, q + 3);
        }
        mn = (s0 + s1) + (s2f + s3);
        if (lane < 16) ob[t * 16 + lane] = mn;

        float part = kp0.x * __shfl(apn, 8*g+0) + kp0.y * __shfl(apn, 8*g+1)
                   + kp0.z * __shfl(apn, 8*g+2) + kp0.w * __shfl(apn, 8*g+3)
                   + kp1.x * __shfl(apn, 8*g+4) + kp1.y * __shfl(apn, 8*g+5)
                   + kp1.z * __shfl(apn, 8*g+6) + kp1.w * __shfl(apn, 8*g+7);
        float nbs = np0.x * __shfl(upn,0) + np0.y * __shfl(upn,1)
                  + np0.z * __shfl(upn,2) + np0.w * __shfl(upn,3)
                  + np1.x * __shfl(upn,4) + np1.y * __shfl(upn,5)
                  + np1.z * __shfl(upn,6) + np1.w * __shfl(upn,7);
        part += (g == 3) ? nbs : 0.f;
        part += __shfl_xor(part, 16);
        part += __shfl_xor(part, 32);
        gv = part;

        Mc[0]=mA.x; Mc[1]=mA.y; Mc[2]=mA.z; Mc[3]=mA.w;
        Mc[4]=mB.x; Mc[5]=mB.y; Mc[6]=mB.z; Mc[7]=mB.w;
        Mc[8]=mC.x; Mc[9]=mC.y; Mc[10]=mC.z; Mc[11]=mC.w;
        Mc[12]=mD.x; Mc[13]=mD.y; Mc[14]=mD.z; Mc[15]=mD.w;
        mA = l0; mB = l1; mC = l2; mD = l3;
        kp0 = kl0; kp1 = kl1; np0 = nl0; np1 = nl1;
        upn = ul; apn = al;
    }
}

extern "C" void kernel_launch(void* const* d_in, const int* in_sizes, int n_in,
                              void* d_out, int out_size, void* d_ws, size_t ws_size,
                              hipStream_t stream) {
    const float* mean0 = nullptr; const float* cov0 = nullptr;
    const float* u = nullptr;     const float* a = nullptr;
    const float* Mm = nullptr;    const float* Nm = nullptr;
    const float* dv = nullptr;    const float* Bm = nullptr;
    const float* Cm = nullptr;    const float* nxp = nullptr;
    const float* nap = nullptr;
    for (int i = 0; i < n_in; ++i) {
        const float* p = (const float*)d_in[i];
        switch (in_sizes[i]) {
            case 256 * 16:        mean0 = p; break;
            case 256 * 256:       cov0 = p; break;
            case 256 * 256 * 8:   u = p; break;
            case 256 * 256 * 32:  a = p; break;
            case 256:             if (!Mm) Mm = p; else Nm = p; break;
            case 16:              if (!dv) dv = p; else nxp = p; break;
            case 128:             Bm = p; break;
            case 512:             Cm = p; break;
            case 32:              nap = p; break;
            default: break;
        }
    }
    float* ws   = (float*)d_ws;
    float* wsK  = ws + OFF_K;
    float* wsM  = ws + OFF_MC;
    float* wsN  = ws + OFF_NB;
    float* wsp  = ws + OFF_P0;
    float* wseg = ws + OFF_WSEG;
    float* bnd  = ws + OFF_BND;

    setup_k<<<1, 256, 0, stream>>>(Mm, Nm, dv, Bm, Cm, nxp, nap, ws);
    chain_k<<<WARM + 1, 64, 0, stream>>>(cov0, Bm, ws, wsK, wsM, wsN);
    if (ws_size >= NEED_WS_BYTES) {
        phA_k<<<16 * 256, 64, 0, stream>>>(u, a, ws, wsK, wsM, wsN, wseg, wsp);
        phB_k<<<256, 64, 0, stream>>>(mean0, wsp, wseg, bnd);
        phC_k<<<16 * 256, 64, 0, stream>>>(u, a, wsK, wsM, wsN, bnd, (float*)d_out);
    } else {
        meanf_k<<<256, 64, 0, stream>>>(mean0, u, a, wsK, wsM, wsN, (float*)d_out);
    }
}

// Round 13
// 202.563 us; speedup vs baseline: 4.1369x; 1.0115x over previous
//
#include <hip/hip_runtime.h>
#include <math.h>

#define TT 256
#define WARM 16
// ws float offsets (chain outputs + scan intermediates only)
#define OFF_K    5632   // 17 x 512 -> 14336
#define OFF_MC   14336  // 17 x 256 -> 18688
#define OFF_NB   18688  // 17 x 128 -> 20864
#define OFF_P0   20864  // Mseg0 (256) -> 21120
#define OFF_PP   21120  // Mc16^16 (256) -> 21376
#define OFF_WSEG 21376  // 16 x 256 x 16 -> 86912
#define OFF_BND  86912  // 16 x 256 x 16 -> 152448
#define NEED_WS_BYTES ((size_t)152448 * 4)

__device__ __forceinline__ float softplus(float v) {
    return fmaxf(v, 0.0f) + log1pf(expf(-fabsf(v)));
}

// Shuffle-based Gauss-Jordan, [X|I] -> [I|X^-1] (verified R5-R12).
// Layout: lane (i, gq) holds aug[i][8*gq+k], k=0..7.
__device__ __forceinline__ void gj16(float (&aug)[8], const int i, const int gq) {
#pragma unroll
    for (int j = 0; j < 16; ++j) {
        float prow[8];
#pragma unroll
        for (int k = 0; k < 8; ++k) prow[k] = __shfl(aug[k], j + 16 * gq);
        const float pjj = __shfl(aug[j & 7], j + 16 * (j >> 3));
        const float cij = __shfl(aug[j & 7], i + 16 * (j >> 3));
        const float pivinv = 1.0f / pjj;
        const float f = cij * pivinv;
#pragma unroll
        for (int k = 0; k < 8; ++k)
            aug[k] = (i == j) ? prow[k] * pivinv : aug[k] - f * prow[k];
    }
}

// ---------------------------------------------------------------------------
// Fused chain kernel (R13): 17 blocks x 64 threads, fully self-contained.
// Each block: QR(M),QR(N) (register MGS, verified R12), assemble A/W/CA/CB
// (verified R4/R12 e-strided LDS), base info-map E/F/H, then INTERLEAVED
// LSB-first double-and-apply (maps commute: powers of the same LFT):
//   for m=0..4: if bit m of n=t+1: L <- F - E(L+H)^-1 E^T; then double map.
// Doubling (verified R10/R11 register form): Z=(F+H)^-1, F'=F-TE^T,
// H'=H-T2 E, E'=TE with T=EZ, T2=E^T Z.  Epilogue (verified): P=L^-1,
// K=PW, Mc=A-K CA, Nb=B-K CB.
// ---------------------------------------------------------------------------
__global__ __launch_bounds__(64) void chain_k(
    const float* __restrict__ Mm, const float* __restrict__ Nm,
    const float* __restrict__ dvec, const float* __restrict__ Bm,
    const float* __restrict__ Cm, const float* __restrict__ nx,
    const float* __restrict__ na, const float* __restrict__ cov0,
    float* __restrict__ wsK, float* __restrict__ wsM, float* __restrict__ wsN)
{
    __shared__ float qm[16][17], qn[16][17], T0s[16][17];
    __shared__ float sC[32][17], sW[16][33], sAm[16][17], sBm[16][9];
    __shared__ float sE[16][17], sF[16][17], sH[16][17], sScr[16][17];
    __shared__ float sCA[32][17], sCB[32][9], sP[16][17], sK[16][33];
    __shared__ float spv[16], d2[16], sNai[32], sNxi[16];
    const int lane = threadIdx.x;
    const int t = blockIdx.x;            // 0..16
    const int n = t + 1;                 // steps to apply
    const int i = lane & 15, gq = lane >> 4, h = gq & 1;

    // ---- load inputs ----
    for (int e = lane; e < 256; e += 64) { qm[e >> 4][e & 15] = Mm[e]; qn[e >> 4][e & 15] = Nm[e]; }
    for (int e = lane; e < 512; e += 64) sC[e >> 4][e & 15] = Cm[e];
    for (int e = lane; e < 128; e += 64) sBm[e >> 3][e & 7] = Bm[e];
    if (lane < 16) {
        float s = softplus(dvec[lane]);
        spv[lane] = sqrtf(s);
        d2[lane] = 1.0f / sqrtf(1.0f + s);
        sNxi[lane] = 1.0f / (softplus(nx[lane]) + 1e-4f);
    }
    if (lane < 32) sNai[lane] = 1.0f / (softplus(na[lane]) + 1e-4f);
    __syncthreads();

    // ---- register MGS QR on both matrices (verified R12, rolled) ----
    {
        const int j0 = lane & 15;
        const int mi = lane >> 4;
        float (*Qs)[17] = (mi == 1) ? qn : qm;
        float col[16];
#pragma unroll
        for (int r = 0; r < 16; ++r) col[r] = Qs[r][j0];
        const int base = lane & 48;
#pragma unroll 1
        for (int j = 0; j < 16; ++j) {
            float qj[16];
#pragma unroll
            for (int r = 0; r < 16; ++r) qj[r] = __shfl(col[r], base + j);
            float nrm = 0.f;
#pragma unroll
            for (int r = 0; r < 16; ++r) nrm += qj[r] * qj[r];
            const float scal = 1.0f / sqrtf(nrm);
#pragma unroll
            for (int r = 0; r < 16; ++r) qj[r] *= scal;
            if (j0 == j) {
#pragma unroll
                for (int r = 0; r < 16; ++r) col[r] = qj[r];
            } else if (j0 > j) {
                float pr = 0.f;
#pragma unroll
                for (int r = 0; r < 16; ++r) pr += qj[r] * col[r];
#pragma unroll
                for (int r = 0; r < 16; ++r) col[r] -= pr * qj[r];
            }
        }
        __syncthreads();
        if (mi < 2) {
#pragma unroll
            for (int r = 0; r < 16; ++r) Qs[r][j0] = col[r];
        }
    }
    __syncthreads();

    // ---- assembly: A, W, base map E/F/H, CA, CB (verified patterns) ----
    for (int e = lane; e < 256; e += 64) {
        int ii = e >> 4, j = e & 15;
        float s = 0.f;
        for (int q = 0; q < 16; ++q) s += qm[ii][q] * d2[q] * qn[j][q];
        T0s[ii][j] = spv[ii] * s;
    }
    __syncthreads();
    for (int e = lane; e < 256; e += 64) {
        int ii = e >> 4, j = e & 15;
        float s = 0.f;
        for (int q = 0; q < 16; ++q) s += qn[ii][q] * T0s[q][j];
        sAm[ii][j] = s;
    }
    for (int e = lane; e < 512; e += 64) {
        int q = e >> 5, r = e & 31;
        sW[q][r] = sC[r][q] * sNai[r];
    }
    __syncthreads();
    for (int e = lane; e < 256; e += 64) {
        int ii = e >> 4, j = e & 15;
        float g = 0.f;
        for (int r = 0; r < 32; ++r) g += sC[r][ii] * sW[j][r];
        sF[ii][j] = g + ((ii == j) ? sNxi[ii] : 0.f);
        sE[ii][j] = sNxi[ii] * sAm[ii][j];
        float hsum = 0.f;
        for (int q = 0; q < 16; ++q) hsum += sAm[q][ii] * sNxi[q] * sAm[q][j];
        sH[ii][j] = hsum;
    }
    for (int e = lane; e < 512; e += 64) {
        int r = e >> 4, j = e & 15;
        float s = 0.f;
        for (int q = 0; q < 16; ++q) s += sC[r][q] * sAm[q][j];
        sCA[r][j] = s;
    }
    for (int e = lane; e < 256; e += 64) {
        int r = e >> 3, j = e & 7;
        float s = 0.f;
        for (int q = 0; q < 16; ++q) s += sC[r][q] * sBm[q][j];
        sCB[r][j] = s;
    }
    __syncthreads();

    // ---- base map to registers (verified R11 layout) ----
    float Erow[16], ETrow[16], Fr[8], Hr[8];
#pragma unroll
    for (int q = 0; q < 16; ++q) { Erow[q] = sE[i][q]; ETrow[q] = sE[q][i]; }
#pragma unroll
    for (int k = 0; k < 8; ++k) { Fr[k] = sF[i][8 * h + k]; Hr[k] = sH[i][8 * h + k]; }

    // ---- L0 = inv(cov0) ----
    float aug[8];
#pragma unroll
    for (int k = 0; k < 8; ++k)
        aug[k] = (gq < 2) ? cov0[i * 16 + 8 * gq + k]
                          : ((8 * (gq - 2) + k == i) ? 1.f : 0.f);
    gj16(aug, i, gq);
    float L_r[8];
#pragma unroll
    for (int k = 0; k < 8; ++k) L_r[k] = __shfl(aug[k], i + 16 * (2 + h));

    // ---- interleaved LSB-first double-and-apply ----
#pragma unroll 1
    for (int m = 0; m < 5; ++m) {
        if ((n >> m) & 1) {
            // apply: L = F - E (L+H)^-1 E^T   (verified R10 apply step)
#pragma unroll
            for (int k = 0; k < 8; ++k)
                aug[k] = (gq < 2) ? (L_r[k] + Hr[k]) : ((8 * (gq - 2) + k == i) ? 1.f : 0.f);
            gj16(aug, i, gq);
            float T_r[8];
#pragma unroll
            for (int k = 0; k < 8; ++k) T_r[k] = 0.f;
#pragma unroll
            for (int q = 0; q < 16; ++q) {
                const float eq = Erow[q];
#pragma unroll
                for (int k = 0; k < 8; ++k) T_r[k] += eq * __shfl(aug[k], q + 16 * (2 + h));
            }
            float Trow[16];
#pragma unroll
            for (int q = 0; q < 16; ++q) Trow[q] = __shfl(T_r[q & 7], i + 16 * (q >> 3));
#pragma unroll
            for (int k = 0; k < 8; ++k) L_r[k] = Fr[k];
#pragma unroll
            for (int q = 0; q < 16; ++q) {
                const float tq = Trow[q];
#pragma unroll
                for (int k = 0; k < 8; ++k) L_r[k] -= tq * __shfl(Erow[q], 8 * h + k);
            }
        }
        if (m < 4) {
            // double the map (verified R10/R11 doubling)
#pragma unroll
            for (int k = 0; k < 8; ++k)
                aug[k] = (gq < 2) ? (Fr[k] + Hr[k]) : ((8 * (gq - 2) + k == i) ? 1.f : 0.f);
            gj16(aug, i, gq);
            float Z_r[8];
#pragma unroll
            for (int k = 0; k < 8; ++k) Z_r[k] = __shfl(aug[k], i + 16 * (2 + h));
            float T_r[8], T2_r[8];
#pragma unroll
            for (int k = 0; k < 8; ++k) { T_r[k] = 0.f; T2_r[k] = 0.f; }
#pragma unroll
            for (int q = 0; q < 16; ++q) {
                const float eq = Erow[q], etq = ETrow[q];
#pragma unroll
                for (int k = 0; k < 8; ++k) {
                    const float z = __shfl(Z_r[k], q + 16 * h);
                    T_r[k] += eq * z;
                    T2_r[k] += etq * z;
                }
            }
            float Trow[16], T2row[16];
#pragma unroll
            for (int q = 0; q < 16; ++q) {
                Trow[q] = __shfl(T_r[q & 7], i + 16 * (q >> 3));
                T2row[q] = __shfl(T2_r[q & 7], i + 16 * (q >> 3));
            }
            float F2r[8], H2r[8], E2r[8];
#pragma unroll
            for (int k = 0; k < 8; ++k) { F2r[k] = Fr[k]; H2r[k] = Hr[k]; E2r[k] = 0.f; }
#pragma unroll
            for (int q = 0; q < 16; ++q) {
                const float tq = Trow[q], t2q = T2row[q];
#pragma unroll
                for (int k = 0; k < 8; ++k) {
                    const float ecol = __shfl(Erow[q], 8 * h + k);    // E[8h+k][q]
                    const float etcol = __shfl(ETrow[q], 8 * h + k);  // E[q][8h+k]
                    F2r[k] -= tq * ecol;
                    H2r[k] -= t2q * etcol;
                    E2r[k] += tq * etcol;
                }
            }
            __syncthreads();
            if (lane < 32) {
#pragma unroll
                for (int k = 0; k < 8; ++k) sScr[i][8 * h + k] = E2r[k];
            }
            __syncthreads();
#pragma unroll
            for (int q = 0; q < 16; ++q) { Erow[q] = sScr[i][q]; ETrow[q] = sScr[q][i]; }
#pragma unroll
            for (int k = 0; k < 8; ++k) { Fr[k] = F2r[k]; Hr[k] = H2r[k]; }
        }
    }

    // ---- epilogue (verified): P = L^-1, K = P W, Mc = A - K CA, Nb = B - K CB
#pragma unroll
    for (int k = 0; k < 8; ++k)
        aug[k] = (gq < 2) ? L_r[k] : ((8 * (gq - 2) + k == i) ? 1.f : 0.f);
    gj16(aug, i, gq);
    float P_r[8];
#pragma unroll
    for (int k = 0; k < 8; ++k) P_r[k] = __shfl(aug[k], i + 16 * (2 + h));
    if (lane < 32) {
#pragma unroll
        for (int k = 0; k < 8; ++k) sP[i][8 * h + k] = P_r[k];
    }
    __syncthreads();
#pragma unroll
    for (int m = 0; m < 8; ++m) {
        const int e = lane + 64 * m, ii = e >> 5, rr = e & 31;
        float s = 0.f;
#pragma unroll
        for (int q = 0; q < 16; ++q) s += sP[ii][q] * sW[q][rr];
        sK[ii][rr] = s;
        wsK[(size_t)t * 512 + e] = s;
    }
    __syncthreads();
#pragma unroll
    for (int m = 0; m < 4; ++m) {
        const int e = lane + 64 * m, ii = e >> 4, jj = e & 15;
        float s = sAm[ii][jj];
#pragma unroll
        for (int r = 0; r < 32; ++r) s -= sK[ii][r] * sCA[r][jj];
        wsM[(size_t)t * 256 + e] = s;
    }
#pragma unroll
    for (int m = 0; m < 2; ++m) {
        const int e = lane + 64 * m, ii = e >> 3, jj = e & 7;
        float s = sBm[ii][jj];
#pragma unroll
        for (int r = 0; r < 32; ++r) s -= sK[ii][r] * sCB[r][jj];
        wsN[(size_t)t * 128 + e] = s;
    }
}

// ---------------------------------------------------------------------------
// Phase A (verified R10-R12, unchanged except dead arg dropped).
// ---------------------------------------------------------------------------
__global__ __launch_bounds__(64) void phA_k(
    const float* __restrict__ u, const float* __restrict__ a,
    const float* __restrict__ wsK, const float* __restrict__ wsM,
    const float* __restrict__ wsN, float* __restrict__ wseg,
    float* __restrict__ wsp)
{
    const int lane = threadIdx.x;
    const int i = lane & 15, g = lane >> 4;
    const int seg = blockIdx.x >> 8;
    const int b = blockIdx.x & 255;

    float mcs[16][4];
#pragma unroll
    for (int j = 0; j < 16; ++j) {
        const int tc = (seg == 0) ? j : 16;
        const float4 v = *(const float4*)(wsM + (size_t)tc * 256 + i * 16 + 4 * g);
        mcs[j][0] = v.x; mcs[j][1] = v.y; mcs[j][2] = v.z; mcs[j][3] = v.w;
    }
    float kc[8], nbc[8];
    if (seg != 0) {
        const float4 k0 = *(const float4*)(wsK + (size_t)16 * 512 + i * 32 + 8 * g);
        const float4 k1 = *(const float4*)(wsK + (size_t)16 * 512 + i * 32 + 8 * g + 4);
        const float4 n0 = *(const float4*)(wsN + (size_t)16 * 128 + i * 8);
        const float4 n1 = *(const float4*)(wsN + (size_t)16 * 128 + i * 8 + 4);
        kc[0]=k0.x; kc[1]=k0.y; kc[2]=k0.z; kc[3]=k0.w;
        kc[4]=k1.x; kc[5]=k1.y; kc[6]=k1.z; kc[7]=k1.w;
        nbc[0]=n0.x; nbc[1]=n0.y; nbc[2]=n0.z; nbc[3]=n0.w;
        nbc[4]=n1.x; nbc[5]=n1.y; nbc[6]=n1.z; nbc[7]=n1.w;
    }

    float w = 0.f;
#pragma unroll
    for (int j = 0; j < 16; ++j) {
        const int t = 16 * seg + j;
        float kr[8], nbr[8];
        if (seg == 0) {
            const float4 k0 = *(const float4*)(wsK + (size_t)j * 512 + i * 32 + 8 * g);
            const float4 k1 = *(const float4*)(wsK + (size_t)j * 512 + i * 32 + 8 * g + 4);
            const float4 n0 = *(const float4*)(wsN + (size_t)j * 128 + i * 8);
            const float4 n1 = *(const float4*)(wsN + (size_t)j * 128 + i * 8 + 4);
            kr[0]=k0.x; kr[1]=k0.y; kr[2]=k0.z; kr[3]=k0.w;
            kr[4]=k1.x; kr[5]=k1.y; kr[6]=k1.z; kr[7]=k1.w;
            nbr[0]=n0.x; nbr[1]=n0.y; nbr[2]=n0.z; nbr[3]=n0.w;
            nbr[4]=n1.x; nbr[5]=n1.y; nbr[6]=n1.z; nbr[7]=n1.w;
        } else {
#pragma unroll
            for (int k = 0; k < 8; ++k) { kr[k] = kc[k]; nbr[k] = nbc[k]; }
        }
        const float a0 = a[(size_t)b * (TT * 32) + t * 32 + (lane & 31)];
        const float u0 = u[(size_t)b * (TT * 8) + t * 8 + (lane & 7)];
        float gvp = kr[0] * __shfl(a0, 8*g+0) + kr[1] * __shfl(a0, 8*g+1)
                  + kr[2] * __shfl(a0, 8*g+2) + kr[3] * __shfl(a0, 8*g+3)
                  + kr[4] * __shfl(a0, 8*g+4) + kr[5] * __shfl(a0, 8*g+5)
                  + kr[6] * __shfl(a0, 8*g+6) + kr[7] * __shfl(a0, 8*g+7);
        float nbs = nbr[0] * __shfl(u0,0) + nbr[1] * __shfl(u0,1)
                  + nbr[2] * __shfl(u0,2) + nbr[3] * __shfl(u0,3)
                  + nbr[4] * __shfl(u0,4) + nbr[5] * __shfl(u0,5)
                  + nbr[6] * __shfl(u0,6) + nbr[7] * __shfl(u0,7);
        gvp += (g == 3) ? nbs : 0.f;
        gvp += __shfl_xor(gvp, 16);
        gvp += __shfl_xor(gvp, 32);
        float part = mcs[j][0] * __shfl(w, 4*g+0) + mcs[j][1] * __shfl(w, 4*g+1)
                   + mcs[j][2] * __shfl(w, 4*g+2) + mcs[j][3] * __shfl(w, 4*g+3);
        part += __shfl_xor(part, 16);
        part += __shfl_xor(part, 32);
        w = part + gvp;
    }
    if (lane < 16) wseg[(size_t)seg * 4096 + b * 16 + i] = w;

    if (blockIdx.x == 0) {          // P0 = Mc15 ... Mc0
        float pr[4];
#pragma unroll
        for (int k = 0; k < 4; ++k) pr[k] = (4 * g + k == i) ? 1.f : 0.f;
#pragma unroll
        for (int j = 0; j < 16; ++j) {
            float np[4] = {0.f, 0.f, 0.f, 0.f};
#pragma unroll
            for (int q = 0; q < 16; ++q) {
                const float mq = __shfl(mcs[j][q & 3], i + 16 * (q >> 2));
#pragma unroll
                for (int k = 0; k < 4; ++k) np[k] += mq * __shfl(pr[k], q + 16 * g);
            }
#pragma unroll
            for (int k = 0; k < 4; ++k) pr[k] = np[k];
        }
#pragma unroll
        for (int k = 0; k < 4; ++k) wsp[i * 16 + 4 * g + k] = pr[k];
    }
    if (blockIdx.x == 256) {        // PP = Mc16^16
        float pr[4];
#pragma unroll
        for (int k = 0; k < 4; ++k) pr[k] = mcs[0][k];
#pragma unroll
        for (int r = 0; r < 4; ++r) {
            float np[4] = {0.f, 0.f, 0.f, 0.f};
#pragma unroll
            for (int q = 0; q < 16; ++q) {
                const float sq = __shfl(pr[q & 3], i + 16 * (q >> 2));
#pragma unroll
                for (int k = 0; k < 4; ++k) np[k] += sq * __shfl(pr[k], q + 16 * g);
            }
#pragma unroll
            for (int k = 0; k < 4; ++k) pr[k] = np[k];
        }
#pragma unroll
        for (int k = 0; k < 4; ++k) wsp[256 + i * 16 + 4 * g + k] = pr[k];
    }
}

// ---------------------------------------------------------------------------
// Phase B (verified R9-R12, unchanged).
// ---------------------------------------------------------------------------
__global__ __launch_bounds__(64) void phB_k(
    const float* __restrict__ mean0, const float* __restrict__ wsp,
    const float* __restrict__ wseg, float* __restrict__ bnd)
{
    const int lane = threadIdx.x;
    const int i = lane & 15, g = lane >> 4;
    const int b = blockIdx.x;

    const float4 v0 = *(const float4*)(wsp + i * 16 + 4 * g);
    const float4 vp = *(const float4*)(wsp + 256 + i * 16 + 4 * g);
    const float m0s[4] = {v0.x, v0.y, v0.z, v0.w};
    const float mps[4] = {vp.x, vp.y, vp.z, vp.w};
    float wv[16];
#pragma unroll
    for (int s = 0; s < 16; ++s) wv[s] = wseg[(size_t)s * 4096 + b * 16 + i];

    float mn = mean0[b * 16 + i];
#pragma unroll
    for (int s = 0; s < 16; ++s) {
        if (lane < 16) bnd[(size_t)s * 4096 + b * 16 + i] = mn;
        const float c0 = (s == 0) ? m0s[0] : mps[0];
        const float c1 = (s == 0) ? m0s[1] : mps[1];
        const float c2 = (s == 0) ? m0s[2] : mps[2];
        const float c3 = (s == 0) ? m0s[3] : mps[3];
        float part = c0 * __shfl(mn, 4 * g + 0) + c1 * __shfl(mn, 4 * g + 1)
                   + c2 * __shfl(mn, 4 * g + 2) + c3 * __shfl(mn, 4 * g + 3);
        part += __shfl_xor(part, 16);
        part += __shfl_xor(part, 32);
        mn = part + wv[s];
    }
}

// ---------------------------------------------------------------------------
// Phase C (verified R10-R12, unchanged).
// ---------------------------------------------------------------------------
__global__ __launch_bounds__(64) void phC_k(
    const float* __restrict__ u, const float* __restrict__ a,
    const float* __restrict__ wsK, const float* __restrict__ wsM,
    const float* __restrict__ wsN, const float* __restrict__ bnd,
    float* __restrict__ out)
{
    const int lane = threadIdx.x;
    const int i = lane & 15, g = lane >> 4;
    const int seg = blockIdx.x >> 8;
    const int b = blockIdx.x & 255;

    float mcs[16][4];
#pragma unroll
    for (int j = 0; j < 16; ++j) {
        const int tc = (seg == 0) ? j : 16;
        const float4 v = *(const float4*)(wsM + (size_t)tc * 256 + i * 16 + 4 * g);
        mcs[j][0] = v.x; mcs[j][1] = v.y; mcs[j][2] = v.z; mcs[j][3] = v.w;
    }
    float kc[8], nbc[8];
    if (seg != 0) {
        const float4 k0 = *(const float4*)(wsK + (size_t)16 * 512 + i * 32 + 8 * g);
        const float4 k1 = *(const float4*)(wsK + (size_t)16 * 512 + i * 32 + 8 * g + 4);
        const float4 n0 = *(const float4*)(wsN + (size_t)16 * 128 + i * 8);
        const float4 n1 = *(const float4*)(wsN + (size_t)16 * 128 + i * 8 + 4);
        kc[0]=k0.x; kc[1]=k0.y; kc[2]=k0.z; kc[3]=k0.w;
        kc[4]=k1.x; kc[5]=k1.y; kc[6]=k1.z; kc[7]=k1.w;
        nbc[0]=n0.x; nbc[1]=n0.y; nbc[2]=n0.z; nbc[3]=n0.w;
        nbc[4]=n1.x; nbc[5]=n1.y; nbc[6]=n1.z; nbc[7]=n1.w;
    }

    float mn = bnd[(size_t)seg * 4096 + b * 16 + i];
    float* ob = out + (size_t)b * 4096 + (size_t)(16 * seg) * 16;
#pragma unroll
    for (int j = 0; j < 16; ++j) {
        const int t = 16 * seg + j;
        float kr[8], nbr[8];
        if (seg == 0) {
            const float4 k0 = *(const float4*)(wsK + (size_t)j * 512 + i * 32 + 8 * g);
            const float4 k1 = *(const float4*)(wsK + (size_t)j * 512 + i * 32 + 8 * g + 4);
            const float4 n0 = *(const float4*)(wsN + (size_t)j * 128 + i * 8);
            const float4 n1 = *(const float4*)(wsN + (size_t)j * 128 + i * 8 + 4);
            kr[0]=k0.x; kr[1]=k0.y; kr[2]=k0.z; kr[3]=k0.w;
            kr[4]=k1.x; kr[5]=k1.y; kr[6]=k1.z; kr[7]=k1.w;
            nbr[0]=n0.x; nbr[1]=n0.y; nbr[2]=n0.z; nbr[3]=n0.w;
            nbr[4]=n1.x; nbr[5]=n1.y; nbr[6]=n1.z; nbr[7]=n1.w;
        } else {
#pragma unroll
            for (int k = 0; k < 8; ++k) { kr[k] = kc[k]; nbr[k] = nbc[k]; }
        }
        const float a0 = a[(size_t)b * (TT * 32) + t * 32 + (lane & 31)];
        const float u0 = u[(size_t)b * (TT * 8) + t * 8 + (lane & 7)];
        float gvp = kr[0] * __shfl(a0, 8*g+0) + kr[1] * __shfl(a0, 8*g+1)
                  + kr[2] * __shfl(a0, 8*g+2) + kr[3] * __shfl(a0, 8*g+3)
                  + kr[4] * __shfl(a0, 8*g+4) + kr[5] * __shfl(a0, 8*g+5)
                  + kr[6] * __shfl(a0, 8*g+6) + kr[7] * __shfl(a0, 8*g+7);
        float nbs = nbr[0] * __shfl(u0,0) + nbr[1] * __shfl(u0,1)
                  + nbr[2] * __shfl(u0,2) + nbr[3] * __shfl(u0,3)
                  + nbr[4] * __shfl(u0,4) + nbr[5] * __shfl(u0,5)
                  + nbr[6] * __shfl(u0,6) + nbr[7] * __shfl(u0,7);
        gvp += (g == 3) ? nbs : 0.f;
        gvp += __shfl_xor(gvp, 16);
        gvp += __shfl_xor(gvp, 32);
        float part = mcs[j][0] * __shfl(mn, 4*g+0) + mcs[j][1] * __shfl(mn, 4*g+1)
                   + mcs[j][2] * __shfl(mn, 4*g+2) + mcs[j][3] * __shfl(mn, 4*g+3);
        part += __shfl_xor(part, 16);
        part += __shfl_xor(part, 32);
        mn = part + gvp;
        if (lane < 16) ob[j * 16 + i] = mn;
    }
}

// ---------------------------------------------------------------------------
// Fallback (verified R6/R8/R9, unchanged): serial mean pass if ws too small.
// ---------------------------------------------------------------------------
__global__ __launch_bounds__(64) void meanf_k(
    const float* __restrict__ mean0, const float* __restrict__ u,
    const float* __restrict__ a, const float* __restrict__ wsK,
    const float* __restrict__ wsM, const float* __restrict__ wsN,
    float* __restrict__ out)
{
    const int lane = threadIdx.x;
    const int b = blockIdx.x;
    const int i = lane & 15;
    const int g = lane >> 4;

    const float* ub = u + (size_t)b * TT * 8;
    const float* ab = a + (size_t)b * TT * 32;
    float* ob = out + (size_t)b * TT * 16;

    float mn = mean0[b * 16 + i];
    float Mc[16];
    {
        const float4* p = (const float4*)(wsM + i * 16);
        float4 x0 = p[0], x1 = p[1], x2 = p[2], x3 = p[3];
        Mc[0]=x0.x; Mc[1]=x0.y; Mc[2]=x0.z; Mc[3]=x0.w;
        Mc[4]=x1.x; Mc[5]=x1.y; Mc[6]=x1.z; Mc[7]=x1.w;
        Mc[8]=x2.x; Mc[9]=x2.y; Mc[10]=x2.z; Mc[11]=x2.w;
        Mc[12]=x3.x; Mc[13]=x3.y; Mc[14]=x3.z; Mc[15]=x3.w;
    }
    float gv;
    {
        float4 k0 = *(const float4*)(wsK + i * 32 + 8 * g);
        float4 k1 = *(const float4*)(wsK + i * 32 + 8 * g + 4);
        float4 n0 = *(const float4*)(wsN + i * 8);
        float4 n1 = *(const float4*)(wsN + i * 8 + 4);
        float u0 = ub[lane & 7];
        float a0 = ab[lane & 31];
        float part = k0.x * __shfl(a0, 8*g+0) + k0.y * __shfl(a0, 8*g+1)
                   + k0.z * __shfl(a0, 8*g+2) + k0.w * __shfl(a0, 8*g+3)
                   + k1.x * __shfl(a0, 8*g+4) + k1.y * __shfl(a0, 8*g+5)
                   + k1.z * __shfl(a0, 8*g+6) + k1.w * __shfl(a0, 8*g+7);
        float nbs = n0.x * __shfl(u0,0) + n0.y * __shfl(u0,1)
                  + n0.z * __shfl(u0,2) + n0.w * __shfl(u0,3)
                  + n1.x * __shfl(u0,4) + n1.y * __shfl(u0,5)
                  + n1.z * __shfl(u0,6) + n1.w * __shfl(u0,7);
        part += (g == 3) ? nbs : 0.f;
        part += __shfl_xor(part, 16);
        part += __shfl_xor(part, 32);
        gv = part;
    }
    float4 mA, mB, mC, mD, kp0, kp1, np0, np1;
    float upn, apn;
    {
        const float4* p = (const float4*)(wsM + 256 + i * 16);
        mA = p[0]; mB = p[1]; mC = p[2]; mD = p[3];
        kp0 = *(const float4*)(wsK + 512 + i * 32 + 8 * g);
        kp1 = *(const float4*)(wsK + 512 + i * 32 + 8 * g + 4);
        np0 = *(const float4*)(wsN + 128 + i * 8);
        np1 = *(const float4*)(wsN + 128 + i * 8 + 4);
        upn = ub[8 + (lane & 7)];
        apn = ab[32 + (lane & 31)];
    }

    for (int t = 0; t < TT; ++t) {
        const int t2 = (t + 2 < TT) ? t + 2 : TT - 1;
        const int s2 = (t2 < WARM) ? t2 : WARM;
        const float4* mp = (const float4*)(wsM + (size_t)s2 * 256 + i * 16);
        float4 l0 = mp[0], l1 = mp[1], l2 = mp[2], l3 = mp[3];
        float4 kl0 = *(const float4*)(wsK + (size_t)s2 * 512 + i * 32 + 8 * g);
        float4 kl1 = *(const float4*)(wsK + (size_t)s2 * 512 + i * 32 + 8 * g + 4);
        float4 nl0 = *(const float4*)(wsN + (size_t)s2 * 128 + i * 8);
        float4 nl1 = *(const float4*)(wsN + (size_t)s2 * 128 + i * 8 + 4);
        float ul = ub[t2 * 8 + (lane & 7)];
        float al = ab[t2 * 32 + (lane & 31)];

        float s0 = gv, s1 = 0.f, s2f = 0.f, s3 = 0.f;
#pragma unroll
        for (int q = 0; q < 16; q += 4) {
            s0  += Mc[q]     * __shfl(mn, q);
            s1  += Mc[q + 1] * __shfl(mn, q + 1);
            s2f += Mc[q + 2] * __shfl(mn, q + 2);
            s3  += Mc[q + 3] * __shfl(mn, q + 3);
        }
        mn = (s0 + s1) + (s2f + s3);
        if (lane < 16) ob[t * 16 + lane] = mn;

        float part = kp0.x * __shfl(apn, 8*g+0) + kp0.y * __shfl(apn, 8*g+1)
                   + kp0.z * __shfl(apn, 8*g+2) + kp0.w * __shfl(apn, 8*g+3)
                   + kp1.x * __shfl(apn, 8*g+4) + kp1.y * __shfl(apn, 8*g+5)
                   + kp1.z * __shfl(apn, 8*g+6) + kp1.w * __shfl(apn, 8*g+7);
        float nbs = np0.x * __shfl(upn,0) + np0.y * __shfl(upn,1)
                  + np0.z * __shfl(upn,2) + np0.w * __shfl(upn,3)
                  + np1.x * __shfl(upn,4) + np1.y * __shfl(upn,5)
                  + np1.z * __shfl(upn,6) + np1.w * __shfl(upn,7);
        part += (g == 3) ? nbs : 0.f;
        part += __shfl_xor(part, 16);
        part += __shfl_xor(part, 32);
        gv = part;

        Mc[0]=mA.x; Mc[1]=mA.y; Mc[2]=mA.z; Mc[3]=mA.w;
        Mc[4]=mB.x; Mc[5]=mB.y; Mc[6]=mB.z; Mc[7]=mB.w;
        Mc[8]=mC.x; Mc[9]=mC.y; Mc[10]=mC.z; Mc[11]=mC.w;
        Mc[12]=mD.x; Mc[13]=mD.y; Mc[14]=mD.z; Mc[15]=mD.w;
        mA = l0; mB = l1; mC = l2; mD = l3;
        kp0 = kl0; kp1 = kl1; np0 = nl0; np1 = nl1;
        upn = ul; apn = al;
    }
}

extern "C" void kernel_launch(void* const* d_in, const int* in_sizes, int n_in,
                              void* d_out, int out_size, void* d_ws, size_t ws_size,
                              hipStream_t stream) {
    const float* mean0 = nullptr; const float* cov0 = nullptr;
    const float* u = nullptr;     const float* a = nullptr;
    const float* Mm = nullptr;    const float* Nm = nullptr;
    const float* dv = nullptr;    const float* Bm = nullptr;
    const float* Cm = nullptr;    const float* nxp = nullptr;
    const float* nap = nullptr;
    for (int i = 0; i < n_in; ++i) {
        const float* p = (const float*)d_in[i];
        switch (in_sizes[i]) {
            case 256 * 16:        mean0 = p; break;
            case 256 * 256:       cov0 = p; break;
            case 256 * 256 * 8:   u = p; break;
            case 256 * 256 * 32:  a = p; break;
            case 256:             if (!Mm) Mm = p; else Nm = p; break;
            case 16:              if (!dv) dv = p; else nxp = p; break;
            case 128:             Bm = p; break;
            case 512:             Cm = p; break;
            case 32:              nap = p; break;
            default: break;
        }
    }
    float* ws   = (float*)d_ws;
    float* wsK  = ws + OFF_K;
    float* wsM  = ws + OFF_MC;
    float* wsN  = ws + OFF_NB;
    float* wsp  = ws + OFF_P0;
    float* wseg = ws + OFF_WSEG;
    float* bnd  = ws + OFF_BND;

    chain_k<<<WARM + 1, 64, 0, stream>>>(Mm, Nm, dv, Bm, Cm, nxp, nap, cov0,
                                         wsK, wsM, wsN);
    if (ws_size >= NEED_WS_BYTES) {
        phA_k<<<16 * 256, 64, 0, stream>>>(u, a, wsK, wsM, wsN, wseg, wsp);
        phB_k<<<256, 64, 0, stream>>>(mean0, wsp, wseg, bnd);
        phC_k<<<16 * 256, 64, 0, stream>>>(u, a, wsK, wsM, wsN, bnd, (float*)d_out);
    } else {
        meanf_k<<<256, 64, 0, stream>>>(mean0, u, a, wsK, wsM, wsN, (float*)d_out);
    }
}